// Round 1
// baseline (321.766 us; speedup 1.0000x reference)
//
#include <hip/hip_runtime.h>
#include <hip/hip_bf16.h>

typedef __hip_bfloat16 bf16;
typedef __bf16 bfrag __attribute__((ext_vector_type(8)));   // 8 bf16 = 4 VGPRs (MFMA A/B operand)
typedef float f32x4 __attribute__((ext_vector_type(4)));    // MFMA C/D

#define AS1 __attribute__((address_space(1)))
#define AS3 __attribute__((address_space(3)))

static constexpr int Bb = 8, Nn = 4096, Cc = 512, Hh = 8;
static constexpr int Mtok = Bb * Nn;          // 32768
static constexpr int QKVC = 3 * Cc;           // 1536
// ws layout (NEED = 57,147,392 bytes; round 4 proved ws_size >= 59,768,832):
//  xn/g [0, 33554432)          bf16 [32768][512]
//  Gcov [33554432, 41943040)   f32  [8][512][512]
//  Gcvb [41943040, 46137344)   bf16 [8][512][512]
//  T    [46137344, 54525952)   bf16 [8][1024][512]
//  P    [54525952, 55050240)   bf16 [8][8][64][64]
//  wq   [55050240, 56623104)   bf16 [1536][512]
//  wp   [56623104, 57147392)   bf16 [512][512]
static constexpr size_t WS_NEED = 57147392;

__device__ __forceinline__ void gl_lds16(const void* g, void* l) {
  __builtin_amdgcn_global_load_lds((const AS1 void*)g, (AS3 void*)l, 16, 0, 0);
}
__device__ __forceinline__ float gelu_exact(float x) {
  return 0.5f * x * (1.0f + erff(x * 0.70710678118654752f));
}

// ---------------- diagnostic fill (fp32 output) ----------------
__global__ __launch_bounds__(256) void fill_f32(float* o, float val, int n) {
  int i = blockIdx.x * 256 + threadIdx.x;
  if (i < n) o[i] = val;
}

// ---------------- fp32 -> bf16 conversion ----------------
__global__ __launch_bounds__(256) void cvt_f32_bf16(const float* __restrict__ a,
                                                    bf16* __restrict__ o, int n) {
  int i = (blockIdx.x * 256 + threadIdx.x) * 8;
  if (i + 8 <= n) {
    float f[8];
    *(float4*)f       = *(const float4*)(a + i);
    *(float4*)(f + 4) = *(const float4*)(a + i + 4);
    bf16 v[8];
#pragma unroll
    for (int j = 0; j < 8; ++j) v[j] = __float2bfloat16(f[j]);
    *(uint4*)(o + i) = *(uint4*)v;
  }
}

// ---------------- LayerNorm (one wave per token), fp32 in -> bf16 out ----------------
__global__ __launch_bounds__(256) void ln_kernel(const float* __restrict__ x,
                                                 const float* __restrict__ gw,
                                                 const float* __restrict__ bw,
                                                 bf16* __restrict__ xn) {
  int tok  = blockIdx.x * 4 + (threadIdx.x >> 6);
  int lane = threadIdx.x & 63;
  const float* xr = x + (size_t)tok * Cc + lane * 8;
  float f[8];
  *(float4*)f       = *(const float4*)xr;
  *(float4*)(f + 4) = *(const float4*)(xr + 4);
  float s = 0.f;
#pragma unroll
  for (int j = 0; j < 8; ++j) s += f[j];
#pragma unroll
  for (int m = 32; m; m >>= 1) s += __shfl_xor(s, m);
  float mu = s * (1.0f / 512.0f);
  float q = 0.f;
#pragma unroll
  for (int j = 0; j < 8; ++j) { float d = f[j] - mu; q += d * d; }
#pragma unroll
  for (int m = 32; m; m >>= 1) q += __shfl_xor(q, m);
  float rstd = rsqrtf(q * (1.0f / 512.0f) + 1e-5f);
  bf16 o[8];
#pragma unroll
  for (int j = 0; j < 8; ++j)
    o[j] = __float2bfloat16((f[j] - mu) * rstd * gw[lane * 8 + j] + bw[lane * 8 + j]);
  *(uint4*)(xn + (size_t)tok * Cc + lane * 8) = *(uint4*)o;
}

// ------------- GEMM C[M,N] = A[M,K] @ B[N,K]^T, bf16 in, bf16 OR fp32 out, batched -------------
template <typename TC>
__global__ __launch_bounds__(256) void gemm_bt(const bf16* __restrict__ A,
                                               const bf16* __restrict__ B,
                                               TC* __restrict__ C,
                                               int M, int N, int K,
                                               const float* __restrict__ bias,
                                               long sA_z, long sB_z, long sC_z) {
  A += (size_t)blockIdx.z * sA_z;
  B += (size_t)blockIdx.z * sB_z;
  C += (size_t)blockIdx.z * sC_z;
  __shared__ __align__(16) bf16 smem[16384];   // sA[128][64] | sB[128][64]; reused as ct[128][128]
  bf16* sA = smem;
  bf16* sB = smem + 8192;
  int t = threadIdx.x, w = t >> 6, lane = t & 63, fr = lane & 15, quad = lane >> 4;
  int n0 = blockIdx.x * 128, m0 = blockIdx.y * 128;
  int wm = (w >> 1) * 64, wn = (w & 1) * 64;
  f32x4 acc[4][4] = {};

  for (int k0 = 0; k0 < K; k0 += 64) {
    __syncthreads();
#pragma unroll
    for (int c2 = 0; c2 < 4; ++c2) {
      int c = w * 4 + c2;                // 1KB chunk id, 0..15
      int row = c * 8 + (lane >> 3);     // 0..127
      int ke  = (lane & 7) * 8;
      gl_lds16(A + (size_t)(m0 + row) * K + k0 + ke, (char*)sA + c * 1024);
      gl_lds16(B + (size_t)(n0 + row) * K + k0 + ke, (char*)sB + c * 1024);
    }
    __syncthreads();
#pragma unroll
    for (int kk = 0; kk < 64; kk += 32) {
      bfrag af[4], bg[4];
#pragma unroll
      for (int i = 0; i < 4; ++i) af[i] = *(const bfrag*)(sA + (wm + i * 16 + fr) * 64 + kk + quad * 8);
#pragma unroll
      for (int j = 0; j < 4; ++j) bg[j] = *(const bfrag*)(sB + (wn + j * 16 + fr) * 64 + kk + quad * 8);
#pragma unroll
      for (int i = 0; i < 4; ++i)
#pragma unroll
        for (int j = 0; j < 4; ++j)
          acc[i][j] = __builtin_amdgcn_mfma_f32_16x16x32_bf16(af[i], bg[j], acc[i][j], 0, 0, 0);
    }
  }

  if constexpr (__is_same(TC, float)) {
    // direct fp32 stores from C-fragment layout (col=fr, row=quad*4+r)
#pragma unroll
    for (int j = 0; j < 4; ++j) {
      float bj = bias ? bias[n0 + wn + j * 16 + fr] : 0.0f;
#pragma unroll
      for (int i = 0; i < 4; ++i)
#pragma unroll
        for (int r = 0; r < 4; ++r)
          C[(size_t)(m0 + wm + i * 16 + quad * 4 + r) * N + n0 + wn + j * 16 + fr] =
              acc[i][j][r] + bj;
    }
  } else {
    __syncthreads();
    bf16* ct = smem;                      // [128][128]
#pragma unroll
    for (int j = 0; j < 4; ++j) {
      float bj = bias ? bias[n0 + wn + j * 16 + fr] : 0.0f;
#pragma unroll
      for (int i = 0; i < 4; ++i)
#pragma unroll
        for (int r = 0; r < 4; ++r)
          ct[(wm + i * 16 + quad * 4 + r) * 128 + wn + j * 16 + fr] =
              __float2bfloat16(acc[i][j][r] + bj);
    }
    __syncthreads();
#pragma unroll
    for (int r8 = 0; r8 < 8; ++r8) {
      int row = r8 * 16 + (t >> 4);
      int ce  = (t & 15) * 8;
      *(uint4*)(C + (size_t)(m0 + row) * N + n0 + ce) = *(const uint4*)(smem + row * 128 + ce);
    }
  }
}

// ---- Gcov[b] += Xb^T Xb (split-K over tokens, XOR-swizzled LDS transpose, fp32 atomics) ----
__global__ __launch_bounds__(256) void xtx(const bf16* __restrict__ xn,
                                           float* __restrict__ Gcov) {
  int tile = blockIdx.x;           // 0..15 -> (m0,n0)
  int split = blockIdx.y;          // 0..7, 512 tokens each
  int b = blockIdx.z;
  int m0 = (tile >> 2) * 128, n0 = (tile & 3) * 128;
  int t = threadIdx.x, w = t >> 6, lane = t & 63, fr = lane & 15, quad = lane >> 4;
  int wm = (w >> 1) * 64, wn = (w & 1) * 64;
  __shared__ __align__(16) bf16 sA[8192], sB[8192];   // [128 ch][64 tok], token XOR-swizzled
  f32x4 acc[4][4] = {};
  const bf16* xb = xn + ((size_t)b * Nn + split * 512) * Cc;
  int ch0 = (t & 15) * 8;
  int sw  = (t & 7) << 3;
  for (int kc = 0; kc < 8; ++kc) {
    __syncthreads();
#pragma unroll
    for (int it = 0; it < 4; ++it) {
      int tk  = it * 16 + (t >> 4);
      int tks = tk ^ sw;
      bf16 va[8]; *(uint4*)va = *(const uint4*)(xb + (size_t)(kc * 64 + tk) * Cc + m0 + ch0);
      bf16 vb[8]; *(uint4*)vb = *(const uint4*)(xb + (size_t)(kc * 64 + tk) * Cc + n0 + ch0);
#pragma unroll
      for (int j = 0; j < 8; ++j) {
        sA[(ch0 + j) * 64 + tks] = va[j];
        sB[(ch0 + j) * 64 + tks] = vb[j];
      }
    }
    __syncthreads();
#pragma unroll
    for (int s = 0; s < 2; ++s) {
      bfrag af[4], bg[4];
#pragma unroll
      for (int i = 0; i < 4; ++i) {
        int ch = wm + i * 16 + fr;
        int blk = (s * 4 + quad) ^ ((ch >> 3) & 7);
        af[i] = *(const bfrag*)(sA + ch * 64 + blk * 8);
      }
#pragma unroll
      for (int j = 0; j < 4; ++j) {
        int ch = wn + j * 16 + fr;
        int blk = (s * 4 + quad) ^ ((ch >> 3) & 7);
        bg[j] = *(const bfrag*)(sB + ch * 64 + blk * 8);
      }
#pragma unroll
      for (int i = 0; i < 4; ++i)
#pragma unroll
        for (int j = 0; j < 4; ++j)
          acc[i][j] = __builtin_amdgcn_mfma_f32_16x16x32_bf16(af[i], bg[j], acc[i][j], 0, 0, 0);
    }
  }
  float* gb = Gcov + (size_t)b * Cc * Cc;
#pragma unroll
  for (int i = 0; i < 4; ++i)
#pragma unroll
    for (int j = 0; j < 4; ++j)
#pragma unroll
      for (int r = 0; r < 4; ++r)
        atomicAdd(&gb[(size_t)(m0 + wm + i * 16 + quad * 4 + r) * Cc + n0 + wn + j * 16 + fr],
                  acc[i][j][r]);
}

// ---- per (b,h): Gram = T_q @ Wk^T (MFMA, K=512), norms via row-dots, softmax -> P bf16 ----
__global__ __launch_bounds__(256) void gram_softmax(const bf16* __restrict__ T,
                                                    const bf16* __restrict__ wq,
                                                    const float* __restrict__ temp,
                                                    bf16* __restrict__ P) {
  int h = blockIdx.x, b = blockIdx.y;
  int t = threadIdx.x, w = t >> 6, lane = t & 63, fr = lane & 15, quad = lane >> 4;
  const bf16* Tq = T + (size_t)b * 1024 * 512 + (size_t)(h * 64) * 512;
  const bf16* Tk = T + (size_t)b * 1024 * 512 + (size_t)(512 + h * 64) * 512;
  const bf16* Wqh = wq + (size_t)(h * 64) * 512;
  const bf16* Wkh = wq + (size_t)(512 + h * 64) * 512;
  f32x4 acc[4][4] = {};
#pragma unroll
  for (int s = 0; s < 4; ++s) {
    int kb = w * 128 + s * 32 + quad * 8;
    bfrag af[4], bg[4];
#pragma unroll
    for (int i = 0; i < 4; ++i) af[i] = *(const bfrag*)(Tq + (size_t)(i * 16 + fr) * 512 + kb);
#pragma unroll
    for (int j = 0; j < 4; ++j) bg[j] = *(const bfrag*)(Wkh + (size_t)(j * 16 + fr) * 512 + kb);
#pragma unroll
    for (int i = 0; i < 4; ++i)
#pragma unroll
      for (int j = 0; j < 4; ++j)
        acc[i][j] = __builtin_amdgcn_mfma_f32_16x16x32_bf16(af[i], bg[j], acc[i][j], 0, 0, 0);
  }
  __shared__ float parts[4 * 4096];
  __shared__ float nrm[2][4][64];
  __shared__ float nqk[2][64];
#pragma unroll
  for (int i = 0; i < 4; ++i)
#pragma unroll
    for (int j = 0; j < 4; ++j)
#pragma unroll
      for (int r = 0; r < 4; ++r)
        parts[w * 4096 + (i * 16 + quad * 4 + r) * 64 + j * 16 + fr] = acc[i][j][r];
  {
    int d = t & 63, qtr = t >> 6, c0 = qtr * 128;
    float pq = 0.f, pk = 0.f;
#pragma unroll 4
    for (int cc = 0; cc < 16; ++cc) {
      bf16 a[8], ww[8];
      *(uint4*)a  = *(const uint4*)(Tq + (size_t)d * 512 + c0 + cc * 8);
      *(uint4*)ww = *(const uint4*)(Wqh + (size_t)d * 512 + c0 + cc * 8);
#pragma unroll
      for (int j = 0; j < 8; ++j) pq += __bfloat162float(a[j]) * __bfloat162float(ww[j]);
      *(uint4*)a  = *(const uint4*)(Tk + (size_t)d * 512 + c0 + cc * 8);
      *(uint4*)ww = *(const uint4*)(Wkh + (size_t)d * 512 + c0 + cc * 8);
#pragma unroll
      for (int j = 0; j < 8; ++j) pk += __bfloat162float(a[j]) * __bfloat162float(ww[j]);
    }
    nrm[0][qtr][d] = pq;
    nrm[1][qtr][d] = pk;
  }
  __syncthreads();
  if (t < 64) {
    nqk[0][t] = fmaxf(sqrtf(nrm[0][0][t] + nrm[0][1][t] + nrm[0][2][t] + nrm[0][3][t]), 1e-12f);
    nqk[1][t] = fmaxf(sqrtf(nrm[1][0][t] + nrm[1][1][t] + nrm[1][2][t] + nrm[1][3][t]), 1e-12f);
  }
  __syncthreads();
  if (t < 64) {
    int d = t;
    float sc = temp[h] / nqk[0][d];
    float l[64]; float mx = -1e30f;
#pragma unroll
    for (int e = 0; e < 64; ++e) {
      float vsum = parts[d * 64 + e] + parts[4096 + d * 64 + e] +
                   parts[8192 + d * 64 + e] + parts[12288 + d * 64 + e];
      l[e] = vsum * sc / nqk[1][e];
      mx = fmaxf(mx, l[e]);
    }
    float sum = 0.f;
#pragma unroll
    for (int e = 0; e < 64; ++e) { l[e] = expf(l[e] - mx); sum += l[e]; }
    float inv = 1.0f / sum;
    bf16* pr = P + ((size_t)(b * 8 + h) * 64 + d) * 64;
#pragma unroll
    for (int e = 0; e < 64; ++e) pr[e] = __float2bfloat16(l[e] * inv);
  }
}

// ---- out = P @ v, exact GELU, store g[token][C] (bf16) ----
__global__ __launch_bounds__(256) void pv_gelu(const bf16* __restrict__ P,
                                               const bf16* __restrict__ v,
                                               bf16* __restrict__ g) {
  int chunk = blockIdx.x, h = blockIdx.y, b = blockIdx.z;
  int t = threadIdx.x, w = t >> 6, lane = t & 63, fr = lane & 15, quad = lane >> 4;
  const bf16* pb = P + (size_t)(b * 8 + h) * 4096;
  bfrag pf[4][2];
#pragma unroll
  for (int i = 0; i < 4; ++i)
#pragma unroll
    for (int c = 0; c < 2; ++c)
      pf[i][c] = *(const bfrag*)(pb + (i * 16 + fr) * 64 + c * 32 + quad * 8);
#pragma unroll 2
  for (int nt = 0; nt < 8; ++nt) {
    int ntok = chunk * 512 + w * 128 + nt * 16 + fr;
    const bf16* vrow = v + (size_t)(b * Nn + ntok) * Cc + h * 64 + quad * 8;
    bfrag bv0 = *(const bfrag*)(vrow);
    bfrag bv1 = *(const bfrag*)(vrow + 32);
    f32x4 acc[4] = {};
#pragma unroll
    for (int i = 0; i < 4; ++i) {
      acc[i] = __builtin_amdgcn_mfma_f32_16x16x32_bf16(pf[i][0], bv0, acc[i], 0, 0, 0);
      acc[i] = __builtin_amdgcn_mfma_f32_16x16x32_bf16(pf[i][1], bv1, acc[i], 0, 0, 0);
    }
    bf16* grow = g + (size_t)(b * Nn + ntok) * Cc + h * 64;
#pragma unroll
    for (int i = 0; i < 4; ++i) {
      bf16 o[4];
#pragma unroll
      for (int r = 0; r < 4; ++r) o[r] = __float2bfloat16(gelu_exact(acc[i][r]));
      *(uint2*)(grow + i * 16 + quad * 4) = *(uint2*)o;
    }
  }
}

extern "C" void kernel_launch(void* const* d_in, const int* in_sizes, int n_in,
                              void* d_out, int out_size, void* d_ws, size_t ws_size,
                              hipStream_t stream) {
  const float* x      = (const float*)d_in[0];
  const float* ln_g   = (const float*)d_in[1];
  const float* ln_b   = (const float*)d_in[2];
  const float* qkv_w  = (const float*)d_in[3];
  const float* temp   = (const float*)d_in[4];
  const float* proj_w = (const float*)d_in[5];
  const float* proj_b = (const float*)d_in[6];
  float* out = (float*)d_out;                       // fp32 output (reference returns float32)
  char*  ws  = (char*)d_ws;

  // --- runtime guards: silent failure -> measurable absmax signature ---
  const int exp_sizes[7] = {16777216, 512, 512, 786432, 8, 262144, 512};
  bool sizes_ok = (n_in == 7) && (out_size == 16777216);
  if (sizes_ok) for (int i = 0; i < 7; ++i) sizes_ok = sizes_ok && (in_sizes[i] == exp_sizes[i]);
  if (!sizes_ok) {
    fill_f32<<<(16777216 + 255) / 256, 256, 0, stream>>>(out, 500.0f, out_size);
    return;
  }
  if (ws_size < WS_NEED) {
    fill_f32<<<(16777216 + 255) / 256, 256, 0, stream>>>(out, (float)(ws_size >> 20), out_size);
    return;
  }

  bf16*  xn   = (bf16*)ws;                          // reused as g after xtx+vGEMM consume it
  bf16*  g    = (bf16*)ws;
  float* Gcov = (float*)(ws + 33554432);
  bf16*  Gcvb = (bf16*)(ws + 41943040);
  bf16*  T    = (bf16*)(ws + 46137344);
  bf16*  P    = (bf16*)(ws + 54525952);
  bf16*  wq   = (bf16*)(ws + 55050240);
  bf16*  wp   = (bf16*)(ws + 56623104);
  bf16*  v    = (bf16*)d_out;                       // park bf16 v in d_out; dead before final GEMM

  cvt_f32_bf16<<<384, 256, 0, stream>>>(qkv_w, wq, QKVC * Cc);
  cvt_f32_bf16<<<128, 256, 0, stream>>>(proj_w, wp, Cc * Cc);
  hipMemsetAsync(Gcov, 0, (size_t)Bb * Cc * Cc * sizeof(float), stream);
  ln_kernel<<<Mtok / 4, 256, 0, stream>>>(x, ln_g, ln_b, xn);
  // v = xn @ Wv^T (Wv = qkv_w rows 1024..1535)
  gemm_bt<bf16><<<dim3(4, 256, 1), 256, 0, stream>>>(xn, wq + 1024 * 512, v, Mtok, Cc, Cc,
                                                     nullptr, 0, 0, 0);
  xtx<<<dim3(16, 8, 8), 256, 0, stream>>>(xn, Gcov);
  cvt_f32_bf16<<<1024, 256, 0, stream>>>(Gcov, Gcvb, Bb * Cc * Cc);
  // T[b] = Wqk @ Gcov[b]  (Gcov symmetric => @Gcov^T == @Gcov)
  gemm_bt<bf16><<<dim3(4, 8, 8), 256, 0, stream>>>(wq, Gcvb, T, 1024, Cc, Cc,
                                                   nullptr, 0, (long)Cc * Cc, (long)1024 * Cc);
  gram_softmax<<<dim3(Hh, Bb), 256, 0, stream>>>(T, wq, temp, P);
  pv_gelu<<<dim3(8, Hh, Bb), 256, 0, stream>>>(P, v, g);
  // out = g @ proj_w^T + proj_b  (fp32 stores, overwrites v)
  gemm_bt<float><<<dim3(4, 256, 1), 256, 0, stream>>>(g, wp, out, Mtok, Cc, Cc,
                                                      proj_b, 0, 0, 0);
}

// Round 5
// 316.068 us; speedup vs baseline: 1.0180x; 1.0180x over previous
//
#include <hip/hip_runtime.h>
#include <hip/hip_bf16.h>

typedef __hip_bfloat16 bf16;
typedef __bf16 bfrag __attribute__((ext_vector_type(8)));   // 8 bf16 = 4 VGPRs (MFMA A/B operand)
typedef float f32x4 __attribute__((ext_vector_type(4)));    // MFMA C/D

#define AS1 __attribute__((address_space(1)))
#define AS3 __attribute__((address_space(3)))

static constexpr int Bb = 8, Nn = 4096, Cc = 512, Hh = 8;
static constexpr int Mtok = Bb * Nn;          // 32768
static constexpr int QKVC = 3 * Cc;           // 1536
// ws layout (NEED = 57,147,392 bytes; proven ws_size >= 59,768,832):
//  xn/g [0, 33554432)          bf16 [32768][512]
//  Gcov [33554432, 41943040)   f32  [8][512][512]
//  Gcvb [41943040, 46137344)   bf16 [8][512][512]
//  T    [46137344, 54525952)   bf16 [8][1024][512]
//  P    [54525952, 55050240)   bf16 [8][8][64][64]
//  wq   [55050240, 56623104)   bf16 [1536][512]
//  wp   [56623104, 57147392)   bf16 [512][512]
static constexpr size_t WS_NEED = 57147392;

__device__ __forceinline__ void gl_lds16(const void* g, void* l) {
  __builtin_amdgcn_global_load_lds((const AS1 void*)g, (AS3 void*)l, 16, 0, 0);
}
__device__ __forceinline__ float gelu_exact(float x) {
  return 0.5f * x * (1.0f + erff(x * 0.70710678118654752f));
}

// ---------------- diagnostic fill (fp32 output) ----------------
__global__ __launch_bounds__(256) void fill_f32(float* o, float val, int n) {
  int i = blockIdx.x * 256 + threadIdx.x;
  if (i < n) o[i] = val;
}

// ---------------- fp32 -> bf16 conversion ----------------
__global__ __launch_bounds__(256) void cvt_f32_bf16(const float* __restrict__ a,
                                                    bf16* __restrict__ o, int n) {
  int i = (blockIdx.x * 256 + threadIdx.x) * 8;
  if (i + 8 <= n) {
    float f[8];
    *(float4*)f       = *(const float4*)(a + i);
    *(float4*)(f + 4) = *(const float4*)(a + i + 4);
    bf16 v[8];
#pragma unroll
    for (int j = 0; j < 8; ++j) v[j] = __float2bfloat16(f[j]);
    *(uint4*)(o + i) = *(uint4*)v;
  }
}

// ---------------- LayerNorm (one wave per token), fp32 in -> bf16 out ----------------
__global__ __launch_bounds__(256) void ln_kernel(const float* __restrict__ x,
                                                 const float* __restrict__ gw,
                                                 const float* __restrict__ bw,
                                                 bf16* __restrict__ xn) {
  int tok  = blockIdx.x * 4 + (threadIdx.x >> 6);
  int lane = threadIdx.x & 63;
  const float* xr = x + (size_t)tok * Cc + lane * 8;
  float f[8];
  *(float4*)f       = *(const float4*)xr;
  *(float4*)(f + 4) = *(const float4*)(xr + 4);
  float s = 0.f;
#pragma unroll
  for (int j = 0; j < 8; ++j) s += f[j];
#pragma unroll
  for (int m = 32; m; m >>= 1) s += __shfl_xor(s, m);
  float mu = s * (1.0f / 512.0f);
  float q = 0.f;
#pragma unroll
  for (int j = 0; j < 8; ++j) { float d = f[j] - mu; q += d * d; }
#pragma unroll
  for (int m = 32; m; m >>= 1) q += __shfl_xor(q, m);
  float rstd = rsqrtf(q * (1.0f / 512.0f) + 1e-5f);
  bf16 o[8];
#pragma unroll
  for (int j = 0; j < 8; ++j)
    o[j] = __float2bfloat16((f[j] - mu) * rstd * gw[lane * 8 + j] + bw[lane * 8 + j]);
  *(uint4*)(xn + (size_t)tok * Cc + lane * 8) = *(uint4*)o;
}

// ------------- GEMM C[M,N] = A[M,K] @ B[N,K]^T, bf16 in, bf16 OR fp32 out, batched -------------
template <typename TC>
__global__ __launch_bounds__(256) void gemm_bt(const bf16* __restrict__ A,
                                               const bf16* __restrict__ B,
                                               TC* __restrict__ C,
                                               int M, int N, int K,
                                               const float* __restrict__ bias,
                                               long sA_z, long sB_z, long sC_z) {
  A += (size_t)blockIdx.z * sA_z;
  B += (size_t)blockIdx.z * sB_z;
  C += (size_t)blockIdx.z * sC_z;
  __shared__ __align__(16) bf16 smem[16384];   // sA[128][64] | sB[128][64]; reused as ct[128][128]
  bf16* sA = smem;
  bf16* sB = smem + 8192;
  int t = threadIdx.x, w = t >> 6, lane = t & 63, fr = lane & 15, quad = lane >> 4;
  int n0 = blockIdx.x * 128, m0 = blockIdx.y * 128;
  int wm = (w >> 1) * 64, wn = (w & 1) * 64;
  f32x4 acc[4][4] = {};

  for (int k0 = 0; k0 < K; k0 += 64) {
    __syncthreads();
#pragma unroll
    for (int c2 = 0; c2 < 4; ++c2) {
      int c = w * 4 + c2;                // 1KB chunk id, 0..15
      int row = c * 8 + (lane >> 3);     // 0..127
      int ke  = (lane & 7) * 8;
      gl_lds16(A + (size_t)(m0 + row) * K + k0 + ke, (char*)sA + c * 1024);
      gl_lds16(B + (size_t)(n0 + row) * K + k0 + ke, (char*)sB + c * 1024);
    }
    __syncthreads();
#pragma unroll
    for (int kk = 0; kk < 64; kk += 32) {
      bfrag af[4], bg[4];
#pragma unroll
      for (int i = 0; i < 4; ++i) af[i] = *(const bfrag*)(sA + (wm + i * 16 + fr) * 64 + kk + quad * 8);
#pragma unroll
      for (int j = 0; j < 4; ++j) bg[j] = *(const bfrag*)(sB + (wn + j * 16 + fr) * 64 + kk + quad * 8);
#pragma unroll
      for (int i = 0; i < 4; ++i)
#pragma unroll
        for (int j = 0; j < 4; ++j)
          acc[i][j] = __builtin_amdgcn_mfma_f32_16x16x32_bf16(af[i], bg[j], acc[i][j], 0, 0, 0);
    }
  }

  if constexpr (__is_same(TC, float)) {
    // direct fp32 stores from C-fragment layout (col=fr, row=quad*4+r)
#pragma unroll
    for (int j = 0; j < 4; ++j) {
      float bj = bias ? bias[n0 + wn + j * 16 + fr] : 0.0f;
#pragma unroll
      for (int i = 0; i < 4; ++i)
#pragma unroll
        for (int r = 0; r < 4; ++r)
          C[(size_t)(m0 + wm + i * 16 + quad * 4 + r) * N + n0 + wn + j * 16 + fr] =
              acc[i][j][r] + bj;
    }
  } else {
    __syncthreads();
    bf16* ct = smem;                      // [128][128]
#pragma unroll
    for (int j = 0; j < 4; ++j) {
      float bj = bias ? bias[n0 + wn + j * 16 + fr] : 0.0f;
#pragma unroll
      for (int i = 0; i < 4; ++i)
#pragma unroll
        for (int r = 0; r < 4; ++r)
          ct[(wm + i * 16 + quad * 4 + r) * 128 + wn + j * 16 + fr] =
              __float2bfloat16(acc[i][j][r] + bj);
    }
    __syncthreads();
#pragma unroll
    for (int r8 = 0; r8 < 8; ++r8) {
      int row = r8 * 16 + (t >> 4);
      int ce  = (t & 15) * 8;
      *(uint4*)(C + (size_t)(m0 + row) * N + n0 + ce) = *(const uint4*)(smem + row * 128 + ce);
    }
  }
}

// ---- Gcov[b] += Xb^T Xb (split-K over tokens, XOR-swizzled LDS transpose, fp32 atomics) ----
// Write path: each thread loads 4 consecutive tokens x 8 channels, transposes in registers,
// writes 8 ds_write_b64 per operand (same swizzled LDS image as the verified b16-scatter
// version: token tk of channel ch lands at position tk ^ (((ch>>3)&7)<<3)).
// Next chunk's global loads are issued during compute (latency hidden under MFMA).
__global__ __launch_bounds__(256) void xtx(const bf16* __restrict__ xn,
                                           float* __restrict__ Gcov) {
  int tile = blockIdx.x;           // 0..15 -> (m0,n0)
  int split = blockIdx.y;          // 0..7, 512 tokens each
  int b = blockIdx.z;
  int m0 = (tile >> 2) * 128, n0 = (tile & 3) * 128;
  int t = threadIdx.x, w = t >> 6, lane = t & 63, fr = lane & 15, quad = lane >> 4;
  int wm = (w >> 1) * 64, wn = (w & 1) * 64;
  __shared__ __align__(16) bf16 sA[8192], sB[8192];   // [128 ch][64 tok], token XOR-swizzled
  f32x4 acc[4][4] = {};
  const bf16* xb = xn + ((size_t)b * Nn + split * 512) * Cc;
  int ch0 = (t & 15) * 8;                  // 8-ch group this thread stages
  int tg  = t >> 4;                        // 4-token group (tokens 4*tg .. 4*tg+3)
  unsigned swz = (unsigned)(t & 7);        // == (ch0>>3)&7
  // byte offset within a channel row for this thread's b64 writes:
  unsigned wpos = (((unsigned)(tg >> 1) ^ swz) * 16u) + (unsigned)(tg & 1) * 8u;
  uint4 va[4], vb[4];
  // prologue: load chunk 0 (tokens 4*tg + j)
#pragma unroll
  for (int j = 0; j < 4; ++j) {
    int tk = tg * 4 + j;
    va[j] = *(const uint4*)(xb + (size_t)tk * Cc + m0 + ch0);
    vb[j] = *(const uint4*)(xb + (size_t)tk * Cc + n0 + ch0);
  }
  for (int kc = 0; kc < 8; ++kc) {
    __syncthreads();                       // prev compute done; LDS reusable
    // register transpose 8ch x 4tok -> 8 x ds_write_b64 per operand
#pragma unroll
    for (int k = 0; k < 4; ++k) {          // channel pair (2k, 2k+1) within the 8-ch group
      unsigned a0 = ((const unsigned*)&va[0])[k], a1 = ((const unsigned*)&va[1])[k];
      unsigned a2 = ((const unsigned*)&va[2])[k], a3 = ((const unsigned*)&va[3])[k];
      uint2 lo = { (a0 & 0xffffu) | (a1 << 16), (a2 & 0xffffu) | (a3 << 16) };
      uint2 hi = { (a0 >> 16) | (a1 & 0xffff0000u), (a2 >> 16) | (a3 & 0xffff0000u) };
      *(uint2*)((char*)sA + (unsigned)(ch0 + 2 * k) * 128 + wpos) = lo;
      *(uint2*)((char*)sA + (unsigned)(ch0 + 2 * k + 1) * 128 + wpos) = hi;
      unsigned b0 = ((const unsigned*)&vb[0])[k], b1 = ((const unsigned*)&vb[1])[k];
      unsigned b2 = ((const unsigned*)&vb[2])[k], b3 = ((const unsigned*)&vb[3])[k];
      uint2 lo2 = { (b0 & 0xffffu) | (b1 << 16), (b2 & 0xffffu) | (b3 << 16) };
      uint2 hi2 = { (b0 >> 16) | (b1 & 0xffff0000u), (b2 >> 16) | (b3 & 0xffff0000u) };
      *(uint2*)((char*)sB + (unsigned)(ch0 + 2 * k) * 128 + wpos) = lo2;
      *(uint2*)((char*)sB + (unsigned)(ch0 + 2 * k + 1) * 128 + wpos) = hi2;
    }
    __syncthreads();                       // tile visible
    if (kc < 7) {                          // prefetch next chunk under compute
      const bf16* xb2 = xb + (size_t)(kc + 1) * 64 * Cc;
#pragma unroll
      for (int j = 0; j < 4; ++j) {
        int tk = tg * 4 + j;
        va[j] = *(const uint4*)(xb2 + (size_t)tk * Cc + m0 + ch0);
        vb[j] = *(const uint4*)(xb2 + (size_t)tk * Cc + n0 + ch0);
      }
    }
#pragma unroll
    for (int s = 0; s < 2; ++s) {
      bfrag af[4], bg[4];
#pragma unroll
      for (int i = 0; i < 4; ++i) {
        int ch = wm + i * 16 + fr;
        int blk = (s * 4 + quad) ^ ((ch >> 3) & 7);
        af[i] = *(const bfrag*)(sA + ch * 64 + blk * 8);
      }
#pragma unroll
      for (int j = 0; j < 4; ++j) {
        int ch = wn + j * 16 + fr;
        int blk = (s * 4 + quad) ^ ((ch >> 3) & 7);
        bg[j] = *(const bfrag*)(sB + ch * 64 + blk * 8);
      }
#pragma unroll
      for (int i = 0; i < 4; ++i)
#pragma unroll
        for (int j = 0; j < 4; ++j)
          acc[i][j] = __builtin_amdgcn_mfma_f32_16x16x32_bf16(af[i], bg[j], acc[i][j], 0, 0, 0);
    }
  }
  float* gb = Gcov + (size_t)b * Cc * Cc;
#pragma unroll
  for (int i = 0; i < 4; ++i)
#pragma unroll
    for (int j = 0; j < 4; ++j)
#pragma unroll
      for (int r = 0; r < 4; ++r)
        atomicAdd(&gb[(size_t)(m0 + wm + i * 16 + quad * 4 + r) * Cc + n0 + wn + j * 16 + fr],
                  acc[i][j][r]);
}

// ---- per (b,h): Gram = T_q @ Wk^T (MFMA, K=512), norms via row-dots, softmax -> P bf16 ----
__global__ __launch_bounds__(256) void gram_softmax(const bf16* __restrict__ T,
                                                    const bf16* __restrict__ wq,
                                                    const float* __restrict__ temp,
                                                    bf16* __restrict__ P) {
  int h = blockIdx.x, b = blockIdx.y;
  int t = threadIdx.x, w = t >> 6, lane = t & 63, fr = lane & 15, quad = lane >> 4;
  const bf16* Tq = T + (size_t)b * 1024 * 512 + (size_t)(h * 64) * 512;
  const bf16* Tk = T + (size_t)b * 1024 * 512 + (size_t)(512 + h * 64) * 512;
  const bf16* Wqh = wq + (size_t)(h * 64) * 512;
  const bf16* Wkh = wq + (size_t)(512 + h * 64) * 512;
  f32x4 acc[4][4] = {};
#pragma unroll
  for (int s = 0; s < 4; ++s) {
    int kb = w * 128 + s * 32 + quad * 8;
    bfrag af[4], bg[4];
#pragma unroll
    for (int i = 0; i < 4; ++i) af[i] = *(const bfrag*)(Tq + (size_t)(i * 16 + fr) * 512 + kb);
#pragma unroll
    for (int j = 0; j < 4; ++j) bg[j] = *(const bfrag*)(Wkh + (size_t)(j * 16 + fr) * 512 + kb);
#pragma unroll
    for (int i = 0; i < 4; ++i)
#pragma unroll
      for (int j = 0; j < 4; ++j)
        acc[i][j] = __builtin_amdgcn_mfma_f32_16x16x32_bf16(af[i], bg[j], acc[i][j], 0, 0, 0);
  }
  __shared__ float parts[4 * 4096];
  __shared__ float nrm[2][4][64];
  __shared__ float nqk[2][64];
#pragma unroll
  for (int i = 0; i < 4; ++i)
#pragma unroll
    for (int j = 0; j < 4; ++j)
#pragma unroll
      for (int r = 0; r < 4; ++r)
        parts[w * 4096 + (i * 16 + quad * 4 + r) * 64 + j * 16 + fr] = acc[i][j][r];
  {
    int d = t & 63, qtr = t >> 6, c0 = qtr * 128;
    float pq = 0.f, pk = 0.f;
#pragma unroll 4
    for (int cc = 0; cc < 16; ++cc) {
      bf16 a[8], ww[8];
      *(uint4*)a  = *(const uint4*)(Tq + (size_t)d * 512 + c0 + cc * 8);
      *(uint4*)ww = *(const uint4*)(Wqh + (size_t)d * 512 + c0 + cc * 8);
#pragma unroll
      for (int j = 0; j < 8; ++j) pq += __bfloat162float(a[j]) * __bfloat162float(ww[j]);
      *(uint4*)a  = *(const uint4*)(Tk + (size_t)d * 512 + c0 + cc * 8);
      *(uint4*)ww = *(const uint4*)(Wkh + (size_t)d * 512 + c0 + cc * 8);
#pragma unroll
      for (int j = 0; j < 8; ++j) pk += __bfloat162float(a[j]) * __bfloat162float(ww[j]);
    }
    nrm[0][qtr][d] = pq;
    nrm[1][qtr][d] = pk;
  }
  __syncthreads();
  if (t < 64) {
    nqk[0][t] = fmaxf(sqrtf(nrm[0][0][t] + nrm[0][1][t] + nrm[0][2][t] + nrm[0][3][t]), 1e-12f);
    nqk[1][t] = fmaxf(sqrtf(nrm[1][0][t] + nrm[1][1][t] + nrm[1][2][t] + nrm[1][3][t]), 1e-12f);
  }
  __syncthreads();
  if (t < 64) {
    int d = t;
    float sc = temp[h] / nqk[0][d];
    float l[64]; float mx = -1e30f;
#pragma unroll
    for (int e = 0; e < 64; ++e) {
      float vsum = parts[d * 64 + e] + parts[4096 + d * 64 + e] +
                   parts[8192 + d * 64 + e] + parts[12288 + d * 64 + e];
      l[e] = vsum * sc / nqk[1][e];
      mx = fmaxf(mx, l[e]);
    }
    float sum = 0.f;
#pragma unroll
    for (int e = 0; e < 64; ++e) { l[e] = expf(l[e] - mx); sum += l[e]; }
    float inv = 1.0f / sum;
    bf16* pr = P + ((size_t)(b * 8 + h) * 64 + d) * 64;
#pragma unroll
    for (int e = 0; e < 64; ++e) pr[e] = __float2bfloat16(l[e] * inv);
  }
}

// ---- out = P @ v, exact GELU, store g[token][C] (bf16) ----
__global__ __launch_bounds__(256) void pv_gelu(const bf16* __restrict__ P,
                                               const bf16* __restrict__ v,
                                               bf16* __restrict__ g) {
  int chunk = blockIdx.x, h = blockIdx.y, b = blockIdx.z;
  int t = threadIdx.x, w = t >> 6, lane = t & 63, fr = lane & 15, quad = lane >> 4;
  const bf16* pb = P + (size_t)(b * 8 + h) * 4096;
  bfrag pf[4][2];
#pragma unroll
  for (int i = 0; i < 4; ++i)
#pragma unroll
    for (int c = 0; c < 2; ++c)
      pf[i][c] = *(const bfrag*)(pb + (i * 16 + fr) * 64 + c * 32 + quad * 8);
#pragma unroll 2
  for (int nt = 0; nt < 8; ++nt) {
    int ntok = chunk * 512 + w * 128 + nt * 16 + fr;
    const bf16* vrow = v + (size_t)(b * Nn + ntok) * Cc + h * 64 + quad * 8;
    bfrag bv0 = *(const bfrag*)(vrow);
    bfrag bv1 = *(const bfrag*)(vrow + 32);
    f32x4 acc[4] = {};
#pragma unroll
    for (int i = 0; i < 4; ++i) {
      acc[i] = __builtin_amdgcn_mfma_f32_16x16x32_bf16(pf[i][0], bv0, acc[i], 0, 0, 0);
      acc[i] = __builtin_amdgcn_mfma_f32_16x16x32_bf16(pf[i][1], bv1, acc[i], 0, 0, 0);
    }
    bf16* grow = g + (size_t)(b * Nn + ntok) * Cc + h * 64;
#pragma unroll
    for (int i = 0; i < 4; ++i) {
      bf16 o[4];
#pragma unroll
      for (int r = 0; r < 4; ++r) o[r] = __float2bfloat16(gelu_exact(acc[i][r]));
      *(uint2*)(grow + i * 16 + quad * 4) = *(uint2*)o;
    }
  }
}

extern "C" void kernel_launch(void* const* d_in, const int* in_sizes, int n_in,
                              void* d_out, int out_size, void* d_ws, size_t ws_size,
                              hipStream_t stream) {
  const float* x      = (const float*)d_in[0];
  const float* ln_g   = (const float*)d_in[1];
  const float* ln_b   = (const float*)d_in[2];
  const float* qkv_w  = (const float*)d_in[3];
  const float* temp   = (const float*)d_in[4];
  const float* proj_w = (const float*)d_in[5];
  const float* proj_b = (const float*)d_in[6];
  float* out = (float*)d_out;                       // fp32 output (reference returns float32)
  char*  ws  = (char*)d_ws;

  // --- runtime guards: silent failure -> measurable absmax signature ---
  const int exp_sizes[7] = {16777216, 512, 512, 786432, 8, 262144, 512};
  bool sizes_ok = (n_in == 7) && (out_size == 16777216);
  if (sizes_ok) for (int i = 0; i < 7; ++i) sizes_ok = sizes_ok && (in_sizes[i] == exp_sizes[i]);
  if (!sizes_ok) {
    fill_f32<<<(16777216 + 255) / 256, 256, 0, stream>>>(out, 500.0f, out_size);
    return;
  }
  if (ws_size < WS_NEED) {
    fill_f32<<<(16777216 + 255) / 256, 256, 0, stream>>>(out, (float)(ws_size >> 20), out_size);
    return;
  }

  bf16*  xn   = (bf16*)ws;                          // reused as g after xtx+vGEMM consume it
  bf16*  g    = (bf16*)ws;
  float* Gcov = (float*)(ws + 33554432);
  bf16*  Gcvb = (bf16*)(ws + 41943040);
  bf16*  T    = (bf16*)(ws + 46137344);
  bf16*  P    = (bf16*)(ws + 54525952);
  bf16*  wq   = (bf16*)(ws + 55050240);
  bf16*  wp   = (bf16*)(ws + 56623104);
  bf16*  v    = (bf16*)d_out;                       // park bf16 v in d_out; dead before final GEMM

  cvt_f32_bf16<<<384, 256, 0, stream>>>(qkv_w, wq, QKVC * Cc);
  cvt_f32_bf16<<<128, 256, 0, stream>>>(proj_w, wp, Cc * Cc);
  hipMemsetAsync(Gcov, 0, (size_t)Bb * Cc * Cc * sizeof(float), stream);
  ln_kernel<<<Mtok / 4, 256, 0, stream>>>(x, ln_g, ln_b, xn);
  // v = xn @ Wv^T (Wv = qkv_w rows 1024..1535)
  gemm_bt<bf16><<<dim3(4, 256, 1), 256, 0, stream>>>(xn, wq + 1024 * 512, v, Mtok, Cc, Cc,
                                                     nullptr, 0, 0, 0);
  xtx<<<dim3(16, 8, 8), 256, 0, stream>>>(xn, Gcov);
  cvt_f32_bf16<<<1024, 256, 0, stream>>>(Gcov, Gcvb, Bb * Cc * Cc);
  // T[b] = Wqk @ Gcov[b]  (Gcov symmetric => @Gcov^T == @Gcov)
  gemm_bt<bf16><<<dim3(4, 8, 8), 256, 0, stream>>>(wq, Gcvb, T, 1024, Cc, Cc,
                                                   nullptr, 0, (long)Cc * Cc, (long)1024 * Cc);
  gram_softmax<<<dim3(Hh, Bb), 256, 0, stream>>>(T, wq, temp, P);
  pv_gelu<<<dim3(8, Hh, Bb), 256, 0, stream>>>(P, v, g);
  // out = g @ proj_w^T + proj_b  (fp32 stores, overwrites v)
  gemm_bt<float><<<dim3(4, 256, 1), 256, 0, stream>>>(g, wp, out, Mtok, Cc, Cc,
                                                      proj_b, 0, 0, 0);
}

// Round 7
// 291.117 us; speedup vs baseline: 1.1053x; 1.0857x over previous
//
#include <hip/hip_runtime.h>
#include <hip/hip_bf16.h>

typedef __hip_bfloat16 bf16;
typedef __bf16 bfrag __attribute__((ext_vector_type(8)));   // 8 bf16 = 4 VGPRs (MFMA A/B operand)
typedef float f32x4 __attribute__((ext_vector_type(4)));    // MFMA C/D

#define AS1 __attribute__((address_space(1)))
#define AS3 __attribute__((address_space(3)))

static constexpr int Bb = 8, Nn = 4096, Cc = 512, Hh = 8;
static constexpr int Mtok = Bb * Nn;          // 32768
static constexpr int QKVC = 3 * Cc;           // 1536
// ws layout (NEED = 57,147,392 bytes; proven ws_size >= 59,768,832):
//  xn/g [0, 33554432)          bf16 [32768][512]
//  Gcov [33554432, 41943040)   f32  [8][512][512]
//  Gcvb [41943040, 46137344)   bf16 [8][512][512]
//  T    [46137344, 54525952)   bf16 [8][1024][512]
//  P    [54525952, 55050240)   bf16 [8][8][64][64]
//  wq   [55050240, 56623104)   bf16 [1536][512]
//  wp   [56623104, 57147392)   bf16 [512][512]
static constexpr size_t WS_NEED = 57147392;

__device__ __forceinline__ void gl_lds16(const void* g, void* l) {
  __builtin_amdgcn_global_load_lds((const AS1 void*)g, (AS3 void*)l, 16, 0, 0);
}
__device__ __forceinline__ float gelu_exact(float x) {
  return 0.5f * x * (1.0f + erff(x * 0.70710678118654752f));
}
// 3-bit rotate-right-by-1: bijection used for LDS slot swizzle (conflict-free reads AND writes)
__device__ __forceinline__ int g3(int x) { return ((x & 1) << 2) | (x >> 1); }

// ---------------- diagnostic fill (fp32 output) ----------------
__global__ __launch_bounds__(256) void fill_f32(float* o, float val, int n) {
  int i = blockIdx.x * 256 + threadIdx.x;
  if (i < n) o[i] = val;
}

// ---------------- fp32 -> bf16 conversion ----------------
__global__ __launch_bounds__(256) void cvt_f32_bf16(const float* __restrict__ a,
                                                    bf16* __restrict__ o, int n) {
  int i = (blockIdx.x * 256 + threadIdx.x) * 8;
  if (i + 8 <= n) {
    float f[8];
    *(float4*)f       = *(const float4*)(a + i);
    *(float4*)(f + 4) = *(const float4*)(a + i + 4);
    bf16 v[8];
#pragma unroll
    for (int j = 0; j < 8; ++j) v[j] = __float2bfloat16(f[j]);
    *(uint4*)(o + i) = *(uint4*)v;
  }
}

// ---- Gcov (upper-tri tiles, fp32) -> Gcvb (full, bf16); lower tiles mirrored via LDS ----
__global__ __launch_bounds__(256) void cvt_mirror(const float* __restrict__ Gcov,
                                                  bf16* __restrict__ Gcvb) {
  int tile = blockIdx.x, b = blockIdx.y;
  int ti = tile >> 2, tj = tile & 3;
  int t = threadIdx.x;
  const float* gb = Gcov + (size_t)b * Cc * Cc;
  bf16* ob = Gcvb + (size_t)b * Cc * Cc;
  if (ti <= tj) {
    // direct convert, coalesced
#pragma unroll
    for (int r8 = 0; r8 < 8; ++r8) {
      int row = r8 * 16 + (t >> 4), col = (t & 15) * 8;
      const float* src = gb + (size_t)(ti * 128 + row) * Cc + tj * 128 + col;
      float f[8];
      *(float4*)f       = *(const float4*)src;
      *(float4*)(f + 4) = *(const float4*)(src + 4);
      bf16 v[8];
#pragma unroll
      for (int j = 0; j < 8; ++j) v[j] = __float2bfloat16(f[j]);
      *(uint4*)(ob + (size_t)(ti * 128 + row) * Cc + tj * 128 + col) = *(uint4*)v;
    }
  } else {
    // mirror: read computed tile (tj,ti) coalesced, transpose through LDS, write (ti,tj)
    __shared__ bf16 ls[128][136];          // pad 8 -> row stride 272B (16B-aligned)
#pragma unroll
    for (int r8 = 0; r8 < 8; ++r8) {
      int srow = r8 * 16 + (t >> 4), scol = (t & 15) * 8;
      const float* src = gb + (size_t)(tj * 128 + srow) * Cc + ti * 128 + scol;
      float f[8];
      *(float4*)f       = *(const float4*)src;
      *(float4*)(f + 4) = *(const float4*)(src + 4);
      bf16 v[8];
#pragma unroll
      for (int j = 0; j < 8; ++j) v[j] = __float2bfloat16(f[j]);
      *(uint4*)&ls[srow][scol] = *(uint4*)v;
    }
    __syncthreads();
#pragma unroll
    for (int r8 = 0; r8 < 8; ++r8) {
      int orow = r8 * 16 + (t >> 4), ocol = (t & 15) * 8;
      bf16 v[8];
#pragma unroll
      for (int u = 0; u < 8; ++u) v[u] = ls[ocol + u][orow];
      *(uint4*)(ob + (size_t)(ti * 128 + orow) * Cc + tj * 128 + ocol) = *(uint4*)v;
    }
  }
}

// ---------------- LayerNorm (one wave per token), fp32 in -> bf16 out ----------------
__global__ __launch_bounds__(256) void ln_kernel(const float* __restrict__ x,
                                                 const float* __restrict__ gw,
                                                 const float* __restrict__ bw,
                                                 bf16* __restrict__ xn) {
  int tok  = blockIdx.x * 4 + (threadIdx.x >> 6);
  int lane = threadIdx.x & 63;
  const float* xr = x + (size_t)tok * Cc + lane * 8;
  float f[8];
  *(float4*)f       = *(const float4*)xr;
  *(float4*)(f + 4) = *(const float4*)(xr + 4);
  float s = 0.f;
#pragma unroll
  for (int j = 0; j < 8; ++j) s += f[j];
#pragma unroll
  for (int m = 32; m; m >>= 1) s += __shfl_xor(s, m);
  float mu = s * (1.0f / 512.0f);
  float q = 0.f;
#pragma unroll
  for (int j = 0; j < 8; ++j) { float d = f[j] - mu; q += d * d; }
#pragma unroll
  for (int m = 32; m; m >>= 1) q += __shfl_xor(q, m);
  float rstd = rsqrtf(q * (1.0f / 512.0f) + 1e-5f);
  bf16 o[8];
#pragma unroll
  for (int j = 0; j < 8; ++j)
    o[j] = __float2bfloat16((f[j] - mu) * rstd * gw[lane * 8 + j] + bw[lane * 8 + j]);
  *(uint4*)(xn + (size_t)tok * Cc + lane * 8) = *(uint4*)o;
}

// ------------- GEMM C[M,N] = A[M,K] @ B[N,K]^T, bf16 in, bf16 OR fp32 out, batched -------------
template <typename TC>
__global__ __launch_bounds__(256) void gemm_bt(const bf16* __restrict__ A,
                                               const bf16* __restrict__ B,
                                               TC* __restrict__ C,
                                               int M, int N, int K,
                                               const float* __restrict__ bias,
                                               long sA_z, long sB_z, long sC_z) {
  A += (size_t)blockIdx.z * sA_z;
  B += (size_t)blockIdx.z * sB_z;
  C += (size_t)blockIdx.z * sC_z;
  __shared__ __align__(16) bf16 smem[16384];   // sA[128][64] | sB[128][64]; reused as ct[128][128]
  bf16* sA = smem;
  bf16* sB = smem + 8192;
  int t = threadIdx.x, w = t >> 6, lane = t & 63, fr = lane & 15, quad = lane >> 4;
  int n0 = blockIdx.x * 128, m0 = blockIdx.y * 128;
  int wm = (w >> 1) * 64, wn = (w & 1) * 64;
  f32x4 acc[4][4] = {};

  for (int k0 = 0; k0 < K; k0 += 64) {
    __syncthreads();
#pragma unroll
    for (int c2 = 0; c2 < 4; ++c2) {
      int c = w * 4 + c2;                // 1KB chunk id, 0..15
      int row = c * 8 + (lane >> 3);     // 0..127
      int ke  = (lane & 7) * 8;
      gl_lds16(A + (size_t)(m0 + row) * K + k0 + ke, (char*)sA + c * 1024);
      gl_lds16(B + (size_t)(n0 + row) * K + k0 + ke, (char*)sB + c * 1024);
    }
    __syncthreads();
#pragma unroll
    for (int kk = 0; kk < 64; kk += 32) {
      bfrag af[4], bg[4];
#pragma unroll
      for (int i = 0; i < 4; ++i) af[i] = *(const bfrag*)(sA + (wm + i * 16 + fr) * 64 + kk + quad * 8);
#pragma unroll
      for (int j = 0; j < 4; ++j) bg[j] = *(const bfrag*)(sB + (wn + j * 16 + fr) * 64 + kk + quad * 8);
#pragma unroll
      for (int i = 0; i < 4; ++i)
#pragma unroll
        for (int j = 0; j < 4; ++j)
          acc[i][j] = __builtin_amdgcn_mfma_f32_16x16x32_bf16(af[i], bg[j], acc[i][j], 0, 0, 0);
    }
  }

  if constexpr (__is_same(TC, float)) {
    // direct fp32 stores from C-fragment layout (col=fr, row=quad*4+r)
#pragma unroll
    for (int j = 0; j < 4; ++j) {
      float bj = bias ? bias[n0 + wn + j * 16 + fr] : 0.0f;
#pragma unroll
      for (int i = 0; i < 4; ++i)
#pragma unroll
        for (int r = 0; r < 4; ++r)
          C[(size_t)(m0 + wm + i * 16 + quad * 4 + r) * N + n0 + wn + j * 16 + fr] =
              acc[i][j][r] + bj;
    }
  } else {
    __syncthreads();
    bf16* ct = smem;                      // [128][128]
#pragma unroll
    for (int j = 0; j < 4; ++j) {
      float bj = bias ? bias[n0 + wn + j * 16 + fr] : 0.0f;
#pragma unroll
      for (int i = 0; i < 4; ++i)
#pragma unroll
        for (int r = 0; r < 4; ++r)
          ct[(wm + i * 16 + quad * 4 + r) * 128 + wn + j * 16 + fr] =
              __float2bfloat16(acc[i][j][r] + bj);
    }
    __syncthreads();
#pragma unroll
    for (int r8 = 0; r8 < 8; ++r8) {
      int row = r8 * 16 + (t >> 4);
      int ce  = (t & 15) * 8;
      *(uint4*)(C + (size_t)(m0 + row) * N + n0 + ce) = *(const uint4*)(smem + row * 128 + ce);
    }
  }
}

// ---- Gcov[b] += Xb^T Xb — upper-triangle tiles only (Gram is symmetric; mirror in cvt_mirror).
// Register-transpose staging (8x ds_write_b64/operand), g3 slot swizzle => conflict-free
// LDS reads AND writes. Prefetch next chunk under compute. XCD-chunked block swizzle.
__global__ __launch_bounds__(256) void xtx(const bf16* __restrict__ xn,
                                           float* __restrict__ Gcov) {
  // grid = 640 = 8 XCDs * 80; map so the 10 tiles of one (split,b) share an XCD's L2
  int flat = blockIdx.x;
  int idx  = (flat & 7) * 80 + (flat >> 3);
  int tile = idx % 10;
  int sb   = idx / 10;
  int split = sb & 7, b = sb >> 3;
  int tm = tile < 4 ? 0 : tile < 7 ? 1 : tile < 9 ? 2 : 3;
  int tn = tile < 4 ? tile : tile < 7 ? tile - 3 : tile < 9 ? tile - 5 : 3;
  int m0 = tm * 128, n0 = tn * 128;
  bool diag = (m0 == n0);
  int t = threadIdx.x, w = t >> 6, lane = t & 63, fr = lane & 15, quad = lane >> 4;
  int wm = (w >> 1) * 64, wn = (w & 1) * 64;
  __shared__ __align__(16) bf16 sA[8192], sB[8192];   // [128 ch][64 tok], g3-swizzled slots
  const bf16* sBp = diag ? sA : sB;
  f32x4 acc[4][4] = {};
  const bf16* xb = xn + ((size_t)b * Nn + split * 512) * Cc;
  int ch0 = (t & 15) * 8;                  // 8-ch group this thread stages
  int tg  = t >> 4;                        // 4-token group (tokens 4*tg .. 4*tg+3)
  int swz = g3(t & 7);                     // g3((ch0>>3)&7)
  // byte offset within a channel row for this thread's b64 writes:
  unsigned wpos = (((unsigned)((tg >> 1) ^ swz)) * 16u) + (unsigned)(tg & 1) * 8u;
  uint4 va[4], vb[4];
  // prologue: load chunk 0 (tokens 4*tg + j)
#pragma unroll
  for (int j = 0; j < 4; ++j) {
    int tk = tg * 4 + j;
    va[j] = *(const uint4*)(xb + (size_t)tk * Cc + m0 + ch0);
    if (!diag) vb[j] = *(const uint4*)(xb + (size_t)tk * Cc + n0 + ch0);
  }
  for (int kc = 0; kc < 8; ++kc) {
    __syncthreads();                       // prev compute done; LDS reusable
    // register transpose 8ch x 4tok -> 8 x ds_write_b64 per operand
#pragma unroll
    for (int k = 0; k < 4; ++k) {          // channel pair (2k, 2k+1) within the 8-ch group
      unsigned a0 = ((const unsigned*)&va[0])[k], a1 = ((const unsigned*)&va[1])[k];
      unsigned a2 = ((const unsigned*)&va[2])[k], a3 = ((const unsigned*)&va[3])[k];
      uint2 lo = { (a0 & 0xffffu) | (a1 << 16), (a2 & 0xffffu) | (a3 << 16) };
      uint2 hi = { (a0 >> 16) | (a1 & 0xffff0000u), (a2 >> 16) | (a3 & 0xffff0000u) };
      *(uint2*)((char*)sA + (unsigned)(ch0 + 2 * k) * 128 + wpos) = lo;
      *(uint2*)((char*)sA + (unsigned)(ch0 + 2 * k + 1) * 128 + wpos) = hi;
      if (!diag) {
        unsigned b0 = ((const unsigned*)&vb[0])[k], b1 = ((const unsigned*)&vb[1])[k];
        unsigned b2 = ((const unsigned*)&vb[2])[k], b3 = ((const unsigned*)&vb[3])[k];
        uint2 lo2 = { (b0 & 0xffffu) | (b1 << 16), (b2 & 0xffffu) | (b3 << 16) };
        uint2 hi2 = { (b0 >> 16) | (b1 & 0xffff0000u), (b2 >> 16) | (b3 & 0xffff0000u) };
        *(uint2*)((char*)sB + (unsigned)(ch0 + 2 * k) * 128 + wpos) = lo2;
        *(uint2*)((char*)sB + (unsigned)(ch0 + 2 * k + 1) * 128 + wpos) = hi2;
      }
    }
    __syncthreads();                       // tile visible
    if (kc < 7) {                          // prefetch next chunk under compute
      const bf16* xb2 = xb + (size_t)(kc + 1) * 64 * Cc;
#pragma unroll
      for (int j = 0; j < 4; ++j) {
        int tk = tg * 4 + j;
        va[j] = *(const uint4*)(xb2 + (size_t)tk * Cc + m0 + ch0);
        if (!diag) vb[j] = *(const uint4*)(xb2 + (size_t)tk * Cc + n0 + ch0);
      }
    }
#pragma unroll
    for (int s = 0; s < 2; ++s) {
      bfrag af[4], bg[4];
#pragma unroll
      for (int i = 0; i < 4; ++i) {
        int ch = wm + i * 16 + fr;
        int blk = (s * 4 + quad) ^ g3((ch >> 3) & 7);
        af[i] = *(const bfrag*)(sA + ch * 64 + blk * 8);
      }
#pragma unroll
      for (int j = 0; j < 4; ++j) {
        int ch = wn + j * 16 + fr;
        int blk = (s * 4 + quad) ^ g3((ch >> 3) & 7);
        bg[j] = *(const bfrag*)(sBp + ch * 64 + blk * 8);
      }
#pragma unroll
      for (int i = 0; i < 4; ++i)
#pragma unroll
        for (int j = 0; j < 4; ++j)
          acc[i][j] = __builtin_amdgcn_mfma_f32_16x16x32_bf16(af[i], bg[j], acc[i][j], 0, 0, 0);
    }
  }
  float* gb = Gcov + (size_t)b * Cc * Cc;
#pragma unroll
  for (int i = 0; i < 4; ++i)
#pragma unroll
    for (int j = 0; j < 4; ++j)
#pragma unroll
      for (int r = 0; r < 4; ++r)
        atomicAdd(&gb[(size_t)(m0 + wm + i * 16 + quad * 4 + r) * Cc + n0 + wn + j * 16 + fr],
                  acc[i][j][r]);
}

// ---- per (b,h): Gram = T_q @ Wk^T (MFMA, K=512), norms via row-dots, softmax -> P bf16 ----
__global__ __launch_bounds__(256) void gram_softmax(const bf16* __restrict__ T,
                                                    const bf16* __restrict__ wq,
                                                    const float* __restrict__ temp,
                                                    bf16* __restrict__ P) {
  int h = blockIdx.x, b = blockIdx.y;
  int t = threadIdx.x, w = t >> 6, lane = t & 63, fr = lane & 15, quad = lane >> 4;
  const bf16* Tq = T + (size_t)b * 1024 * 512 + (size_t)(h * 64) * 512;
  const bf16* Tk = T + (size_t)b * 1024 * 512 + (size_t)(512 + h * 64) * 512;
  const bf16* Wqh = wq + (size_t)(h * 64) * 512;
  const bf16* Wkh = wq + (size_t)(512 + h * 64) * 512;
  f32x4 acc[4][4] = {};
#pragma unroll
  for (int s = 0; s < 4; ++s) {
    int kb = w * 128 + s * 32 + quad * 8;
    bfrag af[4], bg[4];
#pragma unroll
    for (int i = 0; i < 4; ++i) af[i] = *(const bfrag*)(Tq + (size_t)(i * 16 + fr) * 512 + kb);
#pragma unroll
    for (int j = 0; j < 4; ++j) bg[j] = *(const bfrag*)(Wkh + (size_t)(j * 16 + fr) * 512 + kb);
#pragma unroll
    for (int i = 0; i < 4; ++i)
#pragma unroll
      for (int j = 0; j < 4; ++j)
        acc[i][j] = __builtin_amdgcn_mfma_f32_16x16x32_bf16(af[i], bg[j], acc[i][j], 0, 0, 0);
  }
  __shared__ float parts[4 * 4096];
  __shared__ float nrm[2][4][64];
  __shared__ float nqk[2][64];
#pragma unroll
  for (int i = 0; i < 4; ++i)
#pragma unroll
    for (int j = 0; j < 4; ++j)
#pragma unroll
      for (int r = 0; r < 4; ++r)
        parts[w * 4096 + (i * 16 + quad * 4 + r) * 64 + j * 16 + fr] = acc[i][j][r];
  {
    int d = t & 63, qtr = t >> 6, c0 = qtr * 128;
    float pq = 0.f, pk = 0.f;
#pragma unroll 4
    for (int cc = 0; cc < 16; ++cc) {
      bf16 a[8], ww[8];
      *(uint4*)a  = *(const uint4*)(Tq + (size_t)d * 512 + c0 + cc * 8);
      *(uint4*)ww = *(const uint4*)(Wqh + (size_t)d * 512 + c0 + cc * 8);
#pragma unroll
      for (int j = 0; j < 8; ++j) pq += __bfloat162float(a[j]) * __bfloat162float(ww[j]);
      *(uint4*)a  = *(const uint4*)(Tk + (size_t)d * 512 + c0 + cc * 8);
      *(uint4*)ww = *(const uint4*)(Wkh + (size_t)d * 512 + c0 + cc * 8);
#pragma unroll
      for (int j = 0; j < 8; ++j) pk += __bfloat162float(a[j]) * __bfloat162float(ww[j]);
    }
    nrm[0][qtr][d] = pq;
    nrm[1][qtr][d] = pk;
  }
  __syncthreads();
  if (t < 64) {
    nqk[0][t] = fmaxf(sqrtf(nrm[0][0][t] + nrm[0][1][t] + nrm[0][2][t] + nrm[0][3][t]), 1e-12f);
    nqk[1][t] = fmaxf(sqrtf(nrm[1][0][t] + nrm[1][1][t] + nrm[1][2][t] + nrm[1][3][t]), 1e-12f);
  }
  __syncthreads();
  if (t < 64) {
    int d = t;
    float sc = temp[h] / nqk[0][d];
    float l[64]; float mx = -1e30f;
#pragma unroll
    for (int e = 0; e < 64; ++e) {
      float vsum = parts[d * 64 + e] + parts[4096 + d * 64 + e] +
                   parts[8192 + d * 64 + e] + parts[12288 + d * 64 + e];
      l[e] = vsum * sc / nqk[1][e];
      mx = fmaxf(mx, l[e]);
    }
    float sum = 0.f;
#pragma unroll
    for (int e = 0; e < 64; ++e) { l[e] = expf(l[e] - mx); sum += l[e]; }
    float inv = 1.0f / sum;
    bf16* pr = P + ((size_t)(b * 8 + h) * 64 + d) * 64;
#pragma unroll
    for (int e = 0; e < 64; ++e) pr[e] = __float2bfloat16(l[e] * inv);
  }
}

// ---- out = P @ v, exact GELU, store g[token][C] (bf16) ----
__global__ __launch_bounds__(256) void pv_gelu(const bf16* __restrict__ P,
                                               const bf16* __restrict__ v,
                                               bf16* __restrict__ g) {
  int chunk = blockIdx.x, h = blockIdx.y, b = blockIdx.z;
  int t = threadIdx.x, w = t >> 6, lane = t & 63, fr = lane & 15, quad = lane >> 4;
  const bf16* pb = P + (size_t)(b * 8 + h) * 4096;
  bfrag pf[4][2];
#pragma unroll
  for (int i = 0; i < 4; ++i)
#pragma unroll
    for (int c = 0; c < 2; ++c)
      pf[i][c] = *(const bfrag*)(pb + (i * 16 + fr) * 64 + c * 32 + quad * 8);
#pragma unroll 2
  for (int nt = 0; nt < 8; ++nt) {
    int ntok = chunk * 512 + w * 128 + nt * 16 + fr;
    const bf16* vrow = v + (size_t)(b * Nn + ntok) * Cc + h * 64 + quad * 8;
    bfrag bv0 = *(const bfrag*)(vrow);
    bfrag bv1 = *(const bfrag*)(vrow + 32);
    f32x4 acc[4] = {};
#pragma unroll
    for (int i = 0; i < 4; ++i) {
      acc[i] = __builtin_amdgcn_mfma_f32_16x16x32_bf16(pf[i][0], bv0, acc[i], 0, 0, 0);
      acc[i] = __builtin_amdgcn_mfma_f32_16x16x32_bf16(pf[i][1], bv1, acc[i], 0, 0, 0);
    }
    bf16* grow = g + (size_t)(b * Nn + ntok) * Cc + h * 64;
#pragma unroll
    for (int i = 0; i < 4; ++i) {
      bf16 o[4];
#pragma unroll
      for (int r = 0; r < 4; ++r) o[r] = __float2bfloat16(gelu_exact(acc[i][r]));
      *(uint2*)(grow + i * 16 + quad * 4) = *(uint2*)o;
    }
  }
}

extern "C" void kernel_launch(void* const* d_in, const int* in_sizes, int n_in,
                              void* d_out, int out_size, void* d_ws, size_t ws_size,
                              hipStream_t stream) {
  const float* x      = (const float*)d_in[0];
  const float* ln_g   = (const float*)d_in[1];
  const float* ln_b   = (const float*)d_in[2];
  const float* qkv_w  = (const float*)d_in[3];
  const float* temp   = (const float*)d_in[4];
  const float* proj_w = (const float*)d_in[5];
  const float* proj_b = (const float*)d_in[6];
  float* out = (float*)d_out;                       // fp32 output (reference returns float32)
  char*  ws  = (char*)d_ws;

  // --- runtime guards: silent failure -> measurable absmax signature ---
  const int exp_sizes[7] = {16777216, 512, 512, 786432, 8, 262144, 512};
  bool sizes_ok = (n_in == 7) && (out_size == 16777216);
  if (sizes_ok) for (int i = 0; i < 7; ++i) sizes_ok = sizes_ok && (in_sizes[i] == exp_sizes[i]);
  if (!sizes_ok) {
    fill_f32<<<(16777216 + 255) / 256, 256, 0, stream>>>(out, 500.0f, out_size);
    return;
  }
  if (ws_size < WS_NEED) {
    fill_f32<<<(16777216 + 255) / 256, 256, 0, stream>>>(out, (float)(ws_size >> 20), out_size);
    return;
  }

  bf16*  xn   = (bf16*)ws;                          // reused as g after xtx+vGEMM consume it
  bf16*  g    = (bf16*)ws;
  float* Gcov = (float*)(ws + 33554432);
  bf16*  Gcvb = (bf16*)(ws + 41943040);
  bf16*  T    = (bf16*)(ws + 46137344);
  bf16*  P    = (bf16*)(ws + 54525952);
  bf16*  wq   = (bf16*)(ws + 55050240);
  bf16*  wp   = (bf16*)(ws + 56623104);
  bf16*  v    = (bf16*)d_out;                       // park bf16 v in d_out; dead before final GEMM

  cvt_f32_bf16<<<384, 256, 0, stream>>>(qkv_w, wq, QKVC * Cc);
  cvt_f32_bf16<<<128, 256, 0, stream>>>(proj_w, wp, Cc * Cc);
  hipMemsetAsync(Gcov, 0, (size_t)Bb * Cc * Cc * sizeof(float), stream);
  ln_kernel<<<Mtok / 4, 256, 0, stream>>>(x, ln_g, ln_b, xn);
  // v = xn @ Wv^T (Wv = qkv_w rows 1024..1535)
  gemm_bt<bf16><<<dim3(4, 256, 1), 256, 0, stream>>>(xn, wq + 1024 * 512, v, Mtok, Cc, Cc,
                                                     nullptr, 0, 0, 0);
  xtx<<<640, 256, 0, stream>>>(xn, Gcov);
  cvt_mirror<<<dim3(16, 8), 256, 0, stream>>>(Gcov, Gcvb);
  // T[b] = Wqk @ Gcov[b]  (Gcov symmetric => @Gcov^T == @Gcov)
  gemm_bt<bf16><<<dim3(4, 8, 8), 256, 0, stream>>>(wq, Gcvb, T, 1024, Cc, Cc,
                                                   nullptr, 0, (long)Cc * Cc, (long)1024 * Cc);
  gram_softmax<<<dim3(Hh, Bb), 256, 0, stream>>>(T, wq, temp, P);
  pv_gelu<<<dim3(8, Hh, Bb), 256, 0, stream>>>(P, v, g);
  // out = g @ proj_w^T + proj_b  (fp32 stores, overwrites v)
  gemm_bt<float><<<dim3(4, 256, 1), 256, 0, stream>>>(g, wp, out, Mtok, Cc, Cc,
                                                      proj_b, 0, 0, 0);
}

// Round 9
// 276.026 us; speedup vs baseline: 1.1657x; 1.0547x over previous
//
#include <hip/hip_runtime.h>
#include <hip/hip_bf16.h>

typedef __hip_bfloat16 bf16;
typedef __bf16 bfrag __attribute__((ext_vector_type(8)));   // 8 bf16 = 4 VGPRs (MFMA A/B operand)
typedef float f32x4 __attribute__((ext_vector_type(4)));    // MFMA C/D

#define AS1 __attribute__((address_space(1)))
#define AS3 __attribute__((address_space(3)))

static constexpr int Bb = 8, Nn = 4096, Cc = 512, Hh = 8;
static constexpr int Mtok = Bb * Nn;          // 32768
static constexpr int QKVC = 3 * Cc;           // 1536
// ws layout (NEED = 57,147,392 bytes; proven ws_size >= 59,768,832):
//  xn/g [0, 33554432)          bf16 [32768][512]
//  Gcov [33554432, 41943040)   f32  [8][512][512]
//  Gcvb [41943040, 46137344)   bf16 [8][512][512]
//  T    [46137344, 54525952)   bf16 [8][1024][512]
//  P    [54525952, 55050240)   bf16 [8][8][64][64]
//  wq   [55050240, 56623104)   bf16 [1536][512]
//  wp   [56623104, 57147392)   bf16 [512][512]
static constexpr size_t WS_NEED = 57147392;

__device__ __forceinline__ void gl_lds16(const void* g, void* l) {
  __builtin_amdgcn_global_load_lds((const AS1 void*)g, (AS3 void*)l, 16, 0, 0);
}
__device__ __forceinline__ float gelu_exact(float x) {
  return 0.5f * x * (1.0f + erff(x * 0.70710678118654752f));
}
// 3-bit rotate-right-by-1: bijection used for LDS slot swizzle (conflict-free reads AND writes)
__device__ __forceinline__ int g3(int x) { return ((x & 1) << 2) | (x >> 1); }

// ---------------- diagnostic fill (fp32 output) ----------------
__global__ __launch_bounds__(256) void fill_f32(float* o, float val, int n) {
  int i = blockIdx.x * 256 + threadIdx.x;
  if (i < n) o[i] = val;
}

// ---------------- fp32 -> bf16 conversion ----------------
__global__ __launch_bounds__(256) void cvt_f32_bf16(const float* __restrict__ a,
                                                    bf16* __restrict__ o, int n) {
  int i = (blockIdx.x * 256 + threadIdx.x) * 8;
  if (i + 8 <= n) {
    float f[8];
    *(float4*)f       = *(const float4*)(a + i);
    *(float4*)(f + 4) = *(const float4*)(a + i + 4);
    bf16 v[8];
#pragma unroll
    for (int j = 0; j < 8; ++j) v[j] = __float2bfloat16(f[j]);
    *(uint4*)(o + i) = *(uint4*)v;
  }
}

// ---- Gcov (upper-tri tiles, fp32) -> Gcvb (full, bf16); lower tiles mirrored via LDS ----
__global__ __launch_bounds__(256) void cvt_mirror(const float* __restrict__ Gcov,
                                                  bf16* __restrict__ Gcvb) {
  int tile = blockIdx.x, b = blockIdx.y;
  int ti = tile >> 2, tj = tile & 3;
  int t = threadIdx.x;
  const float* gb = Gcov + (size_t)b * Cc * Cc;
  bf16* ob = Gcvb + (size_t)b * Cc * Cc;
  if (ti <= tj) {
    // direct convert, coalesced
#pragma unroll
    for (int r8 = 0; r8 < 8; ++r8) {
      int row = r8 * 16 + (t >> 4), col = (t & 15) * 8;
      const float* src = gb + (size_t)(ti * 128 + row) * Cc + tj * 128 + col;
      float f[8];
      *(float4*)f       = *(const float4*)src;
      *(float4*)(f + 4) = *(const float4*)(src + 4);
      bf16 v[8];
#pragma unroll
      for (int j = 0; j < 8; ++j) v[j] = __float2bfloat16(f[j]);
      *(uint4*)(ob + (size_t)(ti * 128 + row) * Cc + tj * 128 + col) = *(uint4*)v;
    }
  } else {
    // mirror: read computed tile (tj,ti) coalesced, transpose through LDS, write (ti,tj)
    __shared__ bf16 ls[128][136];          // pad 8 -> row stride 272B (16B-aligned)
#pragma unroll
    for (int r8 = 0; r8 < 8; ++r8) {
      int srow = r8 * 16 + (t >> 4), scol = (t & 15) * 8;
      const float* src = gb + (size_t)(tj * 128 + srow) * Cc + ti * 128 + scol;
      float f[8];
      *(float4*)f       = *(const float4*)src;
      *(float4*)(f + 4) = *(const float4*)(src + 4);
      bf16 v[8];
#pragma unroll
      for (int j = 0; j < 8; ++j) v[j] = __float2bfloat16(f[j]);
      *(uint4*)&ls[srow][scol] = *(uint4*)v;
    }
    __syncthreads();
#pragma unroll
    for (int r8 = 0; r8 < 8; ++r8) {
      int orow = r8 * 16 + (t >> 4), ocol = (t & 15) * 8;
      bf16 v[8];
#pragma unroll
      for (int u = 0; u < 8; ++u) v[u] = ls[ocol + u][orow];
      *(uint4*)(ob + (size_t)(ti * 128 + orow) * Cc + tj * 128 + ocol) = *(uint4*)v;
    }
  }
}

// ---------------- LayerNorm (one wave per token), fp32 in -> bf16 out ----------------
__global__ __launch_bounds__(256) void ln_kernel(const float* __restrict__ x,
                                                 const float* __restrict__ gw,
                                                 const float* __restrict__ bw,
                                                 bf16* __restrict__ xn) {
  int tok  = blockIdx.x * 4 + (threadIdx.x >> 6);
  int lane = threadIdx.x & 63;
  const float* xr = x + (size_t)tok * Cc + lane * 8;
  float f[8];
  *(float4*)f       = *(const float4*)xr;
  *(float4*)(f + 4) = *(const float4*)(xr + 4);
  float s = 0.f;
#pragma unroll
  for (int j = 0; j < 8; ++j) s += f[j];
#pragma unroll
  for (int m = 32; m; m >>= 1) s += __shfl_xor(s, m);
  float mu = s * (1.0f / 512.0f);
  float q = 0.f;
#pragma unroll
  for (int j = 0; j < 8; ++j) { float d = f[j] - mu; q += d * d; }
#pragma unroll
  for (int m = 32; m; m >>= 1) q += __shfl_xor(q, m);
  float rstd = rsqrtf(q * (1.0f / 512.0f) + 1e-5f);
  bf16 o[8];
#pragma unroll
  for (int j = 0; j < 8; ++j)
    o[j] = __float2bfloat16((f[j] - mu) * rstd * gw[lane * 8 + j] + bw[lane * 8 + j]);
  *(uint4*)(xn + (size_t)tok * Cc + lane * 8) = *(uint4*)o;
}

// ------------- GEMM C[M,N] = A[M,K] @ B[N,K]^T, bf16 in, bf16 OR fp32 out, batched -------------
// LDS slot swizzle via pre-swizzled global_load_lds source (rule: swizzle source+read, dest
// linear): slot s of row r holds global column (s^(r&7))*8 -> fragment reads spread 64 lanes
// over all 32 banks (8-deep = b128 bandwidth floor; was 16-deep on 16 banks).
// SWZ: XCD-chunked block swizzle (1024 blocks = 8 XCDs x 128): same-A-panel blocks share an L2.
template <typename TC, bool SWZ>
__global__ __launch_bounds__(256) void gemm_bt(const bf16* __restrict__ A,
                                               const bf16* __restrict__ B,
                                               TC* __restrict__ C,
                                               int M, int N, int K,
                                               const float* __restrict__ bias,
                                               long sA_z, long sB_z, long sC_z) {
  A += (size_t)blockIdx.z * sA_z;
  B += (size_t)blockIdx.z * sB_z;
  C += (size_t)blockIdx.z * sC_z;
  __shared__ __align__(16) bf16 smem[16384];   // sA[128][64] | sB[128][64]; reused as ct[128][128]
  bf16* sA = smem;
  bf16* sB = smem + 8192;
  int t = threadIdx.x, w = t >> 6, lane = t & 63, fr = lane & 15, quad = lane >> 4;
  int n0, m0;
  if constexpr (SWZ) {
    int flat = blockIdx.y * 4 + blockIdx.x;    // 0..1023
    int idx  = (flat & 7) * 128 + (flat >> 3); // XCD k owns idx [128k,128k+128)
    n0 = (idx & 3) * 128;
    m0 = (idx >> 2) * 128;
  } else {
    n0 = blockIdx.x * 128;
    m0 = blockIdx.y * 128;
  }
  int wm = (w >> 1) * 64, wn = (w & 1) * 64;
  f32x4 acc[4][4] = {};

  for (int k0 = 0; k0 < K; k0 += 64) {
    __syncthreads();
#pragma unroll
    for (int c2 = 0; c2 < 4; ++c2) {
      int c = w * 4 + c2;                // 1KB chunk id, 0..15
      int row = c * 8 + (lane >> 3);     // 0..127
      int ke  = ((lane & 7) ^ (lane >> 3)) * 8;   // pre-swizzled source slot
      gl_lds16(A + (size_t)(m0 + row) * K + k0 + ke, (char*)sA + c * 1024);
      gl_lds16(B + (size_t)(n0 + row) * K + k0 + ke, (char*)sB + c * 1024);
    }
    __syncthreads();
#pragma unroll
    for (int kk = 0; kk < 64; kk += 32) {
      bfrag af[4], bg[4];
#pragma unroll
      for (int i = 0; i < 4; ++i)
        af[i] = *(const bfrag*)(sA + (wm + i * 16 + fr) * 64 +
                                ((((kk >> 3) + quad) ^ (fr & 7)) * 8));
#pragma unroll
      for (int j = 0; j < 4; ++j)
        bg[j] = *(const bfrag*)(sB + (wn + j * 16 + fr) * 64 +
                                ((((kk >> 3) + quad) ^ (fr & 7)) * 8));
#pragma unroll
      for (int i = 0; i < 4; ++i)
#pragma unroll
        for (int j = 0; j < 4; ++j)
          acc[i][j] = __builtin_amdgcn_mfma_f32_16x16x32_bf16(af[i], bg[j], acc[i][j], 0, 0, 0);
    }
  }

  if constexpr (__is_same(TC, float)) {
    // direct fp32 stores from C-fragment layout (col=fr, row=quad*4+r)
#pragma unroll
    for (int j = 0; j < 4; ++j) {
      float bj = bias ? bias[n0 + wn + j * 16 + fr] : 0.0f;
#pragma unroll
      for (int i = 0; i < 4; ++i)
#pragma unroll
        for (int r = 0; r < 4; ++r)
          C[(size_t)(m0 + wm + i * 16 + quad * 4 + r) * N + n0 + wn + j * 16 + fr] =
              acc[i][j][r] + bj;
    }
  } else {
    __syncthreads();
    bf16* ct = smem;                      // [128][128]
#pragma unroll
    for (int j = 0; j < 4; ++j) {
      float bj = bias ? bias[n0 + wn + j * 16 + fr] : 0.0f;
#pragma unroll
      for (int i = 0; i < 4; ++i)
#pragma unroll
        for (int r = 0; r < 4; ++r)
          ct[(wm + i * 16 + quad * 4 + r) * 128 + wn + j * 16 + fr] =
              __float2bfloat16(acc[i][j][r] + bj);
    }
    __syncthreads();
#pragma unroll
    for (int r8 = 0; r8 < 8; ++r8) {
      int row = r8 * 16 + (t >> 4);
      int ce  = (t & 15) * 8;
      *(uint4*)(C + (size_t)(m0 + row) * N + n0 + ce) = *(const uint4*)(smem + row * 128 + ce);
    }
  }
}

// ---- Gcov[b] += Xb^T Xb — upper-triangle tiles only (Gram is symmetric; mirror in cvt_mirror).
// Register-transpose staging (8x ds_write_b64/operand), g3 slot swizzle => conflict-free
// LDS reads AND writes. Prefetch next chunk under compute. XCD-chunked block swizzle.
__global__ __launch_bounds__(256) void xtx(const bf16* __restrict__ xn,
                                           float* __restrict__ Gcov) {
  // grid = 640 = 8 XCDs * 80; map so the 10 tiles of one (split,b) share an XCD's L2
  int flat = blockIdx.x;
  int idx  = (flat & 7) * 80 + (flat >> 3);
  int tile = idx % 10;
  int sb   = idx / 10;
  int split = sb & 7, b = sb >> 3;
  int tm = tile < 4 ? 0 : tile < 7 ? 1 : tile < 9 ? 2 : 3;
  int tn = tile < 4 ? tile : tile < 7 ? tile - 3 : tile < 9 ? tile - 5 : 3;
  int m0 = tm * 128, n0 = tn * 128;
  bool diag = (m0 == n0);
  int t = threadIdx.x, w = t >> 6, lane = t & 63, fr = lane & 15, quad = lane >> 4;
  int wm = (w >> 1) * 64, wn = (w & 1) * 64;
  __shared__ __align__(16) bf16 sA[8192], sB[8192];   // [128 ch][64 tok], g3-swizzled slots
  const bf16* sBp = diag ? sA : sB;
  f32x4 acc[4][4] = {};
  const bf16* xb = xn + ((size_t)b * Nn + split * 512) * Cc;
  int ch0 = (t & 15) * 8;                  // 8-ch group this thread stages
  int tg  = t >> 4;                        // 4-token group (tokens 4*tg .. 4*tg+3)
  int swz = g3(t & 7);                     // g3((ch0>>3)&7)
  // byte offset within a channel row for this thread's b64 writes:
  unsigned wpos = (((unsigned)((tg >> 1) ^ swz)) * 16u) + (unsigned)(tg & 1) * 8u;
  uint4 va[4], vb[4];
  // prologue: load chunk 0 (tokens 4*tg + j)
#pragma unroll
  for (int j = 0; j < 4; ++j) {
    int tk = tg * 4 + j;
    va[j] = *(const uint4*)(xb + (size_t)tk * Cc + m0 + ch0);
    if (!diag) vb[j] = *(const uint4*)(xb + (size_t)tk * Cc + n0 + ch0);
  }
  for (int kc = 0; kc < 8; ++kc) {
    __syncthreads();                       // prev compute done; LDS reusable
    // register transpose 8ch x 4tok -> 8 x ds_write_b64 per operand
#pragma unroll
    for (int k = 0; k < 4; ++k) {          // channel pair (2k, 2k+1) within the 8-ch group
      unsigned a0 = ((const unsigned*)&va[0])[k], a1 = ((const unsigned*)&va[1])[k];
      unsigned a2 = ((const unsigned*)&va[2])[k], a3 = ((const unsigned*)&va[3])[k];
      uint2 lo = { (a0 & 0xffffu) | (a1 << 16), (a2 & 0xffffu) | (a3 << 16) };
      uint2 hi = { (a0 >> 16) | (a1 & 0xffff0000u), (a2 >> 16) | (a3 & 0xffff0000u) };
      *(uint2*)((char*)sA + (unsigned)(ch0 + 2 * k) * 128 + wpos) = lo;
      *(uint2*)((char*)sA + (unsigned)(ch0 + 2 * k + 1) * 128 + wpos) = hi;
      if (!diag) {
        unsigned b0 = ((const unsigned*)&vb[0])[k], b1 = ((const unsigned*)&vb[1])[k];
        unsigned b2 = ((const unsigned*)&vb[2])[k], b3 = ((const unsigned*)&vb[3])[k];
        uint2 lo2 = { (b0 & 0xffffu) | (b1 << 16), (b2 & 0xffffu) | (b3 << 16) };
        uint2 hi2 = { (b0 >> 16) | (b1 & 0xffff0000u), (b2 >> 16) | (b3 & 0xffff0000u) };
        *(uint2*)((char*)sB + (unsigned)(ch0 + 2 * k) * 128 + wpos) = lo2;
        *(uint2*)((char*)sB + (unsigned)(ch0 + 2 * k + 1) * 128 + wpos) = hi2;
      }
    }
    __syncthreads();                       // tile visible
    if (kc < 7) {                          // prefetch next chunk under compute
      const bf16* xb2 = xb + (size_t)(kc + 1) * 64 * Cc;
#pragma unroll
      for (int j = 0; j < 4; ++j) {
        int tk = tg * 4 + j;
        va[j] = *(const uint4*)(xb2 + (size_t)tk * Cc + m0 + ch0);
        if (!diag) vb[j] = *(const uint4*)(xb2 + (size_t)tk * Cc + n0 + ch0);
      }
    }
#pragma unroll
    for (int s = 0; s < 2; ++s) {
      bfrag af[4], bg[4];
#pragma unroll
      for (int i = 0; i < 4; ++i) {
        int ch = wm + i * 16 + fr;
        int blk = (s * 4 + quad) ^ g3((ch >> 3) & 7);
        af[i] = *(const bfrag*)(sA + ch * 64 + blk * 8);
      }
#pragma unroll
      for (int j = 0; j < 4; ++j) {
        int ch = wn + j * 16 + fr;
        int blk = (s * 4 + quad) ^ g3((ch >> 3) & 7);
        bg[j] = *(const bfrag*)(sBp + ch * 64 + blk * 8);
      }
#pragma unroll
      for (int i = 0; i < 4; ++i)
#pragma unroll
        for (int j = 0; j < 4; ++j)
          acc[i][j] = __builtin_amdgcn_mfma_f32_16x16x32_bf16(af[i], bg[j], acc[i][j], 0, 0, 0);
    }
  }
  float* gb = Gcov + (size_t)b * Cc * Cc;
#pragma unroll
  for (int i = 0; i < 4; ++i)
#pragma unroll
    for (int j = 0; j < 4; ++j)
#pragma unroll
      for (int r = 0; r < 4; ++r)
        atomicAdd(&gb[(size_t)(m0 + wm + i * 16 + quad * 4 + r) * Cc + n0 + wn + j * 16 + fr],
                  acc[i][j][r]);
}

// ---- per (b,h): Gram = T_q @ Wk^T (MFMA, K=512), norms via row-dots, softmax -> P bf16 ----
__global__ __launch_bounds__(256) void gram_softmax(const bf16* __restrict__ T,
                                                    const bf16* __restrict__ wq,
                                                    const float* __restrict__ temp,
                                                    bf16* __restrict__ P) {
  int h = blockIdx.x, b = blockIdx.y;
  int t = threadIdx.x, w = t >> 6, lane = t & 63, fr = lane & 15, quad = lane >> 4;
  const bf16* Tq = T + (size_t)b * 1024 * 512 + (size_t)(h * 64) * 512;
  const bf16* Tk = T + (size_t)b * 1024 * 512 + (size_t)(512 + h * 64) * 512;
  const bf16* Wqh = wq + (size_t)(h * 64) * 512;
  const bf16* Wkh = wq + (size_t)(512 + h * 64) * 512;
  f32x4 acc[4][4] = {};
#pragma unroll
  for (int s = 0; s < 4; ++s) {
    int kb = w * 128 + s * 32 + quad * 8;
    bfrag af[4], bg[4];
#pragma unroll
    for (int i = 0; i < 4; ++i) af[i] = *(const bfrag*)(Tq + (size_t)(i * 16 + fr) * 512 + kb);
#pragma unroll
    for (int j = 0; j < 4; ++j) bg[j] = *(const bfrag*)(Wkh + (size_t)(j * 16 + fr) * 512 + kb);
#pragma unroll
    for (int i = 0; i < 4; ++i)
#pragma unroll
      for (int j = 0; j < 4; ++j)
        acc[i][j] = __builtin_amdgcn_mfma_f32_16x16x32_bf16(af[i], bg[j], acc[i][j], 0, 0, 0);
  }
  __shared__ float parts[4 * 4096];
  __shared__ float nrm[2][4][64];
  __shared__ float nqk[2][64];
#pragma unroll
  for (int i = 0; i < 4; ++i)
#pragma unroll
    for (int j = 0; j < 4; ++j)
#pragma unroll
      for (int r = 0; r < 4; ++r)
        parts[w * 4096 + (i * 16 + quad * 4 + r) * 64 + j * 16 + fr] = acc[i][j][r];
  {
    int d = t & 63, qtr = t >> 6, c0 = qtr * 128;
    float pq = 0.f, pk = 0.f;
#pragma unroll 4
    for (int cc = 0; cc < 16; ++cc) {
      bf16 a[8], ww[8];
      *(uint4*)a  = *(const uint4*)(Tq + (size_t)d * 512 + c0 + cc * 8);
      *(uint4*)ww = *(const uint4*)(Wqh + (size_t)d * 512 + c0 + cc * 8);
#pragma unroll
      for (int j = 0; j < 8; ++j) pq += __bfloat162float(a[j]) * __bfloat162float(ww[j]);
      *(uint4*)a  = *(const uint4*)(Tk + (size_t)d * 512 + c0 + cc * 8);
      *(uint4*)ww = *(const uint4*)(Wkh + (size_t)d * 512 + c0 + cc * 8);
#pragma unroll
      for (int j = 0; j < 8; ++j) pk += __bfloat162float(a[j]) * __bfloat162float(ww[j]);
    }
    nrm[0][qtr][d] = pq;
    nrm[1][qtr][d] = pk;
  }
  __syncthreads();
  if (t < 64) {
    nqk[0][t] = fmaxf(sqrtf(nrm[0][0][t] + nrm[0][1][t] + nrm[0][2][t] + nrm[0][3][t]), 1e-12f);
    nqk[1][t] = fmaxf(sqrtf(nrm[1][0][t] + nrm[1][1][t] + nrm[1][2][t] + nrm[1][3][t]), 1e-12f);
  }
  __syncthreads();
  if (t < 64) {
    int d = t;
    float sc = temp[h] / nqk[0][d];
    float l[64]; float mx = -1e30f;
#pragma unroll
    for (int e = 0; e < 64; ++e) {
      float vsum = parts[d * 64 + e] + parts[4096 + d * 64 + e] +
                   parts[8192 + d * 64 + e] + parts[12288 + d * 64 + e];
      l[e] = vsum * sc / nqk[1][e];
      mx = fmaxf(mx, l[e]);
    }
    float sum = 0.f;
#pragma unroll
    for (int e = 0; e < 64; ++e) { l[e] = expf(l[e] - mx); sum += l[e]; }
    float inv = 1.0f / sum;
    bf16* pr = P + ((size_t)(b * 8 + h) * 64 + d) * 64;
#pragma unroll
    for (int e = 0; e < 64; ++e) pr[e] = __float2bfloat16(l[e] * inv);
  }
}

// ---- out = P @ v, exact GELU, store g[token][C] (bf16) ----
__global__ __launch_bounds__(256) void pv_gelu(const bf16* __restrict__ P,
                                               const bf16* __restrict__ v,
                                               bf16* __restrict__ g) {
  int chunk = blockIdx.x, h = blockIdx.y, b = blockIdx.z;
  int t = threadIdx.x, w = t >> 6, lane = t & 63, fr = lane & 15, quad = lane >> 4;
  const bf16* pb = P + (size_t)(b * 8 + h) * 4096;
  bfrag pf[4][2];
#pragma unroll
  for (int i = 0; i < 4; ++i)
#pragma unroll
    for (int c = 0; c < 2; ++c)
      pf[i][c] = *(const bfrag*)(pb + (i * 16 + fr) * 64 + c * 32 + quad * 8);
#pragma unroll 2
  for (int nt = 0; nt < 8; ++nt) {
    int ntok = chunk * 512 + w * 128 + nt * 16 + fr;
    const bf16* vrow = v + (size_t)(b * Nn + ntok) * Cc + h * 64 + quad * 8;
    bfrag bv0 = *(const bfrag*)(vrow);
    bfrag bv1 = *(const bfrag*)(vrow + 32);
    f32x4 acc[4] = {};
#pragma unroll
    for (int i = 0; i < 4; ++i) {
      acc[i] = __builtin_amdgcn_mfma_f32_16x16x32_bf16(pf[i][0], bv0, acc[i], 0, 0, 0);
      acc[i] = __builtin_amdgcn_mfma_f32_16x16x32_bf16(pf[i][1], bv1, acc[i], 0, 0, 0);
    }
    bf16* grow = g + (size_t)(b * Nn + ntok) * Cc + h * 64;
#pragma unroll
    for (int i = 0; i < 4; ++i) {
      bf16 o[4];
#pragma unroll
      for (int r = 0; r < 4; ++r) o[r] = __float2bfloat16(gelu_exact(acc[i][r]));
      *(uint2*)(grow + i * 16 + quad * 4) = *(uint2*)o;
    }
  }
}

extern "C" void kernel_launch(void* const* d_in, const int* in_sizes, int n_in,
                              void* d_out, int out_size, void* d_ws, size_t ws_size,
                              hipStream_t stream) {
  const float* x      = (const float*)d_in[0];
  const float* ln_g   = (const float*)d_in[1];
  const float* ln_b   = (const float*)d_in[2];
  const float* qkv_w  = (const float*)d_in[3];
  const float* temp   = (const float*)d_in[4];
  const float* proj_w = (const float*)d_in[5];
  const float* proj_b = (const float*)d_in[6];
  float* out = (float*)d_out;                       // fp32 output (reference returns float32)
  char*  ws  = (char*)d_ws;

  // --- runtime guards: silent failure -> measurable absmax signature ---
  const int exp_sizes[7] = {16777216, 512, 512, 786432, 8, 262144, 512};
  bool sizes_ok = (n_in == 7) && (out_size == 16777216);
  if (sizes_ok) for (int i = 0; i < 7; ++i) sizes_ok = sizes_ok && (in_sizes[i] == exp_sizes[i]);
  if (!sizes_ok) {
    fill_f32<<<(16777216 + 255) / 256, 256, 0, stream>>>(out, 500.0f, out_size);
    return;
  }
  if (ws_size < WS_NEED) {
    fill_f32<<<(16777216 + 255) / 256, 256, 0, stream>>>(out, (float)(ws_size >> 20), out_size);
    return;
  }

  bf16*  xn   = (bf16*)ws;                          // reused as g after xtx+vGEMM consume it
  bf16*  g    = (bf16*)ws;
  float* Gcov = (float*)(ws + 33554432);
  bf16*  Gcvb = (bf16*)(ws + 41943040);
  bf16*  T    = (bf16*)(ws + 46137344);
  bf16*  P    = (bf16*)(ws + 54525952);
  bf16*  wq   = (bf16*)(ws + 55050240);
  bf16*  wp   = (bf16*)(ws + 56623104);
  bf16*  v    = (bf16*)d_out;                       // park bf16 v in d_out; dead before final GEMM

  cvt_f32_bf16<<<384, 256, 0, stream>>>(qkv_w, wq, QKVC * Cc);
  cvt_f32_bf16<<<128, 256, 0, stream>>>(proj_w, wp, Cc * Cc);
  hipMemsetAsync(Gcov, 0, (size_t)Bb * Cc * Cc * sizeof(float), stream);
  ln_kernel<<<Mtok / 4, 256, 0, stream>>>(x, ln_g, ln_b, xn);
  // v = xn @ Wv^T (Wv = qkv_w rows 1024..1535)
  gemm_bt<bf16, true><<<dim3(4, 256, 1), 256, 0, stream>>>(xn, wq + 1024 * 512, v, Mtok, Cc, Cc,
                                                           nullptr, 0, 0, 0);
  xtx<<<640, 256, 0, stream>>>(xn, Gcov);
  cvt_mirror<<<dim3(16, 8), 256, 0, stream>>>(Gcov, Gcvb);
  // T[b] = Wqk @ Gcov[b]  (Gcov symmetric => @Gcov^T == @Gcov)
  gemm_bt<bf16, false><<<dim3(4, 8, 8), 256, 0, stream>>>(wq, Gcvb, T, 1024, Cc, Cc,
                                                          nullptr, 0, (long)Cc * Cc, (long)1024 * Cc);
  gram_softmax<<<dim3(Hh, Bb), 256, 0, stream>>>(T, wq, temp, P);
  pv_gelu<<<dim3(8, Hh, Bb), 256, 0, stream>>>(P, v, g);
  // out = g @ proj_w^T + proj_b  (fp32 stores, overwrites v)
  gemm_bt<float, true><<<dim3(4, 256, 1), 256, 0, stream>>>(g, wp, out, Mtok, Cc, Cc,
                                                            proj_b, 0, 0, 0);
}

// Round 10
// 265.271 us; speedup vs baseline: 1.2130x; 1.0405x over previous
//
#include <hip/hip_runtime.h>
#include <hip/hip_bf16.h>

typedef __hip_bfloat16 bf16;
typedef __bf16 bfrag __attribute__((ext_vector_type(8)));   // 8 bf16 = 4 VGPRs (MFMA A/B operand)
typedef float f32x4 __attribute__((ext_vector_type(4)));    // MFMA C/D

#define AS1 __attribute__((address_space(1)))
#define AS3 __attribute__((address_space(3)))

static constexpr int Bb = 8, Nn = 4096, Cc = 512, Hh = 8;
static constexpr int Mtok = Bb * Nn;          // 32768
static constexpr int QKVC = 3 * Cc;           // 1536
// ws layout (NEED = 57,147,392 bytes; proven ws_size >= 59,768,832):
//  xn/g [0, 33554432)          bf16 [32768][512]
//  Gcov [33554432, 41943040)   f32  [8][512][512]
//  Gcvb [41943040, 46137344)   bf16 [8][512][512]
//  T    [46137344, 54525952)   bf16 [8][1024][512]
//  P    [54525952, 55050240)   bf16 [8][8][64][64]
//  wq   [55050240, 56623104)   bf16 [1536][512]
//  wp   [56623104, 57147392)   bf16 [512][512]
static constexpr size_t WS_NEED = 57147392;

__device__ __forceinline__ void gl_lds16(const void* g, void* l) {
  __builtin_amdgcn_global_load_lds((const AS1 void*)g, (AS3 void*)l, 16, 0, 0);
}
__device__ __forceinline__ float gelu_exact(float x) {
  return 0.5f * x * (1.0f + erff(x * 0.70710678118654752f));
}
// 3-bit rotate-right-by-1: bijection used for LDS slot swizzle (conflict-free reads AND writes)
__device__ __forceinline__ int g3(int x) { return ((x & 1) << 2) | (x >> 1); }

// ---------------- diagnostic fill (fp32 output) ----------------
__global__ __launch_bounds__(256) void fill_f32(float* o, float val, int n) {
  int i = blockIdx.x * 256 + threadIdx.x;
  if (i < n) o[i] = val;
}

// ---------------- fp32 -> bf16 conversion ----------------
__global__ __launch_bounds__(256) void cvt_f32_bf16(const float* __restrict__ a,
                                                    bf16* __restrict__ o, int n) {
  int i = (blockIdx.x * 256 + threadIdx.x) * 8;
  if (i + 8 <= n) {
    float f[8];
    *(float4*)f       = *(const float4*)(a + i);
    *(float4*)(f + 4) = *(const float4*)(a + i + 4);
    bf16 v[8];
#pragma unroll
    for (int j = 0; j < 8; ++j) v[j] = __float2bfloat16(f[j]);
    *(uint4*)(o + i) = *(uint4*)v;
  }
}

// ---- Gcov (upper-tri tiles, fp32) -> Gcvb (full, bf16); lower tiles mirrored via LDS ----
__global__ __launch_bounds__(256) void cvt_mirror(const float* __restrict__ Gcov,
                                                  bf16* __restrict__ Gcvb) {
  int tile = blockIdx.x, b = blockIdx.y;
  int ti = tile >> 2, tj = tile & 3;
  int t = threadIdx.x;
  const float* gb = Gcov + (size_t)b * Cc * Cc;
  bf16* ob = Gcvb + (size_t)b * Cc * Cc;
  if (ti <= tj) {
    // direct convert, coalesced
#pragma unroll
    for (int r8 = 0; r8 < 8; ++r8) {
      int row = r8 * 16 + (t >> 4), col = (t & 15) * 8;
      const float* src = gb + (size_t)(ti * 128 + row) * Cc + tj * 128 + col;
      float f[8];
      *(float4*)f       = *(const float4*)src;
      *(float4*)(f + 4) = *(const float4*)(src + 4);
      bf16 v[8];
#pragma unroll
      for (int j = 0; j < 8; ++j) v[j] = __float2bfloat16(f[j]);
      *(uint4*)(ob + (size_t)(ti * 128 + row) * Cc + tj * 128 + col) = *(uint4*)v;
    }
  } else {
    // mirror: read computed tile (tj,ti) coalesced, transpose through LDS, write (ti,tj)
    __shared__ bf16 ls[128][136];          // pad 8 -> row stride 272B (16B-aligned)
#pragma unroll
    for (int r8 = 0; r8 < 8; ++r8) {
      int srow = r8 * 16 + (t >> 4), scol = (t & 15) * 8;
      const float* src = gb + (size_t)(tj * 128 + srow) * Cc + ti * 128 + scol;
      float f[8];
      *(float4*)f       = *(const float4*)src;
      *(float4*)(f + 4) = *(const float4*)(src + 4);
      bf16 v[8];
#pragma unroll
      for (int j = 0; j < 8; ++j) v[j] = __float2bfloat16(f[j]);
      *(uint4*)&ls[srow][scol] = *(uint4*)v;
    }
    __syncthreads();
#pragma unroll
    for (int r8 = 0; r8 < 8; ++r8) {
      int orow = r8 * 16 + (t >> 4), ocol = (t & 15) * 8;
      bf16 v[8];
#pragma unroll
      for (int u = 0; u < 8; ++u) v[u] = ls[ocol + u][orow];
      *(uint4*)(ob + (size_t)(ti * 128 + orow) * Cc + tj * 128 + ocol) = *(uint4*)v;
    }
  }
}

// ---------------- LayerNorm (one wave per token), fp32 in -> bf16 out ----------------
__global__ __launch_bounds__(256) void ln_kernel(const float* __restrict__ x,
                                                 const float* __restrict__ gw,
                                                 const float* __restrict__ bw,
                                                 bf16* __restrict__ xn) {
  int tok  = blockIdx.x * 4 + (threadIdx.x >> 6);
  int lane = threadIdx.x & 63;
  const float* xr = x + (size_t)tok * Cc + lane * 8;
  float f[8];
  *(float4*)f       = *(const float4*)xr;
  *(float4*)(f + 4) = *(const float4*)(xr + 4);
  float s = 0.f;
#pragma unroll
  for (int j = 0; j < 8; ++j) s += f[j];
#pragma unroll
  for (int m = 32; m; m >>= 1) s += __shfl_xor(s, m);
  float mu = s * (1.0f / 512.0f);
  float q = 0.f;
#pragma unroll
  for (int j = 0; j < 8; ++j) { float d = f[j] - mu; q += d * d; }
#pragma unroll
  for (int m = 32; m; m >>= 1) q += __shfl_xor(q, m);
  float rstd = rsqrtf(q * (1.0f / 512.0f) + 1e-5f);
  bf16 o[8];
#pragma unroll
  for (int j = 0; j < 8; ++j)
    o[j] = __float2bfloat16((f[j] - mu) * rstd * gw[lane * 8 + j] + bw[lane * 8 + j]);
  *(uint4*)(xn + (size_t)tok * Cc + lane * 8) = *(uint4*)o;
}

// ------------- GEMM C[M,N] = A[M,K] @ B[N,K]^T, bf16 in, bf16 OR fp32 out, batched -------------
// LDS slot swizzle via pre-swizzled global_load_lds source (rule: swizzle source+read, dest
// linear): slot s of row r holds global column (s^(r&7))*8 -> fragment reads spread 64 lanes
// over all 32 banks (8-deep = b128 bandwidth floor; was 16-deep on 16 banks).
// SWZ: XCD-chunked block swizzle (1024 blocks = 8 XCDs x 128): same-A-panel blocks share an L2.
template <typename TC, bool SWZ>
__global__ __launch_bounds__(256) void gemm_bt(const bf16* __restrict__ A,
                                               const bf16* __restrict__ B,
                                               TC* __restrict__ C,
                                               int M, int N, int K,
                                               const float* __restrict__ bias,
                                               long sA_z, long sB_z, long sC_z) {
  A += (size_t)blockIdx.z * sA_z;
  B += (size_t)blockIdx.z * sB_z;
  C += (size_t)blockIdx.z * sC_z;
  __shared__ __align__(16) bf16 smem[16384];   // sA[128][64] | sB[128][64]; reused as ct[128][128]
  bf16* sA = smem;
  bf16* sB = smem + 8192;
  int t = threadIdx.x, w = t >> 6, lane = t & 63, fr = lane & 15, quad = lane >> 4;
  int n0, m0;
  if constexpr (SWZ) {
    int flat = blockIdx.y * 4 + blockIdx.x;    // 0..1023
    int idx  = (flat & 7) * 128 + (flat >> 3); // XCD k owns idx [128k,128k+128)
    n0 = (idx & 3) * 128;
    m0 = (idx >> 2) * 128;
  } else {
    n0 = blockIdx.x * 128;
    m0 = blockIdx.y * 128;
  }
  int wm = (w >> 1) * 64, wn = (w & 1) * 64;
  f32x4 acc[4][4] = {};

  for (int k0 = 0; k0 < K; k0 += 64) {
    __syncthreads();
#pragma unroll
    for (int c2 = 0; c2 < 4; ++c2) {
      int c = w * 4 + c2;                // 1KB chunk id, 0..15
      int row = c * 8 + (lane >> 3);     // 0..127
      int ke  = ((lane & 7) ^ (lane >> 3)) * 8;   // pre-swizzled source slot
      gl_lds16(A + (size_t)(m0 + row) * K + k0 + ke, (char*)sA + c * 1024);
      gl_lds16(B + (size_t)(n0 + row) * K + k0 + ke, (char*)sB + c * 1024);
    }
    __syncthreads();
#pragma unroll
    for (int kk = 0; kk < 64; kk += 32) {
      bfrag af[4], bg[4];
#pragma unroll
      for (int i = 0; i < 4; ++i)
        af[i] = *(const bfrag*)(sA + (wm + i * 16 + fr) * 64 +
                                ((((kk >> 3) + quad) ^ (fr & 7)) * 8));
#pragma unroll
      for (int j = 0; j < 4; ++j)
        bg[j] = *(const bfrag*)(sB + (wn + j * 16 + fr) * 64 +
                                ((((kk >> 3) + quad) ^ (fr & 7)) * 8));
#pragma unroll
      for (int i = 0; i < 4; ++i)
#pragma unroll
        for (int j = 0; j < 4; ++j)
          acc[i][j] = __builtin_amdgcn_mfma_f32_16x16x32_bf16(af[i], bg[j], acc[i][j], 0, 0, 0);
    }
  }

  if constexpr (__is_same(TC, float)) {
    // direct fp32 stores from C-fragment layout (col=fr, row=quad*4+r)
#pragma unroll
    for (int j = 0; j < 4; ++j) {
      float bj = bias ? bias[n0 + wn + j * 16 + fr] : 0.0f;
#pragma unroll
      for (int i = 0; i < 4; ++i)
#pragma unroll
        for (int r = 0; r < 4; ++r)
          C[(size_t)(m0 + wm + i * 16 + quad * 4 + r) * N + n0 + wn + j * 16 + fr] =
              acc[i][j][r] + bj;
    }
  } else {
    __syncthreads();
    bf16* ct = smem;                      // [128][128]
#pragma unroll
    for (int j = 0; j < 4; ++j) {
      float bj = bias ? bias[n0 + wn + j * 16 + fr] : 0.0f;
#pragma unroll
      for (int i = 0; i < 4; ++i)
#pragma unroll
        for (int r = 0; r < 4; ++r)
          ct[(wm + i * 16 + quad * 4 + r) * 128 + wn + j * 16 + fr] =
              __float2bfloat16(acc[i][j][r] + bj);
    }
    __syncthreads();
#pragma unroll
    for (int r8 = 0; r8 < 8; ++r8) {
      int row = r8 * 16 + (t >> 4);
      int ce  = (t & 15) * 8;
      *(uint4*)(C + (size_t)(m0 + row) * N + n0 + ce) = *(const uint4*)(smem + row * 128 + ce);
    }
  }
}

// ---- Gcov[b] += Xb^T Xb — 64x128 upper-tri tiles (m <= 2n+1), split-K=4.
// Same grid (640) & per-block FLOP as the 128^2/split-8 version, but HALF the atomic ops
// (5.24M vs 10.5M) — r9 counters showed xtx time tracks atomic count.
// A-strip aliases into sB when contained (m in {2n,2n+1}); g3 slot swizzle invariant under
// the 64-channel offset. Register-transpose staging + prefetch under compute as before.
__global__ __launch_bounds__(256) void xtx(const bf16* __restrict__ xn,
                                           float* __restrict__ Gcov) {
  // grid = 640 = 8 XCDs * 80; XCD k handles batch b=k (atomics L2-local)
  int flat = blockIdx.x;
  int idx  = (flat & 7) * 80 + (flat >> 3);
  int tile = idx % 20;
  int sb   = idx / 20;               // 0..31
  int split = sb & 3, b = sb >> 2;
  int nt = tile < 2 ? 0 : tile < 6 ? 1 : tile < 12 ? 2 : 3;
  int mt = tile - (nt == 0 ? 0 : nt == 1 ? 2 : nt == 2 ? 6 : 12);
  int m0 = mt * 64, n0 = nt * 128;
  bool alias = ((mt >> 1) == nt);    // A channels within B strip
  int t = threadIdx.x, w = t >> 6, lane = t & 63, fr = lane & 15, quad = lane >> 4;
  int wn = w * 32;                   // wave's 32-col slice of the 128-col tile
  __shared__ __align__(16) bf16 sB[8192];   // [128 ch][64 tok], g3-swizzled slots
  __shared__ __align__(16) bf16 sAb[4096];  // [64 ch][64 tok]
  bf16* sA = alias ? (sB + (mt & 1) * 4096) : sAb;
  f32x4 acc[4][2] = {};
  const bf16* xb = xn + ((size_t)b * Nn + split * 1024) * Cc;
  int ch0b = (t & 15) * 8, tgb = t >> 4;    // B staging: all threads, 4 tokens each
  int ch0a = (t & 7) * 8,  tga = t >> 3;    // A staging: threads t<128 only
  bool doA = (!alias) && (t < 128);
  unsigned swz = (unsigned)g3(t & 7);       // g3((ch0>>3)&7) for both A and B rows
  unsigned wposb = (((unsigned)(tgb >> 1) ^ swz) * 16u) + (unsigned)(tgb & 1) * 8u;
  unsigned wposa = (((unsigned)(tga >> 1) ^ swz) * 16u) + (unsigned)(tga & 1) * 8u;
  uint4 va[4], vb[4];
  // prologue: load chunk 0
#pragma unroll
  for (int j = 0; j < 4; ++j)
    vb[j] = *(const uint4*)(xb + (size_t)(tgb * 4 + j) * Cc + n0 + ch0b);
  if (doA)
#pragma unroll
    for (int j = 0; j < 4; ++j)
      va[j] = *(const uint4*)(xb + (size_t)(tga * 4 + j) * Cc + m0 + ch0a);
  for (int kc = 0; kc < 16; ++kc) {
    __syncthreads();                       // prev compute done; LDS reusable
    // register transpose 8ch x 4tok -> 8 x ds_write_b64 per operand
#pragma unroll
    for (int k = 0; k < 4; ++k) {
      unsigned b0 = ((const unsigned*)&vb[0])[k], b1 = ((const unsigned*)&vb[1])[k];
      unsigned b2 = ((const unsigned*)&vb[2])[k], b3 = ((const unsigned*)&vb[3])[k];
      uint2 lo = { (b0 & 0xffffu) | (b1 << 16), (b2 & 0xffffu) | (b3 << 16) };
      uint2 hi = { (b0 >> 16) | (b1 & 0xffff0000u), (b2 >> 16) | (b3 & 0xffff0000u) };
      *(uint2*)((char*)sB + (unsigned)(ch0b + 2 * k) * 128 + wposb) = lo;
      *(uint2*)((char*)sB + (unsigned)(ch0b + 2 * k + 1) * 128 + wposb) = hi;
    }
    if (doA) {
#pragma unroll
      for (int k = 0; k < 4; ++k) {
        unsigned a0 = ((const unsigned*)&va[0])[k], a1 = ((const unsigned*)&va[1])[k];
        unsigned a2 = ((const unsigned*)&va[2])[k], a3 = ((const unsigned*)&va[3])[k];
        uint2 lo = { (a0 & 0xffffu) | (a1 << 16), (a2 & 0xffffu) | (a3 << 16) };
        uint2 hi = { (a0 >> 16) | (a1 & 0xffff0000u), (a2 >> 16) | (a3 & 0xffff0000u) };
        *(uint2*)((char*)sAb + (unsigned)(ch0a + 2 * k) * 128 + wposa) = lo;
        *(uint2*)((char*)sAb + (unsigned)(ch0a + 2 * k + 1) * 128 + wposa) = hi;
      }
    }
    __syncthreads();                       // tile visible
    if (kc < 15) {                         // prefetch next chunk under compute
      const bf16* xb2 = xb + (size_t)(kc + 1) * 64 * Cc;
#pragma unroll
      for (int j = 0; j < 4; ++j)
        vb[j] = *(const uint4*)(xb2 + (size_t)(tgb * 4 + j) * Cc + n0 + ch0b);
      if (doA)
#pragma unroll
        for (int j = 0; j < 4; ++j)
          va[j] = *(const uint4*)(xb2 + (size_t)(tga * 4 + j) * Cc + m0 + ch0a);
    }
#pragma unroll
    for (int kk = 0; kk < 2; ++kk) {       // k-steps: tokens kk*32 .. kk*32+31
      bfrag af[4], bg[2];
#pragma unroll
      for (int i = 0; i < 4; ++i) {
        int ch = i * 16 + fr;
        int slot = (kk * 4 + quad) ^ g3((ch >> 3) & 7);
        af[i] = *(const bfrag*)(sA + ch * 64 + slot * 8);
      }
#pragma unroll
      for (int j = 0; j < 2; ++j) {
        int ch = wn + j * 16 + fr;
        int slot = (kk * 4 + quad) ^ g3((ch >> 3) & 7);
        bg[j] = *(const bfrag*)(sB + ch * 64 + slot * 8);
      }
#pragma unroll
      for (int i = 0; i < 4; ++i)
#pragma unroll
        for (int j = 0; j < 2; ++j)
          acc[i][j] = __builtin_amdgcn_mfma_f32_16x16x32_bf16(af[i], bg[j], acc[i][j], 0, 0, 0);
    }
  }
  float* gb = Gcov + (size_t)b * Cc * Cc;
#pragma unroll
  for (int i = 0; i < 4; ++i)
#pragma unroll
    for (int j = 0; j < 2; ++j)
#pragma unroll
      for (int r = 0; r < 4; ++r)
        atomicAdd(&gb[(size_t)(m0 + i * 16 + quad * 4 + r) * Cc + n0 + wn + j * 16 + fr],
                  acc[i][j][r]);
}

// ---- per (b,h): Gram = T_q @ Wk^T (MFMA, K=512), norms via row-dots, softmax -> P bf16 ----
__global__ __launch_bounds__(256) void gram_softmax(const bf16* __restrict__ T,
                                                    const bf16* __restrict__ wq,
                                                    const float* __restrict__ temp,
                                                    bf16* __restrict__ P) {
  int h = blockIdx.x, b = blockIdx.y;
  int t = threadIdx.x, w = t >> 6, lane = t & 63, fr = lane & 15, quad = lane >> 4;
  const bf16* Tq = T + (size_t)b * 1024 * 512 + (size_t)(h * 64) * 512;
  const bf16* Tk = T + (size_t)b * 1024 * 512 + (size_t)(512 + h * 64) * 512;
  const bf16* Wqh = wq + (size_t)(h * 64) * 512;
  const bf16* Wkh = wq + (size_t)(512 + h * 64) * 512;
  f32x4 acc[4][4] = {};
#pragma unroll
  for (int s = 0; s < 4; ++s) {
    int kb = w * 128 + s * 32 + quad * 8;
    bfrag af[4], bg[4];
#pragma unroll
    for (int i = 0; i < 4; ++i) af[i] = *(const bfrag*)(Tq + (size_t)(i * 16 + fr) * 512 + kb);
#pragma unroll
    for (int j = 0; j < 4; ++j) bg[j] = *(const bfrag*)(Wkh + (size_t)(j * 16 + fr) * 512 + kb);
#pragma unroll
    for (int i = 0; i < 4; ++i)
#pragma unroll
      for (int j = 0; j < 4; ++j)
        acc[i][j] = __builtin_amdgcn_mfma_f32_16x16x32_bf16(af[i], bg[j], acc[i][j], 0, 0, 0);
  }
  __shared__ float parts[4 * 4096];
  __shared__ float nrm[2][4][64];
  __shared__ float nqk[2][64];
#pragma unroll
  for (int i = 0; i < 4; ++i)
#pragma unroll
    for (int j = 0; j < 4; ++j)
#pragma unroll
      for (int r = 0; r < 4; ++r)
        parts[w * 4096 + (i * 16 + quad * 4 + r) * 64 + j * 16 + fr] = acc[i][j][r];
  {
    int d = t & 63, qtr = t >> 6, c0 = qtr * 128;
    float pq = 0.f, pk = 0.f;
#pragma unroll 4
    for (int cc = 0; cc < 16; ++cc) {
      bf16 a[8], ww[8];
      *(uint4*)a  = *(const uint4*)(Tq + (size_t)d * 512 + c0 + cc * 8);
      *(uint4*)ww = *(const uint4*)(Wqh + (size_t)d * 512 + c0 + cc * 8);
#pragma unroll
      for (int j = 0; j < 8; ++j) pq += __bfloat162float(a[j]) * __bfloat162float(ww[j]);
      *(uint4*)a  = *(const uint4*)(Tk + (size_t)d * 512 + c0 + cc * 8);
      *(uint4*)ww = *(const uint4*)(Wkh + (size_t)d * 512 + c0 + cc * 8);
#pragma unroll
      for (int j = 0; j < 8; ++j) pk += __bfloat162float(a[j]) * __bfloat162float(ww[j]);
    }
    nrm[0][qtr][d] = pq;
    nrm[1][qtr][d] = pk;
  }
  __syncthreads();
  if (t < 64) {
    nqk[0][t] = fmaxf(sqrtf(nrm[0][0][t] + nrm[0][1][t] + nrm[0][2][t] + nrm[0][3][t]), 1e-12f);
    nqk[1][t] = fmaxf(sqrtf(nrm[1][0][t] + nrm[1][1][t] + nrm[1][2][t] + nrm[1][3][t]), 1e-12f);
  }
  __syncthreads();
  if (t < 64) {
    int d = t;
    float sc = temp[h] / nqk[0][d];
    float l[64]; float mx = -1e30f;
#pragma unroll
    for (int e = 0; e < 64; ++e) {
      float vsum = parts[d * 64 + e] + parts[4096 + d * 64 + e] +
                   parts[8192 + d * 64 + e] + parts[12288 + d * 64 + e];
      l[e] = vsum * sc / nqk[1][e];
      mx = fmaxf(mx, l[e]);
    }
    float sum = 0.f;
#pragma unroll
    for (int e = 0; e < 64; ++e) { l[e] = expf(l[e] - mx); sum += l[e]; }
    float inv = 1.0f / sum;
    bf16* pr = P + ((size_t)(b * 8 + h) * 64 + d) * 64;
#pragma unroll
    for (int e = 0; e < 64; ++e) pr[e] = __float2bfloat16(l[e] * inv);
  }
}

// ---- out = P @ v, exact GELU, store g[token][C] (bf16) ----
__global__ __launch_bounds__(256) void pv_gelu(const bf16* __restrict__ P,
                                               const bf16* __restrict__ v,
                                               bf16* __restrict__ g) {
  int chunk = blockIdx.x, h = blockIdx.y, b = blockIdx.z;
  int t = threadIdx.x, w = t >> 6, lane = t & 63, fr = lane & 15, quad = lane >> 4;
  const bf16* pb = P + (size_t)(b * 8 + h) * 4096;
  bfrag pf[4][2];
#pragma unroll
  for (int i = 0; i < 4; ++i)
#pragma unroll
    for (int c = 0; c < 2; ++c)
      pf[i][c] = *(const bfrag*)(pb + (i * 16 + fr) * 64 + c * 32 + quad * 8);
#pragma unroll 2
  for (int nt = 0; nt < 8; ++nt) {
    int ntok = chunk * 512 + w * 128 + nt * 16 + fr;
    const bf16* vrow = v + (size_t)(b * Nn + ntok) * Cc + h * 64 + quad * 8;
    bfrag bv0 = *(const bfrag*)(vrow);
    bfrag bv1 = *(const bfrag*)(vrow + 32);
    f32x4 acc[4] = {};
#pragma unroll
    for (int i = 0; i < 4; ++i) {
      acc[i] = __builtin_amdgcn_mfma_f32_16x16x32_bf16(pf[i][0], bv0, acc[i], 0, 0, 0);
      acc[i] = __builtin_amdgcn_mfma_f32_16x16x32_bf16(pf[i][1], bv1, acc[i], 0, 0, 0);
    }
    bf16* grow = g + (size_t)(b * Nn + ntok) * Cc + h * 64;
#pragma unroll
    for (int i = 0; i < 4; ++i) {
      bf16 o[4];
#pragma unroll
      for (int r = 0; r < 4; ++r) o[r] = __float2bfloat16(gelu_exact(acc[i][r]));
      *(uint2*)(grow + i * 16 + quad * 4) = *(uint2*)o;
    }
  }
}

extern "C" void kernel_launch(void* const* d_in, const int* in_sizes, int n_in,
                              void* d_out, int out_size, void* d_ws, size_t ws_size,
                              hipStream_t stream) {
  const float* x      = (const float*)d_in[0];
  const float* ln_g   = (const float*)d_in[1];
  const float* ln_b   = (const float*)d_in[2];
  const float* qkv_w  = (const float*)d_in[3];
  const float* temp   = (const float*)d_in[4];
  const float* proj_w = (const float*)d_in[5];
  const float* proj_b = (const float*)d_in[6];
  float* out = (float*)d_out;                       // fp32 output (reference returns float32)
  char*  ws  = (char*)d_ws;

  // --- runtime guards: silent failure -> measurable absmax signature ---
  const int exp_sizes[7] = {16777216, 512, 512, 786432, 8, 262144, 512};
  bool sizes_ok = (n_in == 7) && (out_size == 16777216);
  if (sizes_ok) for (int i = 0; i < 7; ++i) sizes_ok = sizes_ok && (in_sizes[i] == exp_sizes[i]);
  if (!sizes_ok) {
    fill_f32<<<(16777216 + 255) / 256, 256, 0, stream>>>(out, 500.0f, out_size);
    return;
  }
  if (ws_size < WS_NEED) {
    fill_f32<<<(16777216 + 255) / 256, 256, 0, stream>>>(out, (float)(ws_size >> 20), out_size);
    return;
  }

  bf16*  xn   = (bf16*)ws;                          // reused as g after xtx+vGEMM consume it
  bf16*  g    = (bf16*)ws;
  float* Gcov = (float*)(ws + 33554432);
  bf16*  Gcvb = (bf16*)(ws + 41943040);
  bf16*  T    = (bf16*)(ws + 46137344);
  bf16*  P    = (bf16*)(ws + 54525952);
  bf16*  wq   = (bf16*)(ws + 55050240);
  bf16*  wp   = (bf16*)(ws + 56623104);
  bf16*  v    = (bf16*)d_out;                       // park bf16 v in d_out; dead before final GEMM

  cvt_f32_bf16<<<384, 256, 0, stream>>>(qkv_w, wq, QKVC * Cc);
  cvt_f32_bf16<<<128, 256, 0, stream>>>(proj_w, wp, Cc * Cc);
  hipMemsetAsync(Gcov, 0, (size_t)Bb * Cc * Cc * sizeof(float), stream);
  ln_kernel<<<Mtok / 4, 256, 0, stream>>>(x, ln_g, ln_b, xn);
  // v = xn @ Wv^T (Wv = qkv_w rows 1024..1535)
  gemm_bt<bf16, true><<<dim3(4, 256, 1), 256, 0, stream>>>(xn, wq + 1024 * 512, v, Mtok, Cc, Cc,
                                                           nullptr, 0, 0, 0);
  xtx<<<640, 256, 0, stream>>>(xn, Gcov);
  cvt_mirror<<<dim3(16, 8), 256, 0, stream>>>(Gcov, Gcvb);
  // T[b] = Wqk @ Gcov[b]  (Gcov symmetric => @Gcov^T == @Gcov)
  gemm_bt<bf16, false><<<dim3(4, 8, 8), 256, 0, stream>>>(wq, Gcvb, T, 1024, Cc, Cc,
                                                          nullptr, 0, (long)Cc * Cc, (long)1024 * Cc);
  gram_softmax<<<dim3(Hh, Bb), 256, 0, stream>>>(T, wq, temp, P);
  pv_gelu<<<dim3(8, Hh, Bb), 256, 0, stream>>>(P, v, g);
  // out = g @ proj_w^T + proj_b  (fp32 stores, overwrites v)
  gemm_bt<float, true><<<dim3(4, 256, 1), 256, 0, stream>>>(g, wp, out, Mtok, Cc, Cc,
                                                            proj_b, 0, 0, 0);
}

// Round 11
// 259.309 us; speedup vs baseline: 1.2409x; 1.0230x over previous
//
#include <hip/hip_runtime.h>
#include <hip/hip_bf16.h>

typedef __hip_bfloat16 bf16;
typedef __bf16 bfrag __attribute__((ext_vector_type(8)));   // 8 bf16 = 4 VGPRs (MFMA A/B operand)
typedef float f32x4 __attribute__((ext_vector_type(4)));    // MFMA C/D

#define AS1 __attribute__((address_space(1)))
#define AS3 __attribute__((address_space(3)))

static constexpr int Bb = 8, Nn = 4096, Cc = 512, Hh = 8;
static constexpr int Mtok = Bb * Nn;          // 32768
static constexpr int QKVC = 3 * Cc;           // 1536
// ws layout (NEED = 57,147,392 bytes; proven ws_size >= 59,768,832):
//  xn/g [0, 33554432)          bf16 [32768][512]
//  (Gcov region [33554432, 41943040) now UNUSED — xtx partials live in d_out upper half)
//  Gcvb [41943040, 46137344)   bf16 [8][512][512]
//  T    [46137344, 54525952)   bf16 [8][1024][512]
//  P    [54525952, 55050240)   bf16 [8][8][64][64]
//  wq   [55050240, 56623104)   bf16 [1536][512]
//  wp   [56623104, 57147392)   bf16 [512][512]
// d_out (67.1 MB): v bf16 [0, 33554432); xtx partials f32 [33554432, 54525952);
//   both dead before the final GEMM writes out.
static constexpr size_t WS_NEED = 57147392;
static constexpr int SPL_STRIDE = 8 * 20 * 8192;   // floats per split in partial buffer

__device__ __forceinline__ void gl_lds16(const void* g, void* l) {
  __builtin_amdgcn_global_load_lds((const AS1 void*)g, (AS3 void*)l, 16, 0, 0);
}
__device__ __forceinline__ float gelu_exact(float x) {
  return 0.5f * x * (1.0f + erff(x * 0.70710678118654752f));
}
// 3-bit rotate-right-by-1: bijection used for LDS slot swizzle (conflict-free reads AND writes)
__device__ __forceinline__ int g3(int x) { return ((x & 1) << 2) | (x >> 1); }
// xtx tile id from (mt 64-row, nt 128-col) upper-tri indices; section sizes 2,4,6,8
__device__ __forceinline__ int tileid(int mt, int nt) {
  return mt + (nt == 0 ? 0 : nt == 1 ? 2 : nt == 2 ? 6 : 12);
}

// ---------------- diagnostic fill (fp32 output) ----------------
__global__ __launch_bounds__(256) void fill_f32(float* o, float val, int n) {
  int i = blockIdx.x * 256 + threadIdx.x;
  if (i < n) o[i] = val;
}

// ---------------- fp32 -> bf16 conversion ----------------
__global__ __launch_bounds__(256) void cvt_f32_bf16(const float* __restrict__ a,
                                                    bf16* __restrict__ o, int n) {
  int i = (blockIdx.x * 256 + threadIdx.x) * 8;
  if (i + 8 <= n) {
    float f[8];
    *(float4*)f       = *(const float4*)(a + i);
    *(float4*)(f + 4) = *(const float4*)(a + i + 4);
    bf16 v[8];
#pragma unroll
    for (int j = 0; j < 8; ++j) v[j] = __float2bfloat16(f[j]);
    *(uint4*)(o + i) = *(uint4*)v;
  }
}

// ---- sum 4 xtx split-partials -> Gcvb (full bf16); lower tiles mirrored via LDS ----
__global__ __launch_bounds__(256) void cvt_mirror(const float* __restrict__ part,
                                                  bf16* __restrict__ Gcvb) {
  int tile = blockIdx.x, b = blockIdx.y;
  int ti = tile >> 2, tj = tile & 3;
  int t = threadIdx.x;
  bf16* ob = Gcvb + (size_t)b * Cc * Cc;
  if (ti <= tj) {
    // direct: sum partials of tiles (2ti + row>>6, tj), convert, coalesced write
#pragma unroll
    for (int r8 = 0; r8 < 8; ++r8) {
      int row = r8 * 16 + (t >> 4), col = (t & 15) * 8;
      int mt = 2 * ti + (row >> 6), rsub = row & 63;
      const float* p0 = part + ((size_t)b * 20 + tileid(mt, tj)) * 8192 + rsub * 128 + col;
      float f[8];
      *(float4*)f       = *(const float4*)p0;
      *(float4*)(f + 4) = *(const float4*)(p0 + 4);
#pragma unroll
      for (int s = 1; s < 4; ++s) {
        const float* ps = p0 + (size_t)s * SPL_STRIDE;
        float g[8];
        *(float4*)g       = *(const float4*)ps;
        *(float4*)(g + 4) = *(const float4*)(ps + 4);
#pragma unroll
        for (int j = 0; j < 8; ++j) f[j] += g[j];
      }
      bf16 v[8];
#pragma unroll
      for (int j = 0; j < 8; ++j) v[j] = __float2bfloat16(f[j]);
      *(uint4*)(ob + (size_t)(ti * 128 + row) * Cc + tj * 128 + col) = *(uint4*)v;
    }
  } else {
    // mirror: sum partials of source tile (tj,ti) coalesced, transpose through LDS, write (ti,tj)
    __shared__ bf16 ls[128][136];          // pad 8 -> row stride 272B (16B-aligned)
#pragma unroll
    for (int r8 = 0; r8 < 8; ++r8) {
      int srow = r8 * 16 + (t >> 4), scol = (t & 15) * 8;
      int mt = 2 * tj + (srow >> 6), rsub = srow & 63;
      const float* p0 = part + ((size_t)b * 20 + tileid(mt, ti)) * 8192 + rsub * 128 + scol;
      float f[8];
      *(float4*)f       = *(const float4*)p0;
      *(float4*)(f + 4) = *(const float4*)(p0 + 4);
#pragma unroll
      for (int s = 1; s < 4; ++s) {
        const float* ps = p0 + (size_t)s * SPL_STRIDE;
        float g[8];
        *(float4*)g       = *(const float4*)ps;
        *(float4*)(g + 4) = *(const float4*)(ps + 4);
#pragma unroll
        for (int j = 0; j < 8; ++j) f[j] += g[j];
      }
      bf16 v[8];
#pragma unroll
      for (int j = 0; j < 8; ++j) v[j] = __float2bfloat16(f[j]);
      *(uint4*)&ls[srow][scol] = *(uint4*)v;
    }
    __syncthreads();
#pragma unroll
    for (int r8 = 0; r8 < 8; ++r8) {
      int orow = r8 * 16 + (t >> 4), ocol = (t & 15) * 8;
      bf16 v[8];
#pragma unroll
      for (int u = 0; u < 8; ++u) v[u] = ls[ocol + u][orow];
      *(uint4*)(ob + (size_t)(ti * 128 + orow) * Cc + tj * 128 + ocol) = *(uint4*)v;
    }
  }
}

// ---------------- LayerNorm (one wave per token), fp32 in -> bf16 out ----------------
__global__ __launch_bounds__(256) void ln_kernel(const float* __restrict__ x,
                                                 const float* __restrict__ gw,
                                                 const float* __restrict__ bw,
                                                 bf16* __restrict__ xn) {
  int tok  = blockIdx.x * 4 + (threadIdx.x >> 6);
  int lane = threadIdx.x & 63;
  const float* xr = x + (size_t)tok * Cc + lane * 8;
  float f[8];
  *(float4*)f       = *(const float4*)xr;
  *(float4*)(f + 4) = *(const float4*)(xr + 4);
  float s = 0.f;
#pragma unroll
  for (int j = 0; j < 8; ++j) s += f[j];
#pragma unroll
  for (int m = 32; m; m >>= 1) s += __shfl_xor(s, m);
  float mu = s * (1.0f / 512.0f);
  float q = 0.f;
#pragma unroll
  for (int j = 0; j < 8; ++j) { float d = f[j] - mu; q += d * d; }
#pragma unroll
  for (int m = 32; m; m >>= 1) q += __shfl_xor(q, m);
  float rstd = rsqrtf(q * (1.0f / 512.0f) + 1e-5f);
  bf16 o[8];
#pragma unroll
  for (int j = 0; j < 8; ++j)
    o[j] = __float2bfloat16((f[j] - mu) * rstd * gw[lane * 8 + j] + bw[lane * 8 + j]);
  *(uint4*)(xn + (size_t)tok * Cc + lane * 8) = *(uint4*)o;
}

// ------------- GEMM C[M,N] = A[M,K] @ B[N,K]^T, bf16 in, bf16 OR fp32 out, batched -------------
// LDS slot swizzle via pre-swizzled global_load_lds source (rule: swizzle source+read, dest
// linear): slot s of row r holds global column (s^(r&7))*8 -> fragment reads spread 64 lanes
// over all 32 banks (8-deep = b128 bandwidth floor; was 16-deep on 16 banks).
// SWZ: XCD-chunked block swizzle (1024 blocks = 8 XCDs x 128): same-A-panel blocks share an L2.
template <typename TC, bool SWZ>
__global__ __launch_bounds__(256) void gemm_bt(const bf16* __restrict__ A,
                                               const bf16* __restrict__ B,
                                               TC* __restrict__ C,
                                               int M, int N, int K,
                                               const float* __restrict__ bias,
                                               long sA_z, long sB_z, long sC_z) {
  A += (size_t)blockIdx.z * sA_z;
  B += (size_t)blockIdx.z * sB_z;
  C += (size_t)blockIdx.z * sC_z;
  __shared__ __align__(16) bf16 smem[16384];   // sA[128][64] | sB[128][64]; reused as ct[128][128]
  bf16* sA = smem;
  bf16* sB = smem + 8192;
  int t = threadIdx.x, w = t >> 6, lane = t & 63, fr = lane & 15, quad = lane >> 4;
  int n0, m0;
  if constexpr (SWZ) {
    int flat = blockIdx.y * 4 + blockIdx.x;    // 0..1023
    int idx  = (flat & 7) * 128 + (flat >> 3); // XCD k owns idx [128k,128k+128)
    n0 = (idx & 3) * 128;
    m0 = (idx >> 2) * 128;
  } else {
    n0 = blockIdx.x * 128;
    m0 = blockIdx.y * 128;
  }
  int wm = (w >> 1) * 64, wn = (w & 1) * 64;
  f32x4 acc[4][4] = {};

  for (int k0 = 0; k0 < K; k0 += 64) {
    __syncthreads();
#pragma unroll
    for (int c2 = 0; c2 < 4; ++c2) {
      int c = w * 4 + c2;                // 1KB chunk id, 0..15
      int row = c * 8 + (lane >> 3);     // 0..127
      int ke  = ((lane & 7) ^ (lane >> 3)) * 8;   // pre-swizzled source slot
      gl_lds16(A + (size_t)(m0 + row) * K + k0 + ke, (char*)sA + c * 1024);
      gl_lds16(B + (size_t)(n0 + row) * K + k0 + ke, (char*)sB + c * 1024);
    }
    __syncthreads();
#pragma unroll
    for (int kk = 0; kk < 64; kk += 32) {
      bfrag af[4], bg[4];
#pragma unroll
      for (int i = 0; i < 4; ++i)
        af[i] = *(const bfrag*)(sA + (wm + i * 16 + fr) * 64 +
                                ((((kk >> 3) + quad) ^ (fr & 7)) * 8));
#pragma unroll
      for (int j = 0; j < 4; ++j)
        bg[j] = *(const bfrag*)(sB + (wn + j * 16 + fr) * 64 +
                                ((((kk >> 3) + quad) ^ (fr & 7)) * 8));
#pragma unroll
      for (int i = 0; i < 4; ++i)
#pragma unroll
        for (int j = 0; j < 4; ++j)
          acc[i][j] = __builtin_amdgcn_mfma_f32_16x16x32_bf16(af[i], bg[j], acc[i][j], 0, 0, 0);
    }
  }

  if constexpr (__is_same(TC, float)) {
    // direct fp32 stores from C-fragment layout (col=fr, row=quad*4+r)
#pragma unroll
    for (int j = 0; j < 4; ++j) {
      float bj = bias ? bias[n0 + wn + j * 16 + fr] : 0.0f;
#pragma unroll
      for (int i = 0; i < 4; ++i)
#pragma unroll
        for (int r = 0; r < 4; ++r)
          C[(size_t)(m0 + wm + i * 16 + quad * 4 + r) * N + n0 + wn + j * 16 + fr] =
              acc[i][j][r] + bj;
    }
  } else {
    __syncthreads();
    bf16* ct = smem;                      // [128][128]
#pragma unroll
    for (int j = 0; j < 4; ++j) {
      float bj = bias ? bias[n0 + wn + j * 16 + fr] : 0.0f;
#pragma unroll
      for (int i = 0; i < 4; ++i)
#pragma unroll
        for (int r = 0; r < 4; ++r)
          ct[(wm + i * 16 + quad * 4 + r) * 128 + wn + j * 16 + fr] =
              __float2bfloat16(acc[i][j][r] + bj);
    }
    __syncthreads();
#pragma unroll
    for (int r8 = 0; r8 < 8; ++r8) {
      int row = r8 * 16 + (t >> 4);
      int ce  = (t & 15) * 8;
      *(uint4*)(C + (size_t)(m0 + row) * N + n0 + ce) = *(const uint4*)(smem + row * 128 + ce);
    }
  }
}

// ---- partials[split][b][tile] += Xb^T Xb — 64x128 upper-tri tiles (m <= 2n+1), split-K=4.
// NO atomics: each (tile,b,split) block owns a disjoint 32KB partial slot (plain stores);
// cvt_mirror sums the 4 splits. A-strip aliases into sB when contained; g3 slot swizzle;
// register-transpose staging + prefetch under compute.
__global__ __launch_bounds__(256) void xtx(const bf16* __restrict__ xn,
                                           float* __restrict__ part) {
  // grid = 640 = 8 XCDs * 80; XCD k handles batch b=k (stores L2-local)
  int flat = blockIdx.x;
  int idx  = (flat & 7) * 80 + (flat >> 3);
  int tile = idx % 20;
  int sb   = idx / 20;               // 0..31
  int split = sb & 3, b = sb >> 2;
  int nt = tile < 2 ? 0 : tile < 6 ? 1 : tile < 12 ? 2 : 3;
  int mt = tile - (nt == 0 ? 0 : nt == 1 ? 2 : nt == 2 ? 6 : 12);
  int m0 = mt * 64, n0 = nt * 128;
  bool alias = ((mt >> 1) == nt);    // A channels within B strip
  int t = threadIdx.x, w = t >> 6, lane = t & 63, fr = lane & 15, quad = lane >> 4;
  int wn = w * 32;                   // wave's 32-col slice of the 128-col tile
  __shared__ __align__(16) bf16 sB[8192];   // [128 ch][64 tok], g3-swizzled slots
  __shared__ __align__(16) bf16 sAb[4096];  // [64 ch][64 tok]
  bf16* sA = alias ? (sB + (mt & 1) * 4096) : sAb;
  f32x4 acc[4][2] = {};
  const bf16* xb = xn + ((size_t)b * Nn + split * 1024) * Cc;
  int ch0b = (t & 15) * 8, tgb = t >> 4;    // B staging: all threads, 4 tokens each
  int ch0a = (t & 7) * 8,  tga = t >> 3;    // A staging: threads t<128 only
  bool doA = (!alias) && (t < 128);
  unsigned swz = (unsigned)g3(t & 7);       // g3((ch0>>3)&7) for both A and B rows
  unsigned wposb = (((unsigned)(tgb >> 1) ^ swz) * 16u) + (unsigned)(tgb & 1) * 8u;
  unsigned wposa = (((unsigned)(tga >> 1) ^ swz) * 16u) + (unsigned)(tga & 1) * 8u;
  uint4 va[4], vb[4];
  // prologue: load chunk 0
#pragma unroll
  for (int j = 0; j < 4; ++j)
    vb[j] = *(const uint4*)(xb + (size_t)(tgb * 4 + j) * Cc + n0 + ch0b);
  if (doA)
#pragma unroll
    for (int j = 0; j < 4; ++j)
      va[j] = *(const uint4*)(xb + (size_t)(tga * 4 + j) * Cc + m0 + ch0a);
  for (int kc = 0; kc < 16; ++kc) {
    __syncthreads();                       // prev compute done; LDS reusable
    // register transpose 8ch x 4tok -> 8 x ds_write_b64 per operand
#pragma unroll
    for (int k = 0; k < 4; ++k) {
      unsigned b0 = ((const unsigned*)&vb[0])[k], b1 = ((const unsigned*)&vb[1])[k];
      unsigned b2 = ((const unsigned*)&vb[2])[k], b3 = ((const unsigned*)&vb[3])[k];
      uint2 lo = { (b0 & 0xffffu) | (b1 << 16), (b2 & 0xffffu) | (b3 << 16) };
      uint2 hi = { (b0 >> 16) | (b1 & 0xffff0000u), (b2 >> 16) | (b3 & 0xffff0000u) };
      *(uint2*)((char*)sB + (unsigned)(ch0b + 2 * k) * 128 + wposb) = lo;
      *(uint2*)((char*)sB + (unsigned)(ch0b + 2 * k + 1) * 128 + wposb) = hi;
    }
    if (doA) {
#pragma unroll
      for (int k = 0; k < 4; ++k) {
        unsigned a0 = ((const unsigned*)&va[0])[k], a1 = ((const unsigned*)&va[1])[k];
        unsigned a2 = ((const unsigned*)&va[2])[k], a3 = ((const unsigned*)&va[3])[k];
        uint2 lo = { (a0 & 0xffffu) | (a1 << 16), (a2 & 0xffffu) | (a3 << 16) };
        uint2 hi = { (a0 >> 16) | (a1 & 0xffff0000u), (a2 >> 16) | (a3 & 0xffff0000u) };
        *(uint2*)((char*)sAb + (unsigned)(ch0a + 2 * k) * 128 + wposa) = lo;
        *(uint2*)((char*)sAb + (unsigned)(ch0a + 2 * k + 1) * 128 + wposa) = hi;
      }
    }
    __syncthreads();                       // tile visible
    if (kc < 15) {                         // prefetch next chunk under compute
      const bf16* xb2 = xb + (size_t)(kc + 1) * 64 * Cc;
#pragma unroll
      for (int j = 0; j < 4; ++j)
        vb[j] = *(const uint4*)(xb2 + (size_t)(tgb * 4 + j) * Cc + n0 + ch0b);
      if (doA)
#pragma unroll
        for (int j = 0; j < 4; ++j)
          va[j] = *(const uint4*)(xb2 + (size_t)(tga * 4 + j) * Cc + m0 + ch0a);
    }
#pragma unroll
    for (int kk = 0; kk < 2; ++kk) {       // k-steps: tokens kk*32 .. kk*32+31
      bfrag af[4], bg[2];
#pragma unroll
      for (int i = 0; i < 4; ++i) {
        int ch = i * 16 + fr;
        int slot = (kk * 4 + quad) ^ g3((ch >> 3) & 7);
        af[i] = *(const bfrag*)(sA + ch * 64 + slot * 8);
      }
#pragma unroll
      for (int j = 0; j < 2; ++j) {
        int ch = wn + j * 16 + fr;
        int slot = (kk * 4 + quad) ^ g3((ch >> 3) & 7);
        bg[j] = *(const bfrag*)(sB + ch * 64 + slot * 8);
      }
#pragma unroll
      for (int i = 0; i < 4; ++i)
#pragma unroll
        for (int j = 0; j < 2; ++j)
          acc[i][j] = __builtin_amdgcn_mfma_f32_16x16x32_bf16(af[i], bg[j], acc[i][j], 0, 0, 0);
    }
  }
  float* pb = part + (size_t)split * SPL_STRIDE + ((size_t)b * 20 + tile) * 8192;
#pragma unroll
  for (int i = 0; i < 4; ++i)
#pragma unroll
    for (int j = 0; j < 2; ++j)
#pragma unroll
      for (int r = 0; r < 4; ++r)
        pb[(i * 16 + quad * 4 + r) * 128 + wn + j * 16 + fr] = acc[i][j][r];
}

// ---- per (b,h): Gram = T_q @ Wk^T (MFMA, K=512), norms via row-dots, softmax -> P bf16 ----
__global__ __launch_bounds__(256) void gram_softmax(const bf16* __restrict__ T,
                                                    const bf16* __restrict__ wq,
                                                    const float* __restrict__ temp,
                                                    bf16* __restrict__ P) {
  int h = blockIdx.x, b = blockIdx.y;
  int t = threadIdx.x, w = t >> 6, lane = t & 63, fr = lane & 15, quad = lane >> 4;
  const bf16* Tq = T + (size_t)b * 1024 * 512 + (size_t)(h * 64) * 512;
  const bf16* Tk = T + (size_t)b * 1024 * 512 + (size_t)(512 + h * 64) * 512;
  const bf16* Wqh = wq + (size_t)(h * 64) * 512;
  const bf16* Wkh = wq + (size_t)(512 + h * 64) * 512;
  f32x4 acc[4][4] = {};
#pragma unroll
  for (int s = 0; s < 4; ++s) {
    int kb = w * 128 + s * 32 + quad * 8;
    bfrag af[4], bg[4];
#pragma unroll
    for (int i = 0; i < 4; ++i) af[i] = *(const bfrag*)(Tq + (size_t)(i * 16 + fr) * 512 + kb);
#pragma unroll
    for (int j = 0; j < 4; ++j) bg[j] = *(const bfrag*)(Wkh + (size_t)(j * 16 + fr) * 512 + kb);
#pragma unroll
    for (int i = 0; i < 4; ++i)
#pragma unroll
      for (int j = 0; j < 4; ++j)
        acc[i][j] = __builtin_amdgcn_mfma_f32_16x16x32_bf16(af[i], bg[j], acc[i][j], 0, 0, 0);
  }
  __shared__ float parts[4 * 4096];
  __shared__ float nrm[2][4][64];
  __shared__ float nqk[2][64];
#pragma unroll
  for (int i = 0; i < 4; ++i)
#pragma unroll
    for (int j = 0; j < 4; ++j)
#pragma unroll
      for (int r = 0; r < 4; ++r)
        parts[w * 4096 + (i * 16 + quad * 4 + r) * 64 + j * 16 + fr] = acc[i][j][r];
  {
    int d = t & 63, qtr = t >> 6, c0 = qtr * 128;
    float pq = 0.f, pk = 0.f;
#pragma unroll 4
    for (int cc = 0; cc < 16; ++cc) {
      bf16 a[8], ww[8];
      *(uint4*)a  = *(const uint4*)(Tq + (size_t)d * 512 + c0 + cc * 8);
      *(uint4*)ww = *(const uint4*)(Wqh + (size_t)d * 512 + c0 + cc * 8);
#pragma unroll
      for (int j = 0; j < 8; ++j) pq += __bfloat162float(a[j]) * __bfloat162float(ww[j]);
      *(uint4*)a  = *(const uint4*)(Tk + (size_t)d * 512 + c0 + cc * 8);
      *(uint4*)ww = *(const uint4*)(Wkh + (size_t)d * 512 + c0 + cc * 8);
#pragma unroll
      for (int j = 0; j < 8; ++j) pk += __bfloat162float(a[j]) * __bfloat162float(ww[j]);
    }
    nrm[0][qtr][d] = pq;
    nrm[1][qtr][d] = pk;
  }
  __syncthreads();
  if (t < 64) {
    nqk[0][t] = fmaxf(sqrtf(nrm[0][0][t] + nrm[0][1][t] + nrm[0][2][t] + nrm[0][3][t]), 1e-12f);
    nqk[1][t] = fmaxf(sqrtf(nrm[1][0][t] + nrm[1][1][t] + nrm[1][2][t] + nrm[1][3][t]), 1e-12f);
  }
  __syncthreads();
  if (t < 64) {
    int d = t;
    float sc = temp[h] / nqk[0][d];
    float l[64]; float mx = -1e30f;
#pragma unroll
    for (int e = 0; e < 64; ++e) {
      float vsum = parts[d * 64 + e] + parts[4096 + d * 64 + e] +
                   parts[8192 + d * 64 + e] + parts[12288 + d * 64 + e];
      l[e] = vsum * sc / nqk[1][e];
      mx = fmaxf(mx, l[e]);
    }
    float sum = 0.f;
#pragma unroll
    for (int e = 0; e < 64; ++e) { l[e] = expf(l[e] - mx); sum += l[e]; }
    float inv = 1.0f / sum;
    bf16* pr = P + ((size_t)(b * 8 + h) * 64 + d) * 64;
#pragma unroll
    for (int e = 0; e < 64; ++e) pr[e] = __float2bfloat16(l[e] * inv);
  }
}

// ---- out = P @ v, exact GELU, store g[token][C] (bf16) ----
__global__ __launch_bounds__(256) void pv_gelu(const bf16* __restrict__ P,
                                               const bf16* __restrict__ v,
                                               bf16* __restrict__ g) {
  int chunk = blockIdx.x, h = blockIdx.y, b = blockIdx.z;
  int t = threadIdx.x, w = t >> 6, lane = t & 63, fr = lane & 15, quad = lane >> 4;
  const bf16* pb = P + (size_t)(b * 8 + h) * 4096;
  bfrag pf[4][2];
#pragma unroll
  for (int i = 0; i < 4; ++i)
#pragma unroll
    for (int c = 0; c < 2; ++c)
      pf[i][c] = *(const bfrag*)(pb + (i * 16 + fr) * 64 + c * 32 + quad * 8);
#pragma unroll 2
  for (int nt = 0; nt < 8; ++nt) {
    int ntok = chunk * 512 + w * 128 + nt * 16 + fr;
    const bf16* vrow = v + (size_t)(b * Nn + ntok) * Cc + h * 64 + quad * 8;
    bfrag bv0 = *(const bfrag*)(vrow);
    bfrag bv1 = *(const bfrag*)(vrow + 32);
    f32x4 acc[4] = {};
#pragma unroll
    for (int i = 0; i < 4; ++i) {
      acc[i] = __builtin_amdgcn_mfma_f32_16x16x32_bf16(pf[i][0], bv0, acc[i], 0, 0, 0);
      acc[i] = __builtin_amdgcn_mfma_f32_16x16x32_bf16(pf[i][1], bv1, acc[i], 0, 0, 0);
    }
    bf16* grow = g + (size_t)(b * Nn + ntok) * Cc + h * 64;
#pragma unroll
    for (int i = 0; i < 4; ++i) {
      bf16 o[4];
#pragma unroll
      for (int r = 0; r < 4; ++r) o[r] = __float2bfloat16(gelu_exact(acc[i][r]));
      *(uint2*)(grow + i * 16 + quad * 4) = *(uint2*)o;
    }
  }
}

extern "C" void kernel_launch(void* const* d_in, const int* in_sizes, int n_in,
                              void* d_out, int out_size, void* d_ws, size_t ws_size,
                              hipStream_t stream) {
  const float* x      = (const float*)d_in[0];
  const float* ln_g   = (const float*)d_in[1];
  const float* ln_b   = (const float*)d_in[2];
  const float* qkv_w  = (const float*)d_in[3];
  const float* temp   = (const float*)d_in[4];
  const float* proj_w = (const float*)d_in[5];
  const float* proj_b = (const float*)d_in[6];
  float* out = (float*)d_out;                       // fp32 output (reference returns float32)
  char*  ws  = (char*)d_ws;

  // --- runtime guards: silent failure -> measurable absmax signature ---
  const int exp_sizes[7] = {16777216, 512, 512, 786432, 8, 262144, 512};
  bool sizes_ok = (n_in == 7) && (out_size == 16777216);
  if (sizes_ok) for (int i = 0; i < 7; ++i) sizes_ok = sizes_ok && (in_sizes[i] == exp_sizes[i]);
  if (!sizes_ok) {
    fill_f32<<<(16777216 + 255) / 256, 256, 0, stream>>>(out, 500.0f, out_size);
    return;
  }
  if (ws_size < WS_NEED) {
    fill_f32<<<(16777216 + 255) / 256, 256, 0, stream>>>(out, (float)(ws_size >> 20), out_size);
    return;
  }

  bf16*  xn   = (bf16*)ws;                          // reused as g after xtx+vGEMM consume it
  bf16*  g    = (bf16*)ws;
  bf16*  Gcvb = (bf16*)(ws + 41943040);
  bf16*  T    = (bf16*)(ws + 46137344);
  bf16*  P    = (bf16*)(ws + 54525952);
  bf16*  wq   = (bf16*)(ws + 55050240);
  bf16*  wp   = (bf16*)(ws + 56623104);
  bf16*  v    = (bf16*)d_out;                       // park bf16 v in d_out lower half
  float* part = (float*)((char*)d_out + 33554432);  // xtx partials in d_out upper half (21 MB)

  cvt_f32_bf16<<<384, 256, 0, stream>>>(qkv_w, wq, QKVC * Cc);
  cvt_f32_bf16<<<128, 256, 0, stream>>>(proj_w, wp, Cc * Cc);
  ln_kernel<<<Mtok / 4, 256, 0, stream>>>(x, ln_g, ln_b, xn);
  // v = xn @ Wv^T (Wv = qkv_w rows 1024..1535)
  gemm_bt<bf16, true><<<dim3(4, 256, 1), 256, 0, stream>>>(xn, wq + 1024 * 512, v, Mtok, Cc, Cc,
                                                           nullptr, 0, 0, 0);
  xtx<<<640, 256, 0, stream>>>(xn, part);
  cvt_mirror<<<dim3(16, 8), 256, 0, stream>>>(part, Gcvb);
  // T[b] = Wqk @ Gcov[b]  (Gcov symmetric => @Gcov^T == @Gcov)
  gemm_bt<bf16, false><<<dim3(4, 8, 8), 256, 0, stream>>>(wq, Gcvb, T, 1024, Cc, Cc,
                                                          nullptr, 0, (long)Cc * Cc, (long)1024 * Cc);
  gram_softmax<<<dim3(Hh, Bb), 256, 0, stream>>>(T, wq, temp, P);
  pv_gelu<<<dim3(8, Hh, Bb), 256, 0, stream>>>(P, v, g);
  // out = g @ proj_w^T + proj_b  (fp32 stores, overwrites v + partials)
  gemm_bt<float, true><<<dim3(4, 256, 1), 256, 0, stream>>>(g, wp, out, Mtok, Cc, Cc,
                                                            proj_b, 0, 0, 0);
}

// Round 15
// 258.422 us; speedup vs baseline: 1.2451x; 1.0034x over previous
//
#include <hip/hip_runtime.h>
#include <hip/hip_bf16.h>

typedef __hip_bfloat16 bf16;
typedef __bf16 bfrag __attribute__((ext_vector_type(8)));   // 8 bf16 = 4 VGPRs (MFMA A/B operand)
typedef float f32x4 __attribute__((ext_vector_type(4)));    // MFMA C/D

#define AS1 __attribute__((address_space(1)))
#define AS3 __attribute__((address_space(3)))

static constexpr int Bb = 8, Nn = 4096, Cc = 512, Hh = 8;
static constexpr int Mtok = Bb * Nn;          // 32768
static constexpr int QKVC = 3 * Cc;           // 1536
// ws layout (NEED = 57,147,392 bytes; proven ws_size >= 59,768,832):
//  xn/g [0, 33554432)          bf16 [32768][512]
//  (Gcov region [33554432, 41943040) UNUSED — xtx partials live in d_out upper half)
//  Gcvb [41943040, 46137344)   bf16 [8][512][512]
//  T    [46137344, 54525952)   bf16 [8][1024][512]
//  P    [54525952, 55050240)   bf16 [8][8][64][64]
//  wq   [55050240, 56623104)   bf16 [1536][512]
//  wp   [56623104, 57147392)   bf16 [512][512]
// d_out (67.1 MB): v bf16 [0, 33554432); xtx partials f32 [33554432, 54525952);
//   both dead before the final GEMM writes out.
static constexpr size_t WS_NEED = 57147392;
static constexpr int SPL_STRIDE = 8 * 20 * 8192;   // floats per split in partial buffer

__device__ __forceinline__ void gl_lds16(const void* g, void* l) {
  __builtin_amdgcn_global_load_lds((const AS1 void*)g, (AS3 void*)l, 16, 0, 0);
}
__device__ __forceinline__ float gelu_exact(float x) {
  return 0.5f * x * (1.0f + erff(x * 0.70710678118654752f));
}
// 3-bit rotate-right-by-1: bijection used for LDS slot swizzle (conflict-free reads AND writes)
__device__ __forceinline__ int g3(int x) { return ((x & 1) << 2) | (x >> 1); }
// xtx tile id from (mt 64-row, nt 128-col) upper-tri indices; section sizes 2,4,6,8
__device__ __forceinline__ int tileid(int mt, int nt) {
  return mt + (nt == 0 ? 0 : nt == 1 ? 2 : nt == 2 ? 6 : 12);
}

// ---------------- diagnostic fill (fp32 output) ----------------
__global__ __launch_bounds__(256) void fill_f32(float* o, float val, int n) {
  int i = blockIdx.x * 256 + threadIdx.x;
  if (i < n) o[i] = val;
}

// ---------------- fused weight conversion: qkv_w -> wq, proj_w -> wp ----------------
__global__ __launch_bounds__(256) void cvt_w(const float* __restrict__ qkv_w,
                                             const float* __restrict__ proj_w,
                                             bf16* __restrict__ wq,
                                             bf16* __restrict__ wp) {
  int bid = blockIdx.x;
  const float* a;
  bf16* o;
  int i;
  if (bid < 384) { a = qkv_w;  o = wq; i = (bid * 256 + (int)threadIdx.x) * 8; }
  else           { a = proj_w; o = wp; i = ((bid - 384) * 256 + (int)threadIdx.x) * 8; }
  float f[8];
  *(float4*)f       = *(const float4*)(a + i);
  *(float4*)(f + 4) = *(const float4*)(a + i + 4);
  bf16 v[8];
#pragma unroll
  for (int j = 0; j < 8; ++j) v[j] = __float2bfloat16(f[j]);
  *(uint4*)(o + i) = *(uint4*)v;
}

// ---- sum 4 xtx split-partials -> Gcvb (full bf16); lower tiles mirrored via LDS ----
__global__ __launch_bounds__(256) void cvt_mirror(const float* __restrict__ part,
                                                  bf16* __restrict__ Gcvb) {
  int tile = blockIdx.x, b = blockIdx.y;
  int ti = tile >> 2, tj = tile & 3;
  int t = threadIdx.x;
  bf16* ob = Gcvb + (size_t)b * Cc * Cc;
  if (ti <= tj) {
    // direct: sum partials of tiles (2ti + row>>6, tj), convert, coalesced write
#pragma unroll
    for (int r8 = 0; r8 < 8; ++r8) {
      int row = r8 * 16 + (t >> 4), col = (t & 15) * 8;
      int mt = 2 * ti + (row >> 6), rsub = row & 63;
      const float* p0 = part + ((size_t)b * 20 + tileid(mt, tj)) * 8192 + rsub * 128 + col;
      float f[8];
      *(float4*)f       = *(const float4*)p0;
      *(float4*)(f + 4) = *(const float4*)(p0 + 4);
#pragma unroll
      for (int s = 1; s < 4; ++s) {
        const float* ps = p0 + (size_t)s * SPL_STRIDE;
        float g[8];
        *(float4*)g       = *(const float4*)ps;
        *(float4*)(g + 4) = *(const float4*)(ps + 4);
#pragma unroll
        for (int j = 0; j < 8; ++j) f[j] += g[j];
      }
      bf16 v[8];
#pragma unroll
      for (int j = 0; j < 8; ++j) v[j] = __float2bfloat16(f[j]);
      *(uint4*)(ob + (size_t)(ti * 128 + row) * Cc + tj * 128 + col) = *(uint4*)v;
    }
  } else {
    // mirror: sum partials of source tile (tj,ti) coalesced, transpose through LDS, write (ti,tj)
    __shared__ bf16 ls[128][136];          // pad 8 -> row stride 272B (16B-aligned)
#pragma unroll
    for (int r8 = 0; r8 < 8; ++r8) {
      int srow = r8 * 16 + (t >> 4), scol = (t & 15) * 8;
      int mt = 2 * tj + (srow >> 6), rsub = srow & 63;
      const float* p0 = part + ((size_t)b * 20 + tileid(mt, ti)) * 8192 + rsub * 128 + scol;
      float f[8];
      *(float4*)f       = *(const float4*)p0;
      *(float4*)(f + 4) = *(const float4*)(p0 + 4);
#pragma unroll
      for (int s = 1; s < 4; ++s) {
        const float* ps = p0 + (size_t)s * SPL_STRIDE;
        float g[8];
        *(float4*)g       = *(const float4*)ps;
        *(float4*)(g + 4) = *(const float4*)(ps + 4);
#pragma unroll
        for (int j = 0; j < 8; ++j) f[j] += g[j];
      }
      bf16 v[8];
#pragma unroll
      for (int j = 0; j < 8; ++j) v[j] = __float2bfloat16(f[j]);
      *(uint4*)&ls[srow][scol] = *(uint4*)v;
    }
    __syncthreads();
#pragma unroll
    for (int r8 = 0; r8 < 8; ++r8) {
      int orow = r8 * 16 + (t >> 4), ocol = (t & 15) * 8;
      bf16 v[8];
#pragma unroll
      for (int u = 0; u < 8; ++u) v[u] = ls[ocol + u][orow];
      *(uint4*)(ob + (size_t)(ti * 128 + orow) * Cc + tj * 128 + ocol) = *(uint4*)v;
    }
  }
}

// ---------------- LayerNorm (one wave per token), fp32 in -> bf16 out ----------------
__global__ __launch_bounds__(256) void ln_kernel(const float* __restrict__ x,
                                                 const float* __restrict__ gw,
                                                 const float* __restrict__ bw,
                                                 bf16* __restrict__ xn) {
  int tok  = blockIdx.x * 4 + (threadIdx.x >> 6);
  int lane = threadIdx.x & 63;
  const float* xr = x + (size_t)tok * Cc + lane * 8;
  float f[8];
  *(float4*)f       = *(const float4*)xr;
  *(float4*)(f + 4) = *(const float4*)(xr + 4);
  float s = 0.f;
#pragma unroll
  for (int j = 0; j < 8; ++j) s += f[j];
#pragma unroll
  for (int m = 32; m; m >>= 1) s += __shfl_xor(s, m);
  float mu = s * (1.0f / 512.0f);
  float q = 0.f;
#pragma unroll
  for (int j = 0; j < 8; ++j) { float d = f[j] - mu; q += d * d; }
#pragma unroll
  for (int m = 32; m; m >>= 1) q += __shfl_xor(q, m);
  float rstd = rsqrtf(q * (1.0f / 512.0f) + 1e-5f);
  bf16 o[8];
#pragma unroll
  for (int j = 0; j < 8; ++j)
    o[j] = __float2bfloat16((f[j] - mu) * rstd * gw[lane * 8 + j] + bw[lane * 8 + j]);
  *(uint4*)(xn + (size_t)tok * Cc + lane * 8) = *(uint4*)o;
}

// ------------- GEMM C[M,N] = A[M,K] @ B[N,K]^T, bf16 in, bf16 OR fp32 out, batched -------------
// LDS slot swizzle via pre-swizzled global_load_lds source (rule: swizzle source+read, dest
// linear): slot s of row r holds global column (s^(r&7))*8 -> fragment reads spread 64 lanes
// over all 32 banks (8-deep = b128 bandwidth floor; was 16-deep on 16 banks).
// SWZ: XCD-chunked block swizzle (1024 blocks = 8 XCDs x 128): same-A-panel blocks share an L2.
template <typename TC, bool SWZ>
__global__ __launch_bounds__(256) void gemm_bt(const bf16* __restrict__ A,
                                               const bf16* __restrict__ B,
                                               TC* __restrict__ C,
                                               int M, int N, int K,
                                               const float* __restrict__ bias,
                                               long sA_z, long sB_z, long sC_z) {
  A += (size_t)blockIdx.z * sA_z;
  B += (size_t)blockIdx.z * sB_z;
  C += (size_t)blockIdx.z * sC_z;
  __shared__ __align__(16) bf16 smem[16384];   // sA[128][64] | sB[128][64]; reused as ct[128][128]
  bf16* sA = smem;
  bf16* sB = smem + 8192;
  int t = threadIdx.x, w = t >> 6, lane = t & 63, fr = lane & 15, quad = lane >> 4;
  int n0, m0;
  if constexpr (SWZ) {
    int flat = blockIdx.y * 4 + blockIdx.x;    // 0..1023
    int idx  = (flat & 7) * 128 + (flat >> 3); // XCD k owns idx [128k,128k+128)
    n0 = (idx & 3) * 128;
    m0 = (idx >> 2) * 128;
  } else {
    n0 = blockIdx.x * 128;
    m0 = blockIdx.y * 128;
  }
  int wm = (w >> 1) * 64, wn = (w & 1) * 64;
  f32x4 acc[4][4] = {};

  for (int k0 = 0; k0 < K; k0 += 64) {
    __syncthreads();
#pragma unroll
    for (int c2 = 0; c2 < 4; ++c2) {
      int c = w * 4 + c2;                // 1KB chunk id, 0..15
      int row = c * 8 + (lane >> 3);     // 0..127
      int ke  = ((lane & 7) ^ (lane >> 3)) * 8;   // pre-swizzled source slot
      gl_lds16(A + (size_t)(m0 + row) * K + k0 + ke, (char*)sA + c * 1024);
      gl_lds16(B + (size_t)(n0 + row) * K + k0 + ke, (char*)sB + c * 1024);
    }
    __syncthreads();
#pragma unroll
    for (int kk = 0; kk < 64; kk += 32) {
      bfrag af[4], bg[4];
#pragma unroll
      for (int i = 0; i < 4; ++i)
        af[i] = *(const bfrag*)(sA + (wm + i * 16 + fr) * 64 +
                                ((((kk >> 3) + quad) ^ (fr & 7)) * 8));
#pragma unroll
      for (int j = 0; j < 4; ++j)
        bg[j] = *(const bfrag*)(sB + (wn + j * 16 + fr) * 64 +
                                ((((kk >> 3) + quad) ^ (fr & 7)) * 8));
#pragma unroll
      for (int i = 0; i < 4; ++i)
#pragma unroll
        for (int j = 0; j < 4; ++j)
          acc[i][j] = __builtin_amdgcn_mfma_f32_16x16x32_bf16(af[i], bg[j], acc[i][j], 0, 0, 0);
    }
  }

  if constexpr (__is_same(TC, float)) {
    // direct fp32 stores from C-fragment layout (col=fr, row=quad*4+r)
#pragma unroll
    for (int j = 0; j < 4; ++j) {
      float bj = bias ? bias[n0 + wn + j * 16 + fr] : 0.0f;
#pragma unroll
      for (int i = 0; i < 4; ++i)
#pragma unroll
        for (int r = 0; r < 4; ++r)
          C[(size_t)(m0 + wm + i * 16 + quad * 4 + r) * N + n0 + wn + j * 16 + fr] =
              acc[i][j][r] + bj;
    }
  } else {
    __syncthreads();
    bf16* ct = smem;                      // [128][128]
#pragma unroll
    for (int j = 0; j < 4; ++j) {
      float bj = bias ? bias[n0 + wn + j * 16 + fr] : 0.0f;
#pragma unroll
      for (int i = 0; i < 4; ++i)
#pragma unroll
        for (int r = 0; r < 4; ++r)
          ct[(wm + i * 16 + quad * 4 + r) * 128 + wn + j * 16 + fr] =
              __float2bfloat16(acc[i][j][r] + bj);
    }
    __syncthreads();
#pragma unroll
    for (int r8 = 0; r8 < 8; ++r8) {
      int row = r8 * 16 + (t >> 4);
      int ce  = (t & 15) * 8;
      *(uint4*)(C + (size_t)(m0 + row) * N + n0 + ce) = *(const uint4*)(smem + row * 128 + ce);
    }
  }
}

// ---- partials[split][b][tile] += Xb^T Xb — 64x128 upper-tri tiles (m <= 2n+1), split-K=4.
// NO atomics; DOUBLE-BUFFERED LDS: one barrier per 64-token chunk (was 2) — chunk k+1's
// register-transpose ds_writes overlap chunk k's MFMA. g3 slot swizzle; plain stores.
__global__ __launch_bounds__(256) void xtx(const bf16* __restrict__ xn,
                                           float* __restrict__ part) {
  // grid = 640 = 8 XCDs * 80; XCD k handles batch b=k (stores L2-local)
  int flat = blockIdx.x;
  int idx  = (flat & 7) * 80 + (flat >> 3);
  int tile = idx % 20;
  int sb   = idx / 20;               // 0..31
  int split = sb & 3, b = sb >> 2;
  int nt = tile < 2 ? 0 : tile < 6 ? 1 : tile < 12 ? 2 : 3;
  int mt = tile - (nt == 0 ? 0 : nt == 1 ? 2 : nt == 2 ? 6 : 12);
  int m0 = mt * 64, n0 = nt * 128;
  bool alias = ((mt >> 1) == nt);    // A channels within B strip
  int t = threadIdx.x, w = t >> 6, lane = t & 63, fr = lane & 15, quad = lane >> 4;
  int wn = w * 32;                   // wave's 32-col slice of the 128-col tile
  __shared__ __align__(16) bf16 sBd[2][8192];   // [128 ch][64 tok], g3-swizzled slots
  __shared__ __align__(16) bf16 sAd[2][4096];   // [64 ch][64 tok]
  f32x4 acc[4][2] = {};
  const bf16* xb = xn + ((size_t)b * Nn + split * 1024) * Cc;
  int ch0b = (t & 15) * 8, tgb = t >> 4;    // B staging: all threads, 4 tokens each
  int ch0a = (t & 7) * 8,  tga = t >> 3;    // A staging: threads t<128 only
  bool doA = (!alias) && (t < 128);
  unsigned swz = (unsigned)g3(t & 7);       // g3((ch0>>3)&7) for both A and B rows
  unsigned wposb = (((unsigned)(tgb >> 1) ^ swz) * 16u) + (unsigned)(tgb & 1) * 8u;
  unsigned wposa = (((unsigned)(tga >> 1) ^ swz) * 16u) + (unsigned)(tga & 1) * 8u;
  uint4 va[4], vb[4];

  auto load_chunk = [&](int kc) {
    const bf16* xc = xb + (size_t)kc * 64 * Cc;
#pragma unroll
    for (int j = 0; j < 4; ++j)
      vb[j] = *(const uint4*)(xc + (size_t)(tgb * 4 + j) * Cc + n0 + ch0b);
    if (doA)
#pragma unroll
      for (int j = 0; j < 4; ++j)
        va[j] = *(const uint4*)(xc + (size_t)(tga * 4 + j) * Cc + m0 + ch0a);
  };
  auto stage = [&](int bufi) {
    char* sBb = (char*)sBd[bufi];
    char* sAb = (char*)sAd[bufi];
#pragma unroll
    for (int k = 0; k < 4; ++k) {
      unsigned b0 = ((const unsigned*)&vb[0])[k], b1 = ((const unsigned*)&vb[1])[k];
      unsigned b2 = ((const unsigned*)&vb[2])[k], b3 = ((const unsigned*)&vb[3])[k];
      uint2 lo = { (b0 & 0xffffu) | (b1 << 16), (b2 & 0xffffu) | (b3 << 16) };
      uint2 hi = { (b0 >> 16) | (b1 & 0xffff0000u), (b2 >> 16) | (b3 & 0xffff0000u) };
      *(uint2*)(sBb + (unsigned)(ch0b + 2 * k) * 128 + wposb) = lo;
      *(uint2*)(sBb + (unsigned)(ch0b + 2 * k + 1) * 128 + wposb) = hi;
    }
    if (doA) {
#pragma unroll
      for (int k = 0; k < 4; ++k) {
        unsigned a0 = ((const unsigned*)&va[0])[k], a1 = ((const unsigned*)&va[1])[k];
        unsigned a2 = ((const unsigned*)&va[2])[k], a3 = ((const unsigned*)&va[3])[k];
        uint2 lo = { (a0 & 0xffffu) | (a1 << 16), (a2 & 0xffffu) | (a3 << 16) };
        uint2 hi = { (a0 >> 16) | (a1 & 0xffff0000u), (a2 >> 16) | (a3 & 0xffff0000u) };
        *(uint2*)(sAb + (unsigned)(ch0a + 2 * k) * 128 + wposa) = lo;
        *(uint2*)(sAb + (unsigned)(ch0a + 2 * k + 1) * 128 + wposa) = hi;
      }
    }
  };

  // prologue: chunk 0 -> buffer 0
  load_chunk(0);
  stage(0);
  for (int kc = 0; kc < 16; ++kc) {
    __syncthreads();                       // buf[kc&1] visible; buf[kc&1^1] free
    int cur = kc & 1, nxt = cur ^ 1;
    if (kc < 15) load_chunk(kc + 1);       // global latency hidden under compute below
    const bf16* sBp = sBd[cur];
    const bf16* sAp = alias ? (sBd[cur] + (mt & 1) * 4096) : sAd[cur];
#pragma unroll
    for (int kk = 0; kk < 2; ++kk) {       // k-steps: tokens kk*32 .. kk*32+31
      bfrag af[4], bg[2];
#pragma unroll
      for (int i = 0; i < 4; ++i) {
        int ch = i * 16 + fr;
        int slot = (kk * 4 + quad) ^ g3((ch >> 3) & 7);
        af[i] = *(const bfrag*)(sAp + ch * 64 + slot * 8);
      }
#pragma unroll
      for (int j = 0; j < 2; ++j) {
        int ch = wn + j * 16 + fr;
        int slot = (kk * 4 + quad) ^ g3((ch >> 3) & 7);
        bg[j] = *(const bfrag*)(sBp + ch * 64 + slot * 8);
      }
#pragma unroll
      for (int i = 0; i < 4; ++i)
#pragma unroll
        for (int j = 0; j < 2; ++j)
          acc[i][j] = __builtin_amdgcn_mfma_f32_16x16x32_bf16(af[i], bg[j], acc[i][j], 0, 0, 0);
    }
    if (kc < 15) stage(nxt);               // overlaps other waves' compute; synced next iter
  }
  float* pb = part + (size_t)split * SPL_STRIDE + ((size_t)b * 20 + tile) * 8192;
#pragma unroll
  for (int i = 0; i < 4; ++i)
#pragma unroll
    for (int j = 0; j < 2; ++j)
#pragma unroll
      for (int r = 0; r < 4; ++r)
        pb[(i * 16 + quad * 4 + r) * 128 + wn + j * 16 + fr] = acc[i][j][r];
}

// ---- per (b,h): Gram = T_q @ Wk^T (MFMA, K=512), norms via row-dots, softmax -> P bf16 ----
__global__ __launch_bounds__(256) void gram_softmax(const bf16* __restrict__ T,
                                                    const bf16* __restrict__ wq,
                                                    const float* __restrict__ temp,
                                                    bf16* __restrict__ P) {
  int h = blockIdx.x, b = blockIdx.y;
  int t = threadIdx.x, w = t >> 6, lane = t & 63, fr = lane & 15, quad = lane >> 4;
  const bf16* Tq = T + (size_t)b * 1024 * 512 + (size_t)(h * 64) * 512;
  const bf16* Tk = T + (size_t)b * 1024 * 512 + (size_t)(512 + h * 64) * 512;
  const bf16* Wqh = wq + (size_t)(h * 64) * 512;
  const bf16* Wkh = wq + (size_t)(512 + h * 64) * 512;
  f32x4 acc[4][4] = {};
#pragma unroll
  for (int s = 0; s < 4; ++s) {
    int kb = w * 128 + s * 32 + quad * 8;
    bfrag af[4], bg[4];
#pragma unroll
    for (int i = 0; i < 4; ++i) af[i] = *(const bfrag*)(Tq + (size_t)(i * 16 + fr) * 512 + kb);
#pragma unroll
    for (int j = 0; j < 4; ++j) bg[j] = *(const bfrag*)(Wkh + (size_t)(j * 16 + fr) * 512 + kb);
#pragma unroll
    for (int i = 0; i < 4; ++i)
#pragma unroll
      for (int j = 0; j < 4; ++j)
        acc[i][j] = __builtin_amdgcn_mfma_f32_16x16x32_bf16(af[i], bg[j], acc[i][j], 0, 0, 0);
  }
  __shared__ float parts[4 * 4096];
  __shared__ float nrm[2][4][64];
  __shared__ float nqk[2][64];
#pragma unroll
  for (int i = 0; i < 4; ++i)
#pragma unroll
    for (int j = 0; j < 4; ++j)
#pragma unroll
      for (int r = 0; r < 4; ++r)
        parts[w * 4096 + (i * 16 + quad * 4 + r) * 64 + j * 16 + fr] = acc[i][j][r];
  {
    int d = t & 63, qtr = t >> 6, c0 = qtr * 128;
    float pq = 0.f, pk = 0.f;
#pragma unroll 4
    for (int cc = 0; cc < 16; ++cc) {
      bf16 a[8], ww[8];
      *(uint4*)a  = *(const uint4*)(Tq + (size_t)d * 512 + c0 + cc * 8);
      *(uint4*)ww = *(const uint4*)(Wqh + (size_t)d * 512 + c0 + cc * 8);
#pragma unroll
      for (int j = 0; j < 8; ++j) pq += __bfloat162float(a[j]) * __bfloat162float(ww[j]);
      *(uint4*)a  = *(const uint4*)(Tk + (size_t)d * 512 + c0 + cc * 8);
      *(uint4*)ww = *(const uint4*)(Wkh + (size_t)d * 512 + c0 + cc * 8);
#pragma unroll
      for (int j = 0; j < 8; ++j) pk += __bfloat162float(a[j]) * __bfloat162float(ww[j]);
    }
    nrm[0][qtr][d] = pq;
    nrm[1][qtr][d] = pk;
  }
  __syncthreads();
  if (t < 64) {
    nqk[0][t] = fmaxf(sqrtf(nrm[0][0][t] + nrm[0][1][t] + nrm[0][2][t] + nrm[0][3][t]), 1e-12f);
    nqk[1][t] = fmaxf(sqrtf(nrm[1][0][t] + nrm[1][1][t] + nrm[1][2][t] + nrm[1][3][t]), 1e-12f);
  }
  __syncthreads();
  if (t < 64) {
    int d = t;
    float sc = temp[h] / nqk[0][d];
    float l[64]; float mx = -1e30f;
#pragma unroll
    for (int e = 0; e < 64; ++e) {
      float vsum = parts[d * 64 + e] + parts[4096 + d * 64 + e] +
                   parts[8192 + d * 64 + e] + parts[12288 + d * 64 + e];
      l[e] = vsum * sc / nqk[1][e];
      mx = fmaxf(mx, l[e]);
    }
    float sum = 0.f;
#pragma unroll
    for (int e = 0; e < 64; ++e) { l[e] = expf(l[e] - mx); sum += l[e]; }
    float inv = 1.0f / sum;
    bf16* pr = P + ((size_t)(b * 8 + h) * 64 + d) * 64;
#pragma unroll
    for (int e = 0; e < 64; ++e) pr[e] = __float2bfloat16(l[e] * inv);
  }
}

// ---- out = P @ v, exact GELU, store g[token][C] (bf16) ----
__global__ __launch_bounds__(256) void pv_gelu(const bf16* __restrict__ P,
                                               const bf16* __restrict__ v,
                                               bf16* __restrict__ g) {
  int chunk = blockIdx.x, h = blockIdx.y, b = blockIdx.z;
  int t = threadIdx.x, w = t >> 6, lane = t & 63, fr = lane & 15, quad = lane >> 4;
  const bf16* pb = P + (size_t)(b * 8 + h) * 4096;
  bfrag pf[4][2];
#pragma unroll
  for (int i = 0; i < 4; ++i)
#pragma unroll
    for (int c = 0; c < 2; ++c)
      pf[i][c] = *(const bfrag*)(pb + (i * 16 + fr) * 64 + c * 32 + quad * 8);
#pragma unroll 2
  for (int nt = 0; nt < 8; ++nt) {
    int ntok = chunk * 512 + w * 128 + nt * 16 + fr;
    const bf16* vrow = v + (size_t)(b * Nn + ntok) * Cc + h * 64 + quad * 8;
    bfrag bv0 = *(const bfrag*)(vrow);
    bfrag bv1 = *(const bfrag*)(vrow + 32);
    f32x4 acc[4] = {};
#pragma unroll
    for (int i = 0; i < 4; ++i) {
      acc[i] = __builtin_amdgcn_mfma_f32_16x16x32_bf16(pf[i][0], bv0, acc[i], 0, 0, 0);
      acc[i] = __builtin_amdgcn_mfma_f32_16x16x32_bf16(pf[i][1], bv1, acc[i], 0, 0, 0);
    }
    bf16* grow = g + (size_t)(b * Nn + ntok) * Cc + h * 64;
#pragma unroll
    for (int i = 0; i < 4; ++i) {
      bf16 o[4];
#pragma unroll
      for (int r = 0; r < 4; ++r) o[r] = __float2bfloat16(gelu_exact(acc[i][r]));
      *(uint2*)(grow + i * 16 + quad * 4) = *(uint2*)o;
    }
  }
}

extern "C" void kernel_launch(void* const* d_in, const int* in_sizes, int n_in,
                              void* d_out, int out_size, void* d_ws, size_t ws_size,
                              hipStream_t stream) {
  const float* x      = (const float*)d_in[0];
  const float* ln_g   = (const float*)d_in[1];
  const float* ln_b   = (const float*)d_in[2];
  const float* qkv_w  = (const float*)d_in[3];
  const float* temp   = (const float*)d_in[4];
  const float* proj_w = (const float*)d_in[5];
  const float* proj_b = (const float*)d_in[6];
  float* out = (float*)d_out;                       // fp32 output (reference returns float32)
  char*  ws  = (char*)d_ws;

  // --- runtime guards: silent failure -> measurable absmax signature ---
  const int exp_sizes[7] = {16777216, 512, 512, 786432, 8, 262144, 512};
  bool sizes_ok = (n_in == 7) && (out_size == 16777216);
  if (sizes_ok) for (int i = 0; i < 7; ++i) sizes_ok = sizes_ok && (in_sizes[i] == exp_sizes[i]);
  if (!sizes_ok) {
    fill_f32<<<(16777216 + 255) / 256, 256, 0, stream>>>(out, 500.0f, out_size);
    return;
  }
  if (ws_size < WS_NEED) {
    fill_f32<<<(16777216 + 255) / 256, 256, 0, stream>>>(out, (float)(ws_size >> 20), out_size);
    return;
  }

  bf16*  xn   = (bf16*)ws;                          // reused as g after xtx+vGEMM consume it
  bf16*  g    = (bf16*)ws;
  bf16*  Gcvb = (bf16*)(ws + 41943040);
  bf16*  T    = (bf16*)(ws + 46137344);
  bf16*  P    = (bf16*)(ws + 54525952);
  bf16*  wq   = (bf16*)(ws + 55050240);
  bf16*  wp   = (bf16*)(ws + 56623104);
  bf16*  v    = (bf16*)d_out;                       // park bf16 v in d_out lower half
  float* part = (float*)((char*)d_out + 33554432);  // xtx partials in d_out upper half (21 MB)

  cvt_w<<<512, 256, 0, stream>>>(qkv_w, proj_w, wq, wp);
  ln_kernel<<<Mtok / 4, 256, 0, stream>>>(x, ln_g, ln_b, xn);
  // v = xn @ Wv^T (Wv = qkv_w rows 1024..1535)
  gemm_bt<bf16, true><<<dim3(4, 256, 1), 256, 0, stream>>>(xn, wq + 1024 * 512, v, Mtok, Cc, Cc,
                                                           nullptr, 0, 0, 0);
  xtx<<<640, 256, 0, stream>>>(xn, part);
  cvt_mirror<<<dim3(16, 8), 256, 0, stream>>>(part, Gcvb);
  // T[b] = Wqk @ Gcov[b]  (Gcov symmetric => @Gcov^T == @Gcov)
  gemm_bt<bf16, false><<<dim3(4, 8, 8), 256, 0, stream>>>(wq, Gcvb, T, 1024, Cc, Cc,
                                                          nullptr, 0, (long)Cc * Cc, (long)1024 * Cc);
  gram_softmax<<<dim3(Hh, Bb), 256, 0, stream>>>(T, wq, temp, P);
  pv_gelu<<<dim3(8, Hh, Bb), 256, 0, stream>>>(P, v, g);
  // out = g @ proj_w^T + proj_b  (fp32 stores, overwrites v + partials)
  gemm_bt<float, true><<<dim3(4, 256, 1), 256, 0, stream>>>(g, wp, out, Mtok, Cc, Cc,
                                                            proj_b, 0, 0, 0);
}

// Round 16
// 258.079 us; speedup vs baseline: 1.2468x; 1.0013x over previous
//
#include <hip/hip_runtime.h>
#include <hip/hip_bf16.h>

typedef __hip_bfloat16 bf16;
typedef __bf16 bfrag __attribute__((ext_vector_type(8)));   // 8 bf16 = 4 VGPRs (MFMA A/B operand)
typedef float f32x4 __attribute__((ext_vector_type(4)));    // MFMA C/D

#define AS1 __attribute__((address_space(1)))
#define AS3 __attribute__((address_space(3)))

static constexpr int Bb = 8, Nn = 4096, Cc = 512, Hh = 8;
static constexpr int Mtok = Bb * Nn;          // 32768
static constexpr int QKVC = 3 * Cc;           // 1536
// ws layout (NEED = 57,147,392 bytes; proven ws_size >= 59,768,832):
//  xn/g [0, 33554432)          bf16 [32768][512]
//  (Gcov region UNUSED — xtx partials live in d_out upper half)
//  Gcvb [41943040, 46137344)   bf16 [8][512][512]
//  T    [46137344, 54525952)   bf16 [8][1024][512]
//  P    [54525952, 55050240)   bf16 [8][8][64][64]
//  wq   [55050240, 56623104)   bf16 [1536][512]
//  wp   [56623104, 57147392)   bf16 [512][512]
// d_out (67.1 MB): v bf16 [0, 33554432); xtx partials f32 [33554432, 54525952);
//   both dead before the final GEMM writes out.
static constexpr size_t WS_NEED = 57147392;
static constexpr int SPL_STRIDE = 8 * 20 * 8192;   // floats per split in partial buffer

__device__ __forceinline__ void gl_lds16(const void* g, void* l) {
  __builtin_amdgcn_global_load_lds((const AS1 void*)g, (AS3 void*)l, 16, 0, 0);
}
__device__ __forceinline__ float gelu_exact(float x) {
  return 0.5f * x * (1.0f + erff(x * 0.70710678118654752f));
}
// 3-bit rotate-right-by-1: bijection used for LDS slot swizzle (conflict-free reads AND writes)
__device__ __forceinline__ int g3(int x) { return ((x & 1) << 2) | (x >> 1); }
// xtx tile id from (mt 64-row, nt 128-col) upper-tri indices; section sizes 2,4,6,8
__device__ __forceinline__ int tileid(int mt, int nt) {
  return mt + (nt == 0 ? 0 : nt == 1 ? 2 : nt == 2 ? 6 : 12);
}

// ---------------- diagnostic fill (fp32 output) ----------------
__global__ __launch_bounds__(256) void fill_f32(float* o, float val, int n) {
  int i = blockIdx.x * 256 + threadIdx.x;
  if (i < n) o[i] = val;
}

// ------- fused: LayerNorm (blocks 0..8191) + weight conversion (blocks 8192..8703) -------
__global__ __launch_bounds__(256) void ln_cvtw(const float* __restrict__ x,
                                               const float* __restrict__ gw,
                                               const float* __restrict__ bw,
                                               bf16* __restrict__ xn,
                                               const float* __restrict__ qkv_w,
                                               const float* __restrict__ proj_w,
                                               bf16* __restrict__ wq,
                                               bf16* __restrict__ wp) {
  int bid = blockIdx.x;
  if (bid < 8192) {
    int tok  = bid * 4 + (threadIdx.x >> 6);
    int lane = threadIdx.x & 63;
    const float* xr = x + (size_t)tok * Cc + lane * 8;
    float f[8];
    *(float4*)f       = *(const float4*)xr;
    *(float4*)(f + 4) = *(const float4*)(xr + 4);
    float s = 0.f;
#pragma unroll
    for (int j = 0; j < 8; ++j) s += f[j];
#pragma unroll
    for (int m = 32; m; m >>= 1) s += __shfl_xor(s, m);
    float mu = s * (1.0f / 512.0f);
    float q = 0.f;
#pragma unroll
    for (int j = 0; j < 8; ++j) { float d = f[j] - mu; q += d * d; }
#pragma unroll
    for (int m = 32; m; m >>= 1) q += __shfl_xor(q, m);
    float rstd = rsqrtf(q * (1.0f / 512.0f) + 1e-5f);
    bf16 o[8];
#pragma unroll
    for (int j = 0; j < 8; ++j)
      o[j] = __float2bfloat16((f[j] - mu) * rstd * gw[lane * 8 + j] + bw[lane * 8 + j]);
    *(uint4*)(xn + (size_t)tok * Cc + lane * 8) = *(uint4*)o;
  } else {
    int cb = bid - 8192;
    const float* a;
    bf16* o;
    int i;
    if (cb < 384) { a = qkv_w;  o = wq; i = (cb * 256 + (int)threadIdx.x) * 8; }
    else          { a = proj_w; o = wp; i = ((cb - 384) * 256 + (int)threadIdx.x) * 8; }
    float f[8];
    *(float4*)f       = *(const float4*)(a + i);
    *(float4*)(f + 4) = *(const float4*)(a + i + 4);
    bf16 vv[8];
#pragma unroll
    for (int j = 0; j < 8; ++j) vv[j] = __float2bfloat16(f[j]);
    *(uint4*)(o + i) = *(uint4*)vv;
  }
}

// ---- sum 4 xtx split-partials -> Gcvb (full bf16); lower tiles mirrored via LDS ----
__global__ __launch_bounds__(256) void cvt_mirror(const float* __restrict__ part,
                                                  bf16* __restrict__ Gcvb) {
  int tile = blockIdx.x, b = blockIdx.y;
  int ti = tile >> 2, tj = tile & 3;
  int t = threadIdx.x;
  bf16* ob = Gcvb + (size_t)b * Cc * Cc;
  if (ti <= tj) {
    // direct: sum partials of tiles (2ti + row>>6, tj), convert, coalesced write
#pragma unroll
    for (int r8 = 0; r8 < 8; ++r8) {
      int row = r8 * 16 + (t >> 4), col = (t & 15) * 8;
      int mt = 2 * ti + (row >> 6), rsub = row & 63;
      const float* p0 = part + ((size_t)b * 20 + tileid(mt, tj)) * 8192 + rsub * 128 + col;
      float f[8];
      *(float4*)f       = *(const float4*)p0;
      *(float4*)(f + 4) = *(const float4*)(p0 + 4);
#pragma unroll
      for (int s = 1; s < 4; ++s) {
        const float* ps = p0 + (size_t)s * SPL_STRIDE;
        float g[8];
        *(float4*)g       = *(const float4*)ps;
        *(float4*)(g + 4) = *(const float4*)(ps + 4);
#pragma unroll
        for (int j = 0; j < 8; ++j) f[j] += g[j];
      }
      bf16 v[8];
#pragma unroll
      for (int j = 0; j < 8; ++j) v[j] = __float2bfloat16(f[j]);
      *(uint4*)(ob + (size_t)(ti * 128 + row) * Cc + tj * 128 + col) = *(uint4*)v;
    }
  } else {
    // mirror: sum partials of source tile (tj,ti) coalesced, transpose through LDS, write (ti,tj)
    __shared__ bf16 ls[128][136];          // pad 8 -> row stride 272B (16B-aligned)
#pragma unroll
    for (int r8 = 0; r8 < 8; ++r8) {
      int srow = r8 * 16 + (t >> 4), scol = (t & 15) * 8;
      int mt = 2 * tj + (srow >> 6), rsub = srow & 63;
      const float* p0 = part + ((size_t)b * 20 + tileid(mt, ti)) * 8192 + rsub * 128 + scol;
      float f[8];
      *(float4*)f       = *(const float4*)p0;
      *(float4*)(f + 4) = *(const float4*)(p0 + 4);
#pragma unroll
      for (int s = 1; s < 4; ++s) {
        const float* ps = p0 + (size_t)s * SPL_STRIDE;
        float g[8];
        *(float4*)g       = *(const float4*)ps;
        *(float4*)(g + 4) = *(const float4*)(ps + 4);
#pragma unroll
        for (int j = 0; j < 8; ++j) f[j] += g[j];
      }
      bf16 v[8];
#pragma unroll
      for (int j = 0; j < 8; ++j) v[j] = __float2bfloat16(f[j]);
      *(uint4*)&ls[srow][scol] = *(uint4*)v;
    }
    __syncthreads();
#pragma unroll
    for (int r8 = 0; r8 < 8; ++r8) {
      int orow = r8 * 16 + (t >> 4), ocol = (t & 15) * 8;
      bf16 v[8];
#pragma unroll
      for (int u = 0; u < 8; ++u) v[u] = ls[ocol + u][orow];
      *(uint4*)(ob + (size_t)(ti * 128 + orow) * Cc + tj * 128 + ocol) = *(uint4*)v;
    }
  }
}

// ------------- GEMM C[M,N] = A[M,K] @ B[N,K]^T, bf16 in, bf16 OR fp32 out, batched -------------
// LDS slot swizzle via pre-swizzled global_load_lds source; SWZ = XCD-chunked block swizzle.
template <typename TC, bool SWZ>
__global__ __launch_bounds__(256) void gemm_bt(const bf16* __restrict__ A,
                                               const bf16* __restrict__ B,
                                               TC* __restrict__ C,
                                               int M, int N, int K,
                                               const float* __restrict__ bias,
                                               long sA_z, long sB_z, long sC_z) {
  A += (size_t)blockIdx.z * sA_z;
  B += (size_t)blockIdx.z * sB_z;
  C += (size_t)blockIdx.z * sC_z;
  __shared__ __align__(16) bf16 smem[16384];   // sA[128][64] | sB[128][64]; reused as ct[128][128]
  bf16* sA = smem;
  bf16* sB = smem + 8192;
  int t = threadIdx.x, w = t >> 6, lane = t & 63, fr = lane & 15, quad = lane >> 4;
  int n0, m0;
  if constexpr (SWZ) {
    int flat = blockIdx.y * 4 + blockIdx.x;    // 0..1023
    int idx  = (flat & 7) * 128 + (flat >> 3); // XCD k owns idx [128k,128k+128)
    n0 = (idx & 3) * 128;
    m0 = (idx >> 2) * 128;
  } else {
    n0 = blockIdx.x * 128;
    m0 = blockIdx.y * 128;
  }
  int wm = (w >> 1) * 64, wn = (w & 1) * 64;
  f32x4 acc[4][4] = {};

  for (int k0 = 0; k0 < K; k0 += 64) {
    __syncthreads();
#pragma unroll
    for (int c2 = 0; c2 < 4; ++c2) {
      int c = w * 4 + c2;                // 1KB chunk id, 0..15
      int row = c * 8 + (lane >> 3);     // 0..127
      int ke  = ((lane & 7) ^ (lane >> 3)) * 8;   // pre-swizzled source slot
      gl_lds16(A + (size_t)(m0 + row) * K + k0 + ke, (char*)sA + c * 1024);
      gl_lds16(B + (size_t)(n0 + row) * K + k0 + ke, (char*)sB + c * 1024);
    }
    __syncthreads();
#pragma unroll
    for (int kk = 0; kk < 64; kk += 32) {
      bfrag af[4], bg[4];
#pragma unroll
      for (int i = 0; i < 4; ++i)
        af[i] = *(const bfrag*)(sA + (wm + i * 16 + fr) * 64 +
                                ((((kk >> 3) + quad) ^ (fr & 7)) * 8));
#pragma unroll
      for (int j = 0; j < 4; ++j)
        bg[j] = *(const bfrag*)(sB + (wn + j * 16 + fr) * 64 +
                                ((((kk >> 3) + quad) ^ (fr & 7)) * 8));
#pragma unroll
      for (int i = 0; i < 4; ++i)
#pragma unroll
        for (int j = 0; j < 4; ++j)
          acc[i][j] = __builtin_amdgcn_mfma_f32_16x16x32_bf16(af[i], bg[j], acc[i][j], 0, 0, 0);
    }
  }

  if constexpr (__is_same(TC, float)) {
    // direct fp32 stores from C-fragment layout (col=fr, row=quad*4+r)
#pragma unroll
    for (int j = 0; j < 4; ++j) {
      float bj = bias ? bias[n0 + wn + j * 16 + fr] : 0.0f;
#pragma unroll
      for (int i = 0; i < 4; ++i)
#pragma unroll
        for (int r = 0; r < 4; ++r)
          C[(size_t)(m0 + wm + i * 16 + quad * 4 + r) * N + n0 + wn + j * 16 + fr] =
              acc[i][j][r] + bj;
    }
  } else {
    __syncthreads();
    bf16* ct = smem;                      // [128][128]
#pragma unroll
    for (int j = 0; j < 4; ++j) {
      float bj = bias ? bias[n0 + wn + j * 16 + fr] : 0.0f;
#pragma unroll
      for (int i = 0; i < 4; ++i)
#pragma unroll
        for (int r = 0; r < 4; ++r)
          ct[(wm + i * 16 + quad * 4 + r) * 128 + wn + j * 16 + fr] =
              __float2bfloat16(acc[i][j][r] + bj);
    }
    __syncthreads();
#pragma unroll
    for (int r8 = 0; r8 < 8; ++r8) {
      int row = r8 * 16 + (t >> 4);
      int ce  = (t & 15) * 8;
      *(uint4*)(C + (size_t)(m0 + row) * N + n0 + ce) = *(const uint4*)(smem + row * 128 + ce);
    }
  }
}

// ---- fused: v = xn @ wv^T (blocks 0..1023) + xtx partials (blocks 1024..1663) ----
// Both consume only xn and are independent -> one launch; v-GEMM tail backfills with
// xtx blocks. Shared 32KB static LDS; occupancy 5 blocks/CU for both paths.
__global__ __launch_bounds__(256) void vgemm_xtx(const bf16* __restrict__ xn,
                                                 const bf16* __restrict__ wv,
                                                 bf16* __restrict__ v,
                                                 float* __restrict__ part) {
  __shared__ __align__(16) bf16 smem[16384];   // 32 KB, both paths
  int t = threadIdx.x, w = t >> 6, lane = t & 63, fr = lane & 15, quad = lane >> 4;
  if (blockIdx.x < 1024) {
    // ======== v-GEMM path (identical body to gemm_bt<bf16,true>, M=32768,N=512,K=512) ========
    bf16* sA = smem;
    bf16* sB = smem + 8192;
    int flat = blockIdx.x;
    int idx  = (flat & 7) * 128 + (flat >> 3);
    int n0 = (idx & 3) * 128, m0 = (idx >> 2) * 128;
    int wm = (w >> 1) * 64, wn = (w & 1) * 64;
    f32x4 acc[4][4] = {};
    for (int k0 = 0; k0 < 512; k0 += 64) {
      __syncthreads();
#pragma unroll
      for (int c2 = 0; c2 < 4; ++c2) {
        int c = w * 4 + c2;
        int row = c * 8 + (lane >> 3);
        int ke  = ((lane & 7) ^ (lane >> 3)) * 8;
        gl_lds16(xn + (size_t)(m0 + row) * 512 + k0 + ke, (char*)sA + c * 1024);
        gl_lds16(wv + (size_t)(n0 + row) * 512 + k0 + ke, (char*)sB + c * 1024);
      }
      __syncthreads();
#pragma unroll
      for (int kk = 0; kk < 64; kk += 32) {
        bfrag af[4], bg[4];
#pragma unroll
        for (int i = 0; i < 4; ++i)
          af[i] = *(const bfrag*)(sA + (wm + i * 16 + fr) * 64 +
                                  ((((kk >> 3) + quad) ^ (fr & 7)) * 8));
#pragma unroll
        for (int j = 0; j < 4; ++j)
          bg[j] = *(const bfrag*)(sB + (wn + j * 16 + fr) * 64 +
                                  ((((kk >> 3) + quad) ^ (fr & 7)) * 8));
#pragma unroll
        for (int i = 0; i < 4; ++i)
#pragma unroll
          for (int j = 0; j < 4; ++j)
            acc[i][j] = __builtin_amdgcn_mfma_f32_16x16x32_bf16(af[i], bg[j], acc[i][j], 0, 0, 0);
      }
    }
    __syncthreads();
    bf16* ct = smem;                      // [128][128]
#pragma unroll
    for (int j = 0; j < 4; ++j)
#pragma unroll
      for (int i = 0; i < 4; ++i)
#pragma unroll
        for (int r = 0; r < 4; ++r)
          ct[(wm + i * 16 + quad * 4 + r) * 128 + wn + j * 16 + fr] =
              __float2bfloat16(acc[i][j][r]);
    __syncthreads();
#pragma unroll
    for (int r8 = 0; r8 < 8; ++r8) {
      int row = r8 * 16 + (t >> 4);
      int ce  = (t & 15) * 8;
      *(uint4*)(v + (size_t)(m0 + row) * 512 + n0 + ce) = *(const uint4*)(smem + row * 128 + ce);
    }
  } else {
    // ======== xtx path (single-buffered 64x128 upper-tri, split-4, plain stores) ========
    bf16* sB  = smem;                    // [128 ch][64 tok], g3-swizzled slots (16 KB)
    bf16* sAb = smem + 8192;             // [64 ch][64 tok] (8 KB)
    int flat = blockIdx.x - 1024;        // 0..639 = 8 XCDs * 80
    int idx  = (flat & 7) * 80 + (flat >> 3);
    int tile = idx % 20;
    int sb   = idx / 20;                 // 0..31
    int split = sb & 3, b = sb >> 2;
    int nt = tile < 2 ? 0 : tile < 6 ? 1 : tile < 12 ? 2 : 3;
    int mt = tile - (nt == 0 ? 0 : nt == 1 ? 2 : nt == 2 ? 6 : 12);
    int m0 = mt * 64, n0 = nt * 128;
    bool alias = ((mt >> 1) == nt);      // A channels within B strip
    int wn = w * 32;                     // wave's 32-col slice of the 128-col tile
    bf16* sA = alias ? (sB + (mt & 1) * 4096) : sAb;
    f32x4 acc[4][2] = {};
    const bf16* xb = xn + ((size_t)b * Nn + split * 1024) * Cc;
    int ch0b = (t & 15) * 8, tgb = t >> 4;    // B staging: all threads, 4 tokens each
    int ch0a = (t & 7) * 8,  tga = t >> 3;    // A staging: threads t<128 only
    bool doA = (!alias) && (t < 128);
    unsigned swz = (unsigned)g3(t & 7);
    unsigned wposb = (((unsigned)(tgb >> 1) ^ swz) * 16u) + (unsigned)(tgb & 1) * 8u;
    unsigned wposa = (((unsigned)(tga >> 1) ^ swz) * 16u) + (unsigned)(tga & 1) * 8u;
    uint4 va[4], vb[4];
    // prologue: load chunk 0
#pragma unroll
    for (int j = 0; j < 4; ++j)
      vb[j] = *(const uint4*)(xb + (size_t)(tgb * 4 + j) * Cc + n0 + ch0b);
    if (doA)
#pragma unroll
      for (int j = 0; j < 4; ++j)
        va[j] = *(const uint4*)(xb + (size_t)(tga * 4 + j) * Cc + m0 + ch0a);
    for (int kc = 0; kc < 16; ++kc) {
      __syncthreads();                       // prev compute done; LDS reusable
      // register transpose 8ch x 4tok -> 8 x ds_write_b64 per operand
#pragma unroll
      for (int k = 0; k < 4; ++k) {
        unsigned b0 = ((const unsigned*)&vb[0])[k], b1 = ((const unsigned*)&vb[1])[k];
        unsigned b2 = ((const unsigned*)&vb[2])[k], b3 = ((const unsigned*)&vb[3])[k];
        uint2 lo = { (b0 & 0xffffu) | (b1 << 16), (b2 & 0xffffu) | (b3 << 16) };
        uint2 hi = { (b0 >> 16) | (b1 & 0xffff0000u), (b2 >> 16) | (b3 & 0xffff0000u) };
        *(uint2*)((char*)sB + (unsigned)(ch0b + 2 * k) * 128 + wposb) = lo;
        *(uint2*)((char*)sB + (unsigned)(ch0b + 2 * k + 1) * 128 + wposb) = hi;
      }
      if (doA) {
#pragma unroll
        for (int k = 0; k < 4; ++k) {
          unsigned a0 = ((const unsigned*)&va[0])[k], a1 = ((const unsigned*)&va[1])[k];
          unsigned a2 = ((const unsigned*)&va[2])[k], a3 = ((const unsigned*)&va[3])[k];
          uint2 lo = { (a0 & 0xffffu) | (a1 << 16), (a2 & 0xffffu) | (a3 << 16) };
          uint2 hi = { (a0 >> 16) | (a1 & 0xffff0000u), (a2 >> 16) | (a3 & 0xffff0000u) };
          *(uint2*)((char*)sAb + (unsigned)(ch0a + 2 * k) * 128 + wposa) = lo;
          *(uint2*)((char*)sAb + (unsigned)(ch0a + 2 * k + 1) * 128 + wposa) = hi;
        }
      }
      __syncthreads();                       // tile visible
      if (kc < 15) {                         // prefetch next chunk under compute
        const bf16* xb2 = xb + (size_t)(kc + 1) * 64 * Cc;
#pragma unroll
        for (int j = 0; j < 4; ++j)
          vb[j] = *(const uint4*)(xb2 + (size_t)(tgb * 4 + j) * Cc + n0 + ch0b);
        if (doA)
#pragma unroll
          for (int j = 0; j < 4; ++j)
            va[j] = *(const uint4*)(xb2 + (size_t)(tga * 4 + j) * Cc + m0 + ch0a);
      }
#pragma unroll
      for (int kk = 0; kk < 2; ++kk) {       // k-steps: tokens kk*32 .. kk*32+31
        bfrag af[4], bg[2];
#pragma unroll
        for (int i = 0; i < 4; ++i) {
          int ch = i * 16 + fr;
          int slot = (kk * 4 + quad) ^ g3((ch >> 3) & 7);
          af[i] = *(const bfrag*)(sA + ch * 64 + slot * 8);
        }
#pragma unroll
        for (int j = 0; j < 2; ++j) {
          int ch = wn + j * 16 + fr;
          int slot = (kk * 4 + quad) ^ g3((ch >> 3) & 7);
          bg[j] = *(const bfrag*)(sB + ch * 64 + slot * 8);
        }
#pragma unroll
        for (int i = 0; i < 4; ++i)
#pragma unroll
          for (int j = 0; j < 2; ++j)
            acc[i][j] = __builtin_amdgcn_mfma_f32_16x16x32_bf16(af[i], bg[j], acc[i][j], 0, 0, 0);
      }
    }
    float* pb = part + (size_t)split * SPL_STRIDE + ((size_t)b * 20 + tile) * 8192;
#pragma unroll
    for (int i = 0; i < 4; ++i)
#pragma unroll
      for (int j = 0; j < 2; ++j)
#pragma unroll
        for (int r = 0; r < 4; ++r)
          pb[(i * 16 + quad * 4 + r) * 128 + wn + j * 16 + fr] = acc[i][j][r];
  }
}

// ---- per (b,h): Gram = T_q @ Wk^T (MFMA, K=512), norms via row-dots, softmax -> P bf16 ----
__global__ __launch_bounds__(256) void gram_softmax(const bf16* __restrict__ T,
                                                    const bf16* __restrict__ wq,
                                                    const float* __restrict__ temp,
                                                    bf16* __restrict__ P) {
  int h = blockIdx.x, b = blockIdx.y;
  int t = threadIdx.x, w = t >> 6, lane = t & 63, fr = lane & 15, quad = lane >> 4;
  const bf16* Tq = T + (size_t)b * 1024 * 512 + (size_t)(h * 64) * 512;
  const bf16* Tk = T + (size_t)b * 1024 * 512 + (size_t)(512 + h * 64) * 512;
  const bf16* Wqh = wq + (size_t)(h * 64) * 512;
  const bf16* Wkh = wq + (size_t)(512 + h * 64) * 512;
  f32x4 acc[4][4] = {};
#pragma unroll
  for (int s = 0; s < 4; ++s) {
    int kb = w * 128 + s * 32 + quad * 8;
    bfrag af[4], bg[4];
#pragma unroll
    for (int i = 0; i < 4; ++i) af[i] = *(const bfrag*)(Tq + (size_t)(i * 16 + fr) * 512 + kb);
#pragma unroll
    for (int j = 0; j < 4; ++j) bg[j] = *(const bfrag*)(Wkh + (size_t)(j * 16 + fr) * 512 + kb);
#pragma unroll
    for (int i = 0; i < 4; ++i)
#pragma unroll
      for (int j = 0; j < 4; ++j)
        acc[i][j] = __builtin_amdgcn_mfma_f32_16x16x32_bf16(af[i], bg[j], acc[i][j], 0, 0, 0);
  }
  __shared__ float parts[4 * 4096];
  __shared__ float nrm[2][4][64];
  __shared__ float nqk[2][64];
#pragma unroll
  for (int i = 0; i < 4; ++i)
#pragma unroll
    for (int j = 0; j < 4; ++j)
#pragma unroll
      for (int r = 0; r < 4; ++r)
        parts[w * 4096 + (i * 16 + quad * 4 + r) * 64 + j * 16 + fr] = acc[i][j][r];
  {
    int d = t & 63, qtr = t >> 6, c0 = qtr * 128;
    float pq = 0.f, pk = 0.f;
#pragma unroll 4
    for (int cc = 0; cc < 16; ++cc) {
      bf16 a[8], ww[8];
      *(uint4*)a  = *(const uint4*)(Tq + (size_t)d * 512 + c0 + cc * 8);
      *(uint4*)ww = *(const uint4*)(Wqh + (size_t)d * 512 + c0 + cc * 8);
#pragma unroll
      for (int j = 0; j < 8; ++j) pq += __bfloat162float(a[j]) * __bfloat162float(ww[j]);
      *(uint4*)a  = *(const uint4*)(Tk + (size_t)d * 512 + c0 + cc * 8);
      *(uint4*)ww = *(const uint4*)(Wkh + (size_t)d * 512 + c0 + cc * 8);
#pragma unroll
      for (int j = 0; j < 8; ++j) pk += __bfloat162float(a[j]) * __bfloat162float(ww[j]);
    }
    nrm[0][qtr][d] = pq;
    nrm[1][qtr][d] = pk;
  }
  __syncthreads();
  if (t < 64) {
    nqk[0][t] = fmaxf(sqrtf(nrm[0][0][t] + nrm[0][1][t] + nrm[0][2][t] + nrm[0][3][t]), 1e-12f);
    nqk[1][t] = fmaxf(sqrtf(nrm[1][0][t] + nrm[1][1][t] + nrm[1][2][t] + nrm[1][3][t]), 1e-12f);
  }
  __syncthreads();
  if (t < 64) {
    int d = t;
    float sc = temp[h] / nqk[0][d];
    float l[64]; float mx = -1e30f;
#pragma unroll
    for (int e = 0; e < 64; ++e) {
      float vsum = parts[d * 64 + e] + parts[4096 + d * 64 + e] +
                   parts[8192 + d * 64 + e] + parts[12288 + d * 64 + e];
      l[e] = vsum * sc / nqk[1][e];
      mx = fmaxf(mx, l[e]);
    }
    float sum = 0.f;
#pragma unroll
    for (int e = 0; e < 64; ++e) { l[e] = expf(l[e] - mx); sum += l[e]; }
    float inv = 1.0f / sum;
    bf16* pr = P + ((size_t)(b * 8 + h) * 64 + d) * 64;
#pragma unroll
    for (int e = 0; e < 64; ++e) pr[e] = __float2bfloat16(l[e] * inv);
  }
}

// ---- out = P @ v, exact GELU, store g[token][C] (bf16) ----
__global__ __launch_bounds__(256) void pv_gelu(const bf16* __restrict__ P,
                                               const bf16* __restrict__ v,
                                               bf16* __restrict__ g) {
  int chunk = blockIdx.x, h = blockIdx.y, b = blockIdx.z;
  int t = threadIdx.x, w = t >> 6, lane = t & 63, fr = lane & 15, quad = lane >> 4;
  const bf16* pb = P + (size_t)(b * 8 + h) * 4096;
  bfrag pf[4][2];
#pragma unroll
  for (int i = 0; i < 4; ++i)
#pragma unroll
    for (int c = 0; c < 2; ++c)
      pf[i][c] = *(const bfrag*)(pb + (i * 16 + fr) * 64 + c * 32 + quad * 8);
#pragma unroll 2
  for (int nt = 0; nt < 8; ++nt) {
    int ntok = chunk * 512 + w * 128 + nt * 16 + fr;
    const bf16* vrow = v + (size_t)(b * Nn + ntok) * Cc + h * 64 + quad * 8;
    bfrag bv0 = *(const bfrag*)(vrow);
    bfrag bv1 = *(const bfrag*)(vrow + 32);
    f32x4 acc[4] = {};
#pragma unroll
    for (int i = 0; i < 4; ++i) {
      acc[i] = __builtin_amdgcn_mfma_f32_16x16x32_bf16(pf[i][0], bv0, acc[i], 0, 0, 0);
      acc[i] = __builtin_amdgcn_mfma_f32_16x16x32_bf16(pf[i][1], bv1, acc[i], 0, 0, 0);
    }
    bf16* grow = g + (size_t)(b * Nn + ntok) * Cc + h * 64;
#pragma unroll
    for (int i = 0; i < 4; ++i) {
      bf16 o[4];
#pragma unroll
      for (int r = 0; r < 4; ++r) o[r] = __float2bfloat16(gelu_exact(acc[i][r]));
      *(uint2*)(grow + i * 16 + quad * 4) = *(uint2*)o;
    }
  }
}

extern "C" void kernel_launch(void* const* d_in, const int* in_sizes, int n_in,
                              void* d_out, int out_size, void* d_ws, size_t ws_size,
                              hipStream_t stream) {
  const float* x      = (const float*)d_in[0];
  const float* ln_g   = (const float*)d_in[1];
  const float* ln_b   = (const float*)d_in[2];
  const float* qkv_w  = (const float*)d_in[3];
  const float* temp   = (const float*)d_in[4];
  const float* proj_w = (const float*)d_in[5];
  const float* proj_b = (const float*)d_in[6];
  float* out = (float*)d_out;                       // fp32 output (reference returns float32)
  char*  ws  = (char*)d_ws;

  // --- runtime guards: silent failure -> measurable absmax signature ---
  const int exp_sizes[7] = {16777216, 512, 512, 786432, 8, 262144, 512};
  bool sizes_ok = (n_in == 7) && (out_size == 16777216);
  if (sizes_ok) for (int i = 0; i < 7; ++i) sizes_ok = sizes_ok && (in_sizes[i] == exp_sizes[i]);
  if (!sizes_ok) {
    fill_f32<<<(16777216 + 255) / 256, 256, 0, stream>>>(out, 500.0f, out_size);
    return;
  }
  if (ws_size < WS_NEED) {
    fill_f32<<<(16777216 + 255) / 256, 256, 0, stream>>>(out, (float)(ws_size >> 20), out_size);
    return;
  }

  bf16*  xn   = (bf16*)ws;                          // reused as g after xtx+vGEMM consume it
  bf16*  g    = (bf16*)ws;
  bf16*  Gcvb = (bf16*)(ws + 41943040);
  bf16*  T    = (bf16*)(ws + 46137344);
  bf16*  P    = (bf16*)(ws + 54525952);
  bf16*  wq   = (bf16*)(ws + 55050240);
  bf16*  wp   = (bf16*)(ws + 56623104);
  bf16*  v    = (bf16*)d_out;                       // park bf16 v in d_out lower half
  float* part = (float*)((char*)d_out + 33554432);  // xtx partials in d_out upper half (21 MB)

  ln_cvtw<<<8704, 256, 0, stream>>>(x, ln_g, ln_b, xn, qkv_w, proj_w, wq, wp);
  // fused: v = xn @ Wv^T (blocks 0..1023) + xtx partials (blocks 1024..1663)
  vgemm_xtx<<<1664, 256, 0, stream>>>(xn, wq + 1024 * 512, v, part);
  cvt_mirror<<<dim3(16, 8), 256, 0, stream>>>(part, Gcvb);
  // T[b] = Wqk @ Gcov[b]  (Gcov symmetric => @Gcov^T == @Gcov)
  gemm_bt<bf16, false><<<dim3(4, 8, 8), 256, 0, stream>>>(wq, Gcvb, T, 1024, Cc, Cc,
                                                          nullptr, 0, (long)Cc * Cc, (long)1024 * Cc);
  gram_softmax<<<dim3(Hh, Bb), 256, 0, stream>>>(T, wq, temp, P);
  pv_gelu<<<dim3(8, Hh, Bb), 256, 0, stream>>>(P, v, g);
  // out = g @ proj_w^T + proj_b  (fp32 stores, overwrites v + partials)
  gemm_bt<float, true><<<dim3(4, 256, 1), 256, 0, stream>>>(g, wp, out, Mtok, Cc, Cc,
                                                            proj_b, 0, 0, 0);
}

// Round 18
// 254.657 us; speedup vs baseline: 1.2635x; 1.0134x over previous
//
#include <hip/hip_runtime.h>
#include <hip/hip_bf16.h>

typedef __hip_bfloat16 bf16;
typedef __bf16 bfrag __attribute__((ext_vector_type(8)));   // 8 bf16 = 4 VGPRs (MFMA A/B operand)
typedef float f32x4 __attribute__((ext_vector_type(4)));    // MFMA C/D

#define AS1 __attribute__((address_space(1)))
#define AS3 __attribute__((address_space(3)))

static constexpr int Bb = 8, Nn = 4096, Cc = 512, Hh = 8;
static constexpr int Mtok = Bb * Nn;          // 32768
static constexpr int QKVC = 3 * Cc;           // 1536
// ws layout (NEED = 57,147,392 bytes; proven ws_size >= 59,768,832):
//  xn/g [0, 33554432)          bf16 [32768][512]
//  Gcvb [41943040, 46137344)   bf16 [8][512][512]
//  T    [46137344, 54525952)   bf16 [8][1024][512]
//  P    [54525952, 55050240)   bf16 [8][8][64][64]
//  wq   [55050240, 56623104)   bf16 [1536][512]
//  wp   [56623104, 57147392)   bf16 [512][512]
// d_out (67.1 MB): v bf16 [0, 33554432); xtx partials f32 [33554432, 54525952);
//   both dead before the final GEMM writes out.
static constexpr size_t WS_NEED = 57147392;
static constexpr int SPL_STRIDE = 8 * 20 * 8192;   // floats per split in partial buffer

__device__ __forceinline__ void gl_lds16(const void* g, void* l) {
  __builtin_amdgcn_global_load_lds((const AS1 void*)g, (AS3 void*)l, 16, 0, 0);
}
__device__ __forceinline__ float gelu_exact(float x) {
  return 0.5f * x * (1.0f + erff(x * 0.70710678118654752f));
}
// 3-bit rotate-right-by-1: bijection used for LDS slot swizzle (conflict-free reads AND writes)
__device__ __forceinline__ int g3(int x) { return ((x & 1) << 2) | (x >> 1); }
// xtx tile id from (mt 64-row, nt 128-col) upper-tri indices; section sizes 2,4,6,8
__device__ __forceinline__ int tileid(int mt, int nt) {
  return mt + (nt == 0 ? 0 : nt == 1 ? 2 : nt == 2 ? 6 : 12);
}

// ---------------- diagnostic fill (fp32 output) ----------------
__global__ __launch_bounds__(256) void fill_f32(float* o, float val, int n) {
  int i = blockIdx.x * 256 + threadIdx.x;
  if (i < n) o[i] = val;
}

// ------- fused: LayerNorm (blocks 0..8191) + weight conversion (blocks 8192..8703) -------
__global__ __launch_bounds__(256) void ln_cvtw(const float* __restrict__ x,
                                               const float* __restrict__ gw,
                                               const float* __restrict__ bw,
                                               bf16* __restrict__ xn,
                                               const float* __restrict__ qkv_w,
                                               const float* __restrict__ proj_w,
                                               bf16* __restrict__ wq,
                                               bf16* __restrict__ wp) {
  int bid = blockIdx.x;
  if (bid < 8192) {
    int tok  = bid * 4 + (threadIdx.x >> 6);
    int lane = threadIdx.x & 63;
    const float* xr = x + (size_t)tok * Cc + lane * 8;
    float f[8];
    *(float4*)f       = *(const float4*)xr;
    *(float4*)(f + 4) = *(const float4*)(xr + 4);
    float s = 0.f;
#pragma unroll
    for (int j = 0; j < 8; ++j) s += f[j];
#pragma unroll
    for (int m = 32; m; m >>= 1) s += __shfl_xor(s, m);
    float mu = s * (1.0f / 512.0f);
    float q = 0.f;
#pragma unroll
    for (int j = 0; j < 8; ++j) { float d = f[j] - mu; q += d * d; }
#pragma unroll
    for (int m = 32; m; m >>= 1) q += __shfl_xor(q, m);
    float rstd = rsqrtf(q * (1.0f / 512.0f) + 1e-5f);
    bf16 o[8];
#pragma unroll
    for (int j = 0; j < 8; ++j)
      o[j] = __float2bfloat16((f[j] - mu) * rstd * gw[lane * 8 + j] + bw[lane * 8 + j]);
    *(uint4*)(xn + (size_t)tok * Cc + lane * 8) = *(uint4*)o;
  } else {
    int cb = bid - 8192;
    const float* a;
    bf16* o;
    int i;
    if (cb < 384) { a = qkv_w;  o = wq; i = (cb * 256 + (int)threadIdx.x) * 8; }
    else          { a = proj_w; o = wp; i = ((cb - 384) * 256 + (int)threadIdx.x) * 8; }
    float f[8];
    *(float4*)f       = *(const float4*)(a + i);
    *(float4*)(f + 4) = *(const float4*)(a + i + 4);
    bf16 vv[8];
#pragma unroll
    for (int j = 0; j < 8; ++j) vv[j] = __float2bfloat16(f[j]);
    *(uint4*)(o + i) = *(uint4*)vv;
  }
}

// ---- sum 4 xtx split-partials -> Gcvb (full bf16); lower tiles mirrored via LDS ----
__global__ __launch_bounds__(256) void cvt_mirror(const float* __restrict__ part,
                                                  bf16* __restrict__ Gcvb) {
  int tile = blockIdx.x, b = blockIdx.y;
  int ti = tile >> 2, tj = tile & 3;
  int t = threadIdx.x;
  bf16* ob = Gcvb + (size_t)b * Cc * Cc;
  if (ti <= tj) {
#pragma unroll
    for (int r8 = 0; r8 < 8; ++r8) {
      int row = r8 * 16 + (t >> 4), col = (t & 15) * 8;
      int mt = 2 * ti + (row >> 6), rsub = row & 63;
      const float* p0 = part + ((size_t)b * 20 + tileid(mt, tj)) * 8192 + rsub * 128 + col;
      float f[8];
      *(float4*)f       = *(const float4*)p0;
      *(float4*)(f + 4) = *(const float4*)(p0 + 4);
#pragma unroll
      for (int s = 1; s < 4; ++s) {
        const float* ps = p0 + (size_t)s * SPL_STRIDE;
        float g[8];
        *(float4*)g       = *(const float4*)ps;
        *(float4*)(g + 4) = *(const float4*)(ps + 4);
#pragma unroll
        for (int j = 0; j < 8; ++j) f[j] += g[j];
      }
      bf16 v[8];
#pragma unroll
      for (int j = 0; j < 8; ++j) v[j] = __float2bfloat16(f[j]);
      *(uint4*)(ob + (size_t)(ti * 128 + row) * Cc + tj * 128 + col) = *(uint4*)v;
    }
  } else {
    __shared__ bf16 ls[128][136];          // pad 8 -> row stride 272B (16B-aligned)
#pragma unroll
    for (int r8 = 0; r8 < 8; ++r8) {
      int srow = r8 * 16 + (t >> 4), scol = (t & 15) * 8;
      int mt = 2 * tj + (srow >> 6), rsub = srow & 63;
      const float* p0 = part + ((size_t)b * 20 + tileid(mt, ti)) * 8192 + rsub * 128 + scol;
      float f[8];
      *(float4*)f       = *(const float4*)p0;
      *(float4*)(f + 4) = *(const float4*)(p0 + 4);
#pragma unroll
      for (int s = 1; s < 4; ++s) {
        const float* ps = p0 + (size_t)s * SPL_STRIDE;
        float g[8];
        *(float4*)g       = *(const float4*)ps;
        *(float4*)(g + 4) = *(const float4*)(ps + 4);
#pragma unroll
        for (int j = 0; j < 8; ++j) f[j] += g[j];
      }
      bf16 v[8];
#pragma unroll
      for (int j = 0; j < 8; ++j) v[j] = __float2bfloat16(f[j]);
      *(uint4*)&ls[srow][scol] = *(uint4*)v;
    }
    __syncthreads();
#pragma unroll
    for (int r8 = 0; r8 < 8; ++r8) {
      int orow = r8 * 16 + (t >> 4), ocol = (t & 15) * 8;
      bf16 v[8];
#pragma unroll
      for (int u = 0; u < 8; ++u) v[u] = ls[ocol + u][orow];
      *(uint4*)(ob + (size_t)(ti * 128 + orow) * Cc + tj * 128 + ocol) = *(uint4*)v;
    }
  }
}

// ------------- 128-tile GEMM (kept for the small batched T-GEMM) -------------
template <typename TC, bool SWZ>
__global__ __launch_bounds__(256) void gemm_bt(const bf16* __restrict__ A,
                                               const bf16* __restrict__ B,
                                               TC* __restrict__ C,
                                               int M, int N, int K,
                                               const float* __restrict__ bias,
                                               long sA_z, long sB_z, long sC_z) {
  A += (size_t)blockIdx.z * sA_z;
  B += (size_t)blockIdx.z * sB_z;
  C += (size_t)blockIdx.z * sC_z;
  __shared__ __align__(16) bf16 smem[16384];
  bf16* sA = smem;
  bf16* sB = smem + 8192;
  int t = threadIdx.x, w = t >> 6, lane = t & 63, fr = lane & 15, quad = lane >> 4;
  int n0, m0;
  if constexpr (SWZ) {
    int flat = blockIdx.y * 4 + blockIdx.x;
    int idx  = (flat & 7) * 128 + (flat >> 3);
    n0 = (idx & 3) * 128;
    m0 = (idx >> 2) * 128;
  } else {
    n0 = blockIdx.x * 128;
    m0 = blockIdx.y * 128;
  }
  int wm = (w >> 1) * 64, wn = (w & 1) * 64;
  f32x4 acc[4][4] = {};

  for (int k0 = 0; k0 < K; k0 += 64) {
    __syncthreads();
#pragma unroll
    for (int c2 = 0; c2 < 4; ++c2) {
      int c = w * 4 + c2;
      int row = c * 8 + (lane >> 3);
      int ke  = ((lane & 7) ^ (lane >> 3)) * 8;
      gl_lds16(A + (size_t)(m0 + row) * K + k0 + ke, (char*)sA + c * 1024);
      gl_lds16(B + (size_t)(n0 + row) * K + k0 + ke, (char*)sB + c * 1024);
    }
    __syncthreads();
#pragma unroll
    for (int kk = 0; kk < 64; kk += 32) {
      bfrag af[4], bg[4];
#pragma unroll
      for (int i = 0; i < 4; ++i)
        af[i] = *(const bfrag*)(sA + (wm + i * 16 + fr) * 64 +
                                ((((kk >> 3) + quad) ^ (fr & 7)) * 8));
#pragma unroll
      for (int j = 0; j < 4; ++j)
        bg[j] = *(const bfrag*)(sB + (wn + j * 16 + fr) * 64 +
                                ((((kk >> 3) + quad) ^ (fr & 7)) * 8));
#pragma unroll
      for (int i = 0; i < 4; ++i)
#pragma unroll
        for (int j = 0; j < 4; ++j)
          acc[i][j] = __builtin_amdgcn_mfma_f32_16x16x32_bf16(af[i], bg[j], acc[i][j], 0, 0, 0);
    }
  }

  if constexpr (__is_same(TC, float)) {
#pragma unroll
    for (int j = 0; j < 4; ++j) {
      float bj = bias ? bias[n0 + wn + j * 16 + fr] : 0.0f;
#pragma unroll
      for (int i = 0; i < 4; ++i)
#pragma unroll
        for (int r = 0; r < 4; ++r)
          C[(size_t)(m0 + wm + i * 16 + quad * 4 + r) * N + n0 + wn + j * 16 + fr] =
              acc[i][j][r] + bj;
    }
  } else {
    __syncthreads();
    bf16* ct = smem;                      // [128][128]
#pragma unroll
    for (int j = 0; j < 4; ++j) {
      float bj = bias ? bias[n0 + wn + j * 16 + fr] : 0.0f;
#pragma unroll
      for (int i = 0; i < 4; ++i)
#pragma unroll
        for (int r = 0; r < 4; ++r)
          ct[(wm + i * 16 + quad * 4 + r) * 128 + wn + j * 16 + fr] =
              __float2bfloat16(acc[i][j][r] + bj);
    }
    __syncthreads();
#pragma unroll
    for (int r8 = 0; r8 < 8; ++r8) {
      int row = r8 * 16 + (t >> 4);
      int ce  = (t & 15) * 8;
      *(uint4*)(C + (size_t)(m0 + row) * N + n0 + ce) = *(const uint4*)(smem + row * 128 + ce);
    }
  }
}

// ------------- 256x256-tile 2-PHASE double-buffered GEMM (T3/T4 minimum recipe) -------------
// stage(k+1) issued BEFORE compute(k); ONE __syncthreads (vmcnt0+barrier) per K-step, so
// next-tile loads are in flight during MFMA instead of a cold drain. Same verified slot
// swizzle (row stride 64 elems). 512 threads = 8 waves (2M x 4N, 128x64 out each).
// Grid must be M/256 * N/256 blocks (flat); XCD-chunked so same-A pairs share an L2.
template <typename TC>
__global__ __launch_bounds__(512) void gemm_bt2(const bf16* __restrict__ A,
                                                const bf16* __restrict__ B,
                                                TC* __restrict__ C,
                                                int M, int N, int K,
                                                const float* __restrict__ bias) {
  __shared__ __align__(16) bf16 smem[65536];   // 128KB: 2 x (sA[256][64] | sB[256][64]); reused as ct
  int t = threadIdx.x, w = t >> 6, lane = t & 63, fr = lane & 15, quad = lane >> 4;
  int nt2 = N >> 8;                            // n-tiles (2 for N=512)
  int flat = blockIdx.x;
  int idx  = (flat & 7) * (gridDim.x >> 3) + (flat >> 3);   // XCD-chunked (grid % 8 == 0)
  int m0 = (idx / nt2) * 256, n0 = (idx % nt2) * 256;
  int wm = (w >> 2) * 128, wn = (w & 3) * 64;
  f32x4 acc[8][4] = {};

  // stage one 64-wide K-strip of the 256-row A and B panels into buffer `buf`
  auto stage = [&](int buf, int k0) {
    char* sAc = (char*)(smem + buf * 32768);
    char* sBc = sAc + 32768;                   // +16384 bf16
    int ke = ((lane & 7) ^ (lane >> 3)) * 8;   // pre-swizzled source slot
#pragma unroll
    for (int c2 = 0; c2 < 4; ++c2) {
      int c = w * 4 + c2;                      // 0..31: A chunks
      int row = c * 8 + (lane >> 3);
      gl_lds16(A + (size_t)(m0 + row) * K + k0 + ke, sAc + c * 1024);
      gl_lds16(B + (size_t)(n0 + row) * K + k0 + ke, sBc + c * 1024);
    }
  };

  stage(0, 0);
  __syncthreads();                             // drains vmcnt -> buf0 ready
  int nks = K >> 6;
  for (int ks = 0; ks < nks; ++ks) {
    if (ks + 1 < nks) stage((ks + 1) & 1, (ks + 1) * 64);   // overlap with compute below
    const bf16* sA = smem + (ks & 1) * 32768;
    const bf16* sB = sA + 16384;
#pragma unroll
    for (int kk = 0; kk < 64; kk += 32) {
      bfrag af[8], bg[4];
#pragma unroll
      for (int i = 0; i < 8; ++i)
        af[i] = *(const bfrag*)(sA + (wm + i * 16 + fr) * 64 +
                                ((((kk >> 3) + quad) ^ (fr & 7)) * 8));
#pragma unroll
      for (int j = 0; j < 4; ++j)
        bg[j] = *(const bfrag*)(sB + (wn + j * 16 + fr) * 64 +
                                ((((kk >> 3) + quad) ^ (fr & 7)) * 8));
#pragma unroll
      for (int i = 0; i < 8; ++i)
#pragma unroll
        for (int j = 0; j < 4; ++j)
          acc[i][j] = __builtin_amdgcn_mfma_f32_16x16x32_bf16(af[i], bg[j], acc[i][j], 0, 0, 0);
    }
    __syncthreads();                           // drains next-tile loads + retires buf reads
  }

  if constexpr (__is_same(TC, float)) {
    // direct fp32 stores (col=fr within j-frag, row=quad*4+r within i-frag)
#pragma unroll
    for (int j = 0; j < 4; ++j) {
      float bj = bias ? bias[n0 + wn + j * 16 + fr] : 0.0f;
#pragma unroll
      for (int i = 0; i < 8; ++i)
#pragma unroll
        for (int r = 0; r < 4; ++r)
          C[(size_t)(m0 + wm + i * 16 + quad * 4 + r) * N + n0 + wn + j * 16 + fr] =
              acc[i][j][r] + bj;
    }
  } else {
    bf16* ct = smem;                           // [256][256] (128KB, all compute retired)
#pragma unroll
    for (int j = 0; j < 4; ++j) {
      float bj = bias ? bias[n0 + wn + j * 16 + fr] : 0.0f;
#pragma unroll
      for (int i = 0; i < 8; ++i)
#pragma unroll
        for (int r = 0; r < 4; ++r)
          ct[(wm + i * 16 + quad * 4 + r) * 256 + wn + j * 16 + fr] =
              __float2bfloat16(acc[i][j][r] + bj);
    }
    __syncthreads();
#pragma unroll
    for (int it = 0; it < 16; ++it) {
      int row = it * 16 + (t >> 5);
      int ce  = (t & 31) * 8;
      *(uint4*)(C + (size_t)(m0 + row) * N + n0 + ce) = *(const uint4*)(ct + row * 256 + ce);
    }
  }
}

// ---- partials[split][b][tile] += Xb^T Xb — 64x128 upper-tri tiles (m <= 2n+1), split-K=4.
// NO atomics; single-buffered LDS (measured-equivalent); g3 slot swizzle; plain stores.
__global__ __launch_bounds__(256) void xtx(const bf16* __restrict__ xn,
                                           float* __restrict__ part) {
  bf16* sB;
  bf16* sAb;
  __shared__ __align__(16) bf16 smem[12288];   // sB 16KB + sAb 8KB
  sB = smem; sAb = smem + 8192;
  int flat = blockIdx.x;                       // 0..639 = 8 XCDs * 80
  int idx  = (flat & 7) * 80 + (flat >> 3);
  int tile = idx % 20;
  int sb   = idx / 20;                         // 0..31
  int split = sb & 3, b = sb >> 2;
  int nt = tile < 2 ? 0 : tile < 6 ? 1 : tile < 12 ? 2 : 3;
  int mt = tile - (nt == 0 ? 0 : nt == 1 ? 2 : nt == 2 ? 6 : 12);
  int m0 = mt * 64, n0 = nt * 128;
  bool alias = ((mt >> 1) == nt);              // A channels within B strip
  int t = threadIdx.x, w = t >> 6, lane = t & 63, fr = lane & 15, quad = lane >> 4;
  int wn = w * 32;
  bf16* sA = alias ? (sB + (mt & 1) * 4096) : sAb;
  f32x4 acc[4][2] = {};
  const bf16* xb = xn + ((size_t)b * Nn + split * 1024) * Cc;
  int ch0b = (t & 15) * 8, tgb = t >> 4;
  int ch0a = (t & 7) * 8,  tga = t >> 3;
  bool doA = (!alias) && (t < 128);
  unsigned swz = (unsigned)g3(t & 7);
  unsigned wposb = (((unsigned)(tgb >> 1) ^ swz) * 16u) + (unsigned)(tgb & 1) * 8u;
  unsigned wposa = (((unsigned)(tga >> 1) ^ swz) * 16u) + (unsigned)(tga & 1) * 8u;
  uint4 va[4], vb[4];
#pragma unroll
  for (int j = 0; j < 4; ++j)
    vb[j] = *(const uint4*)(xb + (size_t)(tgb * 4 + j) * Cc + n0 + ch0b);
  if (doA)
#pragma unroll
    for (int j = 0; j < 4; ++j)
      va[j] = *(const uint4*)(xb + (size_t)(tga * 4 + j) * Cc + m0 + ch0a);
  for (int kc = 0; kc < 16; ++kc) {
    __syncthreads();
#pragma unroll
    for (int k = 0; k < 4; ++k) {
      unsigned b0 = ((const unsigned*)&vb[0])[k], b1 = ((const unsigned*)&vb[1])[k];
      unsigned b2 = ((const unsigned*)&vb[2])[k], b3 = ((const unsigned*)&vb[3])[k];
      uint2 lo = { (b0 & 0xffffu) | (b1 << 16), (b2 & 0xffffu) | (b3 << 16) };
      uint2 hi = { (b0 >> 16) | (b1 & 0xffff0000u), (b2 >> 16) | (b3 & 0xffff0000u) };
      *(uint2*)((char*)sB + (unsigned)(ch0b + 2 * k) * 128 + wposb) = lo;
      *(uint2*)((char*)sB + (unsigned)(ch0b + 2 * k + 1) * 128 + wposb) = hi;
    }
    if (doA) {
#pragma unroll
      for (int k = 0; k < 4; ++k) {
        unsigned a0 = ((const unsigned*)&va[0])[k], a1 = ((const unsigned*)&va[1])[k];
        unsigned a2 = ((const unsigned*)&va[2])[k], a3 = ((const unsigned*)&va[3])[k];
        uint2 lo = { (a0 & 0xffffu) | (a1 << 16), (a2 & 0xffffu) | (a3 << 16) };
        uint2 hi = { (a0 >> 16) | (a1 & 0xffff0000u), (a2 >> 16) | (a3 & 0xffff0000u) };
        *(uint2*)((char*)sAb + (unsigned)(ch0a + 2 * k) * 128 + wposa) = lo;
        *(uint2*)((char*)sAb + (unsigned)(ch0a + 2 * k + 1) * 128 + wposa) = hi;
      }
    }
    __syncthreads();
    if (kc < 15) {
      const bf16* xb2 = xb + (size_t)(kc + 1) * 64 * Cc;
#pragma unroll
      for (int j = 0; j < 4; ++j)
        vb[j] = *(const uint4*)(xb2 + (size_t)(tgb * 4 + j) * Cc + n0 + ch0b);
      if (doA)
#pragma unroll
        for (int j = 0; j < 4; ++j)
          va[j] = *(const uint4*)(xb2 + (size_t)(tga * 4 + j) * Cc + m0 + ch0a);
    }
#pragma unroll
    for (int kk = 0; kk < 2; ++kk) {
      bfrag af[4], bg[2];
#pragma unroll
      for (int i = 0; i < 4; ++i) {
        int ch = i * 16 + fr;
        int slot = (kk * 4 + quad) ^ g3((ch >> 3) & 7);
        af[i] = *(const bfrag*)(sA + ch * 64 + slot * 8);
      }
#pragma unroll
      for (int j = 0; j < 2; ++j) {
        int ch = wn + j * 16 + fr;
        int slot = (kk * 4 + quad) ^ g3((ch >> 3) & 7);
        bg[j] = *(const bfrag*)(sB + ch * 64 + slot * 8);
      }
#pragma unroll
      for (int i = 0; i < 4; ++i)
#pragma unroll
        for (int j = 0; j < 2; ++j)
          acc[i][j] = __builtin_amdgcn_mfma_f32_16x16x32_bf16(af[i], bg[j], acc[i][j], 0, 0, 0);
    }
  }
  float* pb = part + (size_t)split * SPL_STRIDE + ((size_t)b * 20 + tile) * 8192;
#pragma unroll
  for (int i = 0; i < 4; ++i)
#pragma unroll
    for (int j = 0; j < 2; ++j)
#pragma unroll
      for (int r = 0; r < 4; ++r)
        pb[(i * 16 + quad * 4 + r) * 128 + wn + j * 16 + fr] = acc[i][j][r];
}

// ---- per (b,h): Gram = T_q @ Wk^T (MFMA, K=512), norms via row-dots, softmax -> P bf16 ----
__global__ __launch_bounds__(256) void gram_softmax(const bf16* __restrict__ T,
                                                    const bf16* __restrict__ wq,
                                                    const float* __restrict__ temp,
                                                    bf16* __restrict__ P) {
  int h = blockIdx.x, b = blockIdx.y;
  int t = threadIdx.x, w = t >> 6, lane = t & 63, fr = lane & 15, quad = lane >> 4;
  const bf16* Tq = T + (size_t)b * 1024 * 512 + (size_t)(h * 64) * 512;
  const bf16* Tk = T + (size_t)b * 1024 * 512 + (size_t)(512 + h * 64) * 512;
  const bf16* Wqh = wq + (size_t)(h * 64) * 512;
  const bf16* Wkh = wq + (size_t)(512 + h * 64) * 512;
  f32x4 acc[4][4] = {};
#pragma unroll
  for (int s = 0; s < 4; ++s) {
    int kb = w * 128 + s * 32 + quad * 8;
    bfrag af[4], bg[4];
#pragma unroll
    for (int i = 0; i < 4; ++i) af[i] = *(const bfrag*)(Tq + (size_t)(i * 16 + fr) * 512 + kb);
#pragma unroll
    for (int j = 0; j < 4; ++j) bg[j] = *(const bfrag*)(Wkh + (size_t)(j * 16 + fr) * 512 + kb);
#pragma unroll
    for (int i = 0; i < 4; ++i)
#pragma unroll
      for (int j = 0; j < 4; ++j)
        acc[i][j] = __builtin_amdgcn_mfma_f32_16x16x32_bf16(af[i], bg[j], acc[i][j], 0, 0, 0);
  }
  __shared__ float parts[4 * 4096];
  __shared__ float nrm[2][4][64];
  __shared__ float nqk[2][64];
#pragma unroll
  for (int i = 0; i < 4; ++i)
#pragma unroll
    for (int j = 0; j < 4; ++j)
#pragma unroll
      for (int r = 0; r < 4; ++r)
        parts[w * 4096 + (i * 16 + quad * 4 + r) * 64 + j * 16 + fr] = acc[i][j][r];
  {
    int d = t & 63, qtr = t >> 6, c0 = qtr * 128;
    float pq = 0.f, pk = 0.f;
#pragma unroll 4
    for (int cc = 0; cc < 16; ++cc) {
      bf16 a[8], ww[8];
      *(uint4*)a  = *(const uint4*)(Tq + (size_t)d * 512 + c0 + cc * 8);
      *(uint4*)ww = *(const uint4*)(Wqh + (size_t)d * 512 + c0 + cc * 8);
#pragma unroll
      for (int j = 0; j < 8; ++j) pq += __bfloat162float(a[j]) * __bfloat162float(ww[j]);
      *(uint4*)a  = *(const uint4*)(Tk + (size_t)d * 512 + c0 + cc * 8);
      *(uint4*)ww = *(const uint4*)(Wkh + (size_t)d * 512 + c0 + cc * 8);
#pragma unroll
      for (int j = 0; j < 8; ++j) pk += __bfloat162float(a[j]) * __bfloat162float(ww[j]);
    }
    nrm[0][qtr][d] = pq;
    nrm[1][qtr][d] = pk;
  }
  __syncthreads();
  if (t < 64) {
    nqk[0][t] = fmaxf(sqrtf(nrm[0][0][t] + nrm[0][1][t] + nrm[0][2][t] + nrm[0][3][t]), 1e-12f);
    nqk[1][t] = fmaxf(sqrtf(nrm[1][0][t] + nrm[1][1][t] + nrm[1][2][t] + nrm[1][3][t]), 1e-12f);
  }
  __syncthreads();
  if (t < 64) {
    int d = t;
    float sc = temp[h] / nqk[0][d];
    float l[64]; float mx = -1e30f;
#pragma unroll
    for (int e = 0; e < 64; ++e) {
      float vsum = parts[d * 64 + e] + parts[4096 + d * 64 + e] +
                   parts[8192 + d * 64 + e] + parts[12288 + d * 64 + e];
      l[e] = vsum * sc / nqk[1][e];
      mx = fmaxf(mx, l[e]);
    }
    float sum = 0.f;
#pragma unroll
    for (int e = 0; e < 64; ++e) { l[e] = expf(l[e] - mx); sum += l[e]; }
    float inv = 1.0f / sum;
    bf16* pr = P + ((size_t)(b * 8 + h) * 64 + d) * 64;
#pragma unroll
    for (int e = 0; e < 64; ++e) pr[e] = __float2bfloat16(l[e] * inv);
  }
}

// ---- out = P @ v, exact GELU, store g[token][C] (bf16) ----
__global__ __launch_bounds__(256) void pv_gelu(const bf16* __restrict__ P,
                                               const bf16* __restrict__ v,
                                               bf16* __restrict__ g) {
  int chunk = blockIdx.x, h = blockIdx.y, b = blockIdx.z;
  int t = threadIdx.x, w = t >> 6, lane = t & 63, fr = lane & 15, quad = lane >> 4;
  const bf16* pb = P + (size_t)(b * 8 + h) * 4096;
  bfrag pf[4][2];
#pragma unroll
  for (int i = 0; i < 4; ++i)
#pragma unroll
    for (int c = 0; c < 2; ++c)
      pf[i][c] = *(const bfrag*)(pb + (i * 16 + fr) * 64 + c * 32 + quad * 8);
#pragma unroll 2
  for (int nt = 0; nt < 8; ++nt) {
    int ntok = chunk * 512 + w * 128 + nt * 16 + fr;
    const bf16* vrow = v + (size_t)(b * Nn + ntok) * Cc + h * 64 + quad * 8;
    bfrag bv0 = *(const bfrag*)(vrow);
    bfrag bv1 = *(const bfrag*)(vrow + 32);
    f32x4 acc[4] = {};
#pragma unroll
    for (int i = 0; i < 4; ++i) {
      acc[i] = __builtin_amdgcn_mfma_f32_16x16x32_bf16(pf[i][0], bv0, acc[i], 0, 0, 0);
      acc[i] = __builtin_amdgcn_mfma_f32_16x16x32_bf16(pf[i][1], bv1, acc[i], 0, 0, 0);
    }
    bf16* grow = g + (size_t)(b * Nn + ntok) * Cc + h * 64;
#pragma unroll
    for (int i = 0; i < 4; ++i) {
      bf16 o[4];
#pragma unroll
      for (int r = 0; r < 4; ++r) o[r] = __float2bfloat16(gelu_exact(acc[i][r]));
      *(uint2*)(grow + i * 16 + quad * 4) = *(uint2*)o;
    }
  }
}

extern "C" void kernel_launch(void* const* d_in, const int* in_sizes, int n_in,
                              void* d_out, int out_size, void* d_ws, size_t ws_size,
                              hipStream_t stream) {
  const float* x      = (const float*)d_in[0];
  const float* ln_g   = (const float*)d_in[1];
  const float* ln_b   = (const float*)d_in[2];
  const float* qkv_w  = (const float*)d_in[3];
  const float* temp   = (const float*)d_in[4];
  const float* proj_w = (const float*)d_in[5];
  const float* proj_b = (const float*)d_in[6];
  float* out = (float*)d_out;                       // fp32 output (reference returns float32)
  char*  ws  = (char*)d_ws;

  // --- runtime guards: silent failure -> measurable absmax signature ---
  const int exp_sizes[7] = {16777216, 512, 512, 786432, 8, 262144, 512};
  bool sizes_ok = (n_in == 7) && (out_size == 16777216);
  if (sizes_ok) for (int i = 0; i < 7; ++i) sizes_ok = sizes_ok && (in_sizes[i] == exp_sizes[i]);
  if (!sizes_ok) {
    fill_f32<<<(16777216 + 255) / 256, 256, 0, stream>>>(out, 500.0f, out_size);
    return;
  }
  if (ws_size < WS_NEED) {
    fill_f32<<<(16777216 + 255) / 256, 256, 0, stream>>>(out, (float)(ws_size >> 20), out_size);
    return;
  }

  bf16*  xn   = (bf16*)ws;                          // reused as g after xtx+vGEMM consume it
  bf16*  g    = (bf16*)ws;
  bf16*  Gcvb = (bf16*)(ws + 41943040);
  bf16*  T    = (bf16*)(ws + 46137344);
  bf16*  P    = (bf16*)(ws + 54525952);
  bf16*  wq   = (bf16*)(ws + 55050240);
  bf16*  wp   = (bf16*)(ws + 56623104);
  bf16*  v    = (bf16*)d_out;                       // park bf16 v in d_out lower half
  float* part = (float*)((char*)d_out + 33554432);  // xtx partials in d_out upper half (21 MB)

  ln_cvtw<<<8704, 256, 0, stream>>>(x, ln_g, ln_b, xn, qkv_w, proj_w, wq, wp);
  // v = xn @ Wv^T  (256x256-tile 2-phase; grid 128 m-tiles x 2 n-tiles = 256 = 1/CU)
  gemm_bt2<bf16><<<256, 512, 0, stream>>>(xn, wq + 1024 * 512, v, Mtok, Cc, Cc, nullptr);
  xtx<<<640, 256, 0, stream>>>(xn, part);
  cvt_mirror<<<dim3(16, 8), 256, 0, stream>>>(part, Gcvb);
  // T[b] = Wqk @ Gcov[b]  (Gcov symmetric => @Gcov^T == @Gcov)
  gemm_bt<bf16, false><<<dim3(4, 8, 8), 256, 0, stream>>>(wq, Gcvb, T, 1024, Cc, Cc,
                                                          nullptr, 0, (long)Cc * Cc, (long)1024 * Cc);
  gram_softmax<<<dim3(Hh, Bb), 256, 0, stream>>>(T, wq, temp, P);
  pv_gelu<<<dim3(8, Hh, Bb), 256, 0, stream>>>(P, v, g);
  // out = g @ proj_w^T + proj_b  (fp32 stores, overwrites v + partials)
  gemm_bt2<float><<<256, 512, 0, stream>>>(g, wp, out, Mtok, Cc, Cc, proj_b);
}